// Round 10
// baseline (920.316 us; speedup 1.0000x reference)
//
#include <hip/hip_runtime.h>
#include <stdint.h>

// Transformer prefill: B=2,S=1024,V=32000,D=1024,H=16,L=4,DK=64,DF=4096
#define B_ 2
#define S_ 1024
#define V_ 32000
#define D_ 1024
#define H_ 16
#define L_ 4
#define DF_ 4096
#define M_ (B_*S_)

typedef short short8 __attribute__((ext_vector_type(8)));
typedef float f32x4 __attribute__((ext_vector_type(4)));

__device__ __forceinline__ unsigned short f2bf(float f){
  union { float f; unsigned int u; } v; v.f = f;
  unsigned int u = v.u;
  u = u + 0x7fffu + ((u >> 16) & 1u);
  return (unsigned short)(u >> 16);
}

__device__ __forceinline__ float bf2f(unsigned short u){
  union { unsigned int u; float f; } v; v.u = ((unsigned int)u) << 16;
  return v.f;
}

__device__ __forceinline__ void gload16(const void* g, void* l){
  __builtin_amdgcn_global_load_lds(
      (__attribute__((address_space(1))) void*)(uintptr_t)g,
      (__attribute__((address_space(3))) void*)(uintptr_t)l, 16, 0, 0);
}

// ---------------- embed gather ----------------
__global__ __launch_bounds__(256) void embed_k(const int* __restrict__ ids,
    const float* __restrict__ emb, float* __restrict__ x){
  int row = blockIdx.x;
  int id = ids[row];
  float4 v = reinterpret_cast<const float4*>(emb + (size_t)id*D_)[threadIdx.x];
  reinterpret_cast<float4*>(x + (size_t)row*D_)[threadIdx.x] = v;
}

// ---------------- layernorm: f32 in -> bf16 out ----------------
__global__ __launch_bounds__(256) void ln_k(const float* __restrict__ x,
    const float* __restrict__ g, const float* __restrict__ b,
    unsigned short* __restrict__ out){
  int row = blockIdx.x;
  int tid = threadIdx.x;
  float4 v = reinterpret_cast<const float4*>(x + (size_t)row*D_)[tid];
  float s = v.x+v.y+v.z+v.w;
  float ss = v.x*v.x + v.y*v.y + v.z*v.z + v.w*v.w;
  #pragma unroll
  for (int off=1; off<64; off<<=1){ s += __shfl_xor(s, off); ss += __shfl_xor(ss, off); }
  __shared__ float rs[4], rss[4];
  int wave = tid>>6, lane = tid&63;
  if (lane==0){ rs[wave]=s; rss[wave]=ss; }
  __syncthreads();
  s  = rs[0]+rs[1]+rs[2]+rs[3];
  ss = rss[0]+rss[1]+rss[2]+rss[3];
  float mean = s * (1.0f/(float)D_);
  float var  = ss * (1.0f/(float)D_) - mean*mean;
  float inv = rsqrtf(var + 1e-5f);
  float4 gg = reinterpret_cast<const float4*>(g)[tid];
  float4 bb = reinterpret_cast<const float4*>(b)[tid];
  ushort4 o;
  o.x = f2bf((v.x-mean)*inv*gg.x + bb.x);
  o.y = f2bf((v.y-mean)*inv*gg.y + bb.y);
  o.z = f2bf((v.z-mean)*inv*gg.z + bb.z);
  o.w = f2bf((v.w-mean)*inv*gg.w + bb.w);
  reinterpret_cast<ushort4*>(out + (size_t)row*D_)[tid] = o;
}

// ---------------- fused split-K reduce + residual + LN ----------------
__global__ __launch_bounds__(256) void rln_k(float* __restrict__ x,
    const float* __restrict__ part, const float* __restrict__ bias,
    const float* __restrict__ g, const float* __restrict__ b,
    unsigned short* __restrict__ out, int KS){
  int row = blockIdx.x;
  int tid = threadIdx.x;
  float4 v = reinterpret_cast<const float4*>(x + (size_t)row*D_)[tid];
  for (int z=0; z<KS; z++){
    float4 p = reinterpret_cast<const float4*>(part + (size_t)z*M_*D_ + (size_t)row*D_)[tid];
    v.x+=p.x; v.y+=p.y; v.z+=p.z; v.w+=p.w;
  }
  if (bias){
    float4 bb4 = reinterpret_cast<const float4*>(bias)[tid];
    v.x+=bb4.x; v.y+=bb4.y; v.z+=bb4.z; v.w+=bb4.w;
  }
  reinterpret_cast<float4*>(x + (size_t)row*D_)[tid] = v;
  float s = v.x+v.y+v.z+v.w;
  float ss = v.x*v.x + v.y*v.y + v.z*v.z + v.w*v.w;
  #pragma unroll
  for (int off=1; off<64; off<<=1){ s += __shfl_xor(s, off); ss += __shfl_xor(ss, off); }
  __shared__ float rs[4], rss[4];
  int wave = tid>>6, lane = tid&63;
  if (lane==0){ rs[wave]=s; rss[wave]=ss; }
  __syncthreads();
  s  = rs[0]+rs[1]+rs[2]+rs[3];
  ss = rss[0]+rss[1]+rss[2]+rss[3];
  float mean = s * (1.0f/(float)D_);
  float var  = ss * (1.0f/(float)D_) - mean*mean;
  float inv = rsqrtf(var + 1e-5f);
  float4 gg = reinterpret_cast<const float4*>(g)[tid];
  float4 bb = reinterpret_cast<const float4*>(b)[tid];
  ushort4 o;
  o.x = f2bf((v.x-mean)*inv*gg.x + bb.x);
  o.y = f2bf((v.y-mean)*inv*gg.y + bb.y);
  o.z = f2bf((v.z-mean)*inv*gg.z + bb.z);
  o.w = f2bf((v.w-mean)*inv*gg.w + bb.w);
  reinterpret_cast<ushort4*>(out + (size_t)row*D_)[tid] = o;
}

// ---------------- transpose + f32->bf16: in [K][N] -> out [N][K] ----------------
__global__ __launch_bounds__(256) void transpose_k(const float* __restrict__ in,
    unsigned short* __restrict__ out, int K, int N, size_t in_ls, size_t out_ls){
  __shared__ float t[64][65];
  const float* inp = in + (size_t)blockIdx.z*in_ls;
  unsigned short* outp = out + (size_t)blockIdx.z*out_ls;
  int k0 = blockIdx.y*64, n0 = blockIdx.x*64;
  int rr = threadIdx.x >> 4, c4 = (threadIdx.x & 15)*4;
  #pragma unroll
  for (int i=0;i<4;i++){
    float4 v = *reinterpret_cast<const float4*>(inp + (size_t)(k0+rr+i*16)*N + n0 + c4);
    t[rr+i*16][c4+0]=v.x; t[rr+i*16][c4+1]=v.y; t[rr+i*16][c4+2]=v.z; t[rr+i*16][c4+3]=v.w;
  }
  __syncthreads();
  #pragma unroll
  for (int i=0;i<4;i++){
    int n = rr + i*16;
    ushort4 o;
    o.x = f2bf(t[c4+0][n]); o.y = f2bf(t[c4+1][n]);
    o.z = f2bf(t[c4+2][n]); o.w = f2bf(t[c4+3][n]);
    *reinterpret_cast<ushort4*>(outp + (size_t)(n0+n)*K + k0 + c4) = o;
  }
}

#define VMC(n)  asm volatile("s_waitcnt vmcnt(" #n ")" ::: "memory")
#define BARW(n) do{ __builtin_amdgcn_s_barrier(); \
  asm volatile("s_waitcnt lgkmcnt(" #n ")" ::: "memory"); }while(0)
#define ENDP(TAIL) do{ TAIL; __builtin_amdgcn_s_barrier(); }while(0)

// ---------------- 128^2 double-buffered 2-phase GEMM (fallback only) ----------------
template<int EP>
__global__ __launch_bounds__(256)
void gemm_bt(const unsigned short* __restrict__ A, const unsigned short* __restrict__ B,
             void* __restrict__ C, const float* __restrict__ bias,
             const float* __restrict__ resid, int K, int ldc, int MB, int kLen){
  __shared__ unsigned short As[2][128*64];
  __shared__ unsigned short Bs[2][128*64];
  const int tid = threadIdx.x;
  const int wave = tid>>6, lane = tid&63;
  const int wm = wave>>1, wn = wave&1;
  const int nwg = gridDim.x;
  const int p = blockIdx.x;
  const int t = (nwg & 7) ? p : ((p & 7)*(nwg>>3) + (p>>3));
  const int by = t % MB, bx = t / MB;
  const int row0 = by*128, col0 = bx*128;
  const int kz = blockIdx.z;
  const int k0 = kz*kLen;
  f32x4 acc[4][4] = {};
  const int sw8 = ((lane&7) ^ ((lane>>3)&7))*8;
  const unsigned short* Ag = A + (size_t)(row0 + wave*8 + (lane>>3))*K + sw8;
  const unsigned short* Bg = B + (size_t)(col0 + wave*8 + (lane>>3))*K + sw8;
  const int r = lane&15, g16 = lane>>4;
  const int rsw = (r&7)<<4;
#define STAGE_BT(buf, kt) do{ \
    _Pragma("unroll") \
    for (int i=0;i<4;i++){ \
      gload16(Ag + (size_t)i*32*K + (kt), As[buf] + (wave*8 + i*32)*64); \
      gload16(Bg + (size_t)i*32*K + (kt), Bs[buf] + (wave*8 + i*32)*64); \
    } }while(0)
  STAGE_BT(0, k0);
  __syncthreads();
  int cur = 0;
  for (int kt=k0; kt<k0+kLen; kt+=64){
    if (kt + 64 < k0 + kLen) STAGE_BT(cur^1, kt+64);
    #pragma unroll
    for (int ks=0; ks<2; ks++){
      short8 a[4], b[4];
      #pragma unroll
      for (int m=0;m<4;m++)
        a[m] = *reinterpret_cast<const short8*>((const char*)As[cur] + (wm*64+m*16+r)*128 + ((ks*64 + g16*16) ^ rsw));
      #pragma unroll
      for (int n=0;n<4;n++)
        b[n] = *reinterpret_cast<const short8*>((const char*)Bs[cur] + (wn*64+n*16+r)*128 + ((ks*64 + g16*16) ^ rsw));
      #pragma unroll
      for (int m=0;m<4;m++)
        #pragma unroll
        for (int n=0;n<4;n++)
          acc[m][n] = __builtin_amdgcn_mfma_f32_16x16x32_bf16(a[m], b[n], acc[m][n], 0,0,0);
    }
    __syncthreads();
    cur ^= 1;
  }
  #pragma unroll
  for (int m=0;m<4;m++){
    const int row = row0 + wm*64 + m*16 + g16*4;
    #pragma unroll
    for (int n=0;n<4;n++){
      const int col = col0 + wn*64 + n*16 + r;
      #pragma unroll
      for (int j=0;j<4;j++){
        float val = acc[m][n][j];
        size_t idx = (size_t)(row+j)*ldc + col;
        if constexpr (EP==2 || EP==3) val += bias[col];
        if constexpr (EP==2) val = 0.5f*val*(1.0f + erff(val*0.70710678118f));
        if constexpr (EP==1 || EP==3) val += resid[idx];
        if constexpr (EP==0 || EP==2) ((unsigned short*)C)[idx] = f2bf(val);
        else ((float*)C)[idx] = val;
      }
    }
  }
}

// ---------------- 256^2 8-phase GEMM (head), A-fragment pipelined ----------------
#define LDA8(buf,m,ks) (*(const short8*)(lds8 + (buf)*65536 + (wm*128+(m)*16+r)*128 + (((ks)*64+g16*16)^rsw)))
#define LDB8(buf,n,ks) (*(const short8*)(lds8 + (buf)*65536 + 32768 + (wn*64+(n)*16+r)*128 + (((ks)*64+g16*16)^rsw)))
#define STG(buf,isB,h,i,tile) gload16( \
    ((isB) ? Bw + (size_t)(col0 + (h)*128 + (i)*64 + wave*8 + srow)*K + (size_t)(tile)*64 + scsw \
           : A  + (size_t)(row0 + (h)*128 + (i)*64 + wave*8 + srow)*K + (size_t)(tile)*64 + scsw), \
    lds8 + (buf)*65536 + (isB)*32768 + ((h)*128 + (i)*64 + wave*8)*128 )
#define STG_HT(buf,isB,h,tile) do{ STG(buf,isB,h,0,tile); STG(buf,isB,h,1,tile); }while(0)
#define BLOAD8(bT) do{ \
  bfr[0][0]=LDB8(bT,0,0); bfr[0][1]=LDB8(bT,0,1); bfr[1][0]=LDB8(bT,1,0); bfr[1][1]=LDB8(bT,1,1); \
  bfr[2][0]=LDB8(bT,2,0); bfr[2][1]=LDB8(bT,2,1); bfr[3][0]=LDB8(bT,3,0); bfr[3][1]=LDB8(bT,3,1); }while(0)
#define RD_A8(AR,buf,mb) do{ AR[0]=LDA8(buf,mb,0); AR[1]=LDA8(buf,mb,1); \
                             AR[2]=LDA8(buf,(mb)+1,0); AR[3]=LDA8(buf,(mb)+1,1); }while(0)
#define MM8A(mb,AR,n) do{ \
  acc[mb][n]    =__builtin_amdgcn_mfma_f32_16x16x32_bf16(AR[0],bfr[n][0],acc[mb][n],0,0,0); \
  acc[mb][n]    =__builtin_amdgcn_mfma_f32_16x16x32_bf16(AR[1],bfr[n][1],acc[mb][n],0,0,0); \
  acc[(mb)+1][n]=__builtin_amdgcn_mfma_f32_16x16x32_bf16(AR[2],bfr[n][0],acc[(mb)+1][n],0,0,0); \
  acc[(mb)+1][n]=__builtin_amdgcn_mfma_f32_16x16x32_bf16(AR[3],bfr[n][1],acc[(mb)+1][n],0,0,0); }while(0)
#define MFMA16A(mb,AR) do{ __builtin_amdgcn_s_setprio(1); \
  MM8A(mb,AR,0); MM8A(mb,AR,1); MM8A(mb,AR,2); MM8A(mb,AR,3); \
  __builtin_amdgcn_s_setprio(0); }while(0)

__global__ __launch_bounds__(512, 1)
void gemm_8ph(const unsigned short* __restrict__ A, const unsigned short* __restrict__ Bw,
              float* __restrict__ C, int K, int ldc, int MB){
  __shared__ char lds8[131072];
  const int tid = threadIdx.x;
  const int wave = tid>>6, lane = tid&63;
  const int wm = wave>>2, wn = wave&3;
  const int nwg = gridDim.x;
  const int pp = blockIdx.x;
  const int t = (nwg & 7) ? pp : ((pp & 7)*(nwg>>3) + (pp>>3));
  const int by = t % MB, bx = t / MB;
  const int row0 = by*256, col0 = bx*256;
  const int r = lane&15, g16 = lane>>4;
  const int rsw = (r&7)<<4;
  const int srow = lane>>3;
  const int scsw = ((lane&7) ^ srow)*8;

  f32x4 acc[8][4] = {};
  short8 bfr[4][2];
  short8 aA[4], aB[4];
  const int NT = K/64;

  // prologue: t0 (B+A) -> buf0; t1.B -> buf1  (drain t0's 8, leave t1.B's 4)
  STG_HT(0,1,0,0); STG_HT(0,1,1,0);
  STG_HT(0,0,0,0); STG_HT(0,0,1,0);
  STG_HT(1,1,0,1); STG_HT(1,1,1,1);
  VMC(4);
  __builtin_amdgcn_s_barrier();

  for (int T0 = 0; T0 < NT-2; T0 += 2){
    BLOAD8(0); RD_A8(aA,0,0);
    RD_A8(aB,0,2); STG_HT(1,0,0,T0+1); BARW(4); MFMA16A(0,aA); ENDP(((void)0));
    RD_A8(aA,0,4); STG_HT(1,0,1,T0+1); BARW(4); MFMA16A(2,aB); ENDP(((void)0));
    RD_A8(aB,0,6); STG_HT(0,1,0,T0+2); BARW(4); MFMA16A(4,aA); ENDP(((void)0));
    STG_HT(0,1,1,T0+2);                BARW(0); MFMA16A(6,aB); ENDP(VMC(4));
    BLOAD8(1); RD_A8(aA,1,0);
    RD_A8(aB,1,2); STG_HT(0,0,0,T0+2); BARW(4); MFMA16A(0,aA); ENDP(((void)0));
    RD_A8(aA,1,4); STG_HT(0,0,1,T0+2); BARW(4); MFMA16A(2,aB); ENDP(((void)0));
    RD_A8(aB,1,6); STG_HT(1,1,0,T0+3); BARW(4); MFMA16A(4,aA); ENDP(((void)0));
    STG_HT(1,1,1,T0+3);                BARW(0); MFMA16A(6,aB); ENDP(VMC(4));
  }
  // epilogue: tiles NT-2 (buf0), NT-1 (buf1); only t_{NT-1}.A left to stage
  BLOAD8(0); RD_A8(aA,0,0);
  RD_A8(aB,0,2); STG_HT(1,0,0,NT-1); BARW(4); MFMA16A(0,aA); ENDP(((void)0));
  RD_A8(aA,0,4); STG_HT(1,0,1,NT-1); BARW(4); MFMA16A(2,aB); ENDP(((void)0));
  RD_A8(aB,0,6);                     BARW(4); MFMA16A(4,aA); ENDP(VMC(0));
                                     BARW(0); MFMA16A(6,aB); ENDP(((void)0));
  BLOAD8(1); RD_A8(aA,1,0);
  RD_A8(aB,1,2);                     BARW(4); MFMA16A(0,aA); ENDP(((void)0));
  RD_A8(aA,1,4);                     BARW(4); MFMA16A(2,aB); ENDP(((void)0));
  RD_A8(aB,1,6);                     BARW(4); MFMA16A(4,aA); ENDP(((void)0));
                                     BARW(0); MFMA16A(6,aB);

  #pragma unroll
  for (int m=0;m<8;m++){
    const int row = row0 + wm*128 + m*16 + g16*4;
    #pragma unroll
    for (int n=0;n<4;n++){
      const int col = col0 + wn*64 + n*16 + r;
      #pragma unroll
      for (int j=0;j<4;j++)
        C[(size_t)(row+j)*ldc + col] = acc[m][n][j];
    }
  }
}

// ---------------- 128x256 4-phase GEMM (FF1), A-fragment pipelined ----------------
#define L4A(buf,m,ks) (*(const short8*)(lds4 + (buf)*49152 + (wm*64+(m)*16+r)*128 + (((ks)*64+g16*16)^rsw)))
#define L4B(buf,n,ks) (*(const short8*)(lds4 + (buf)*49152 + 16384 + (wn*64+(n)*16+r)*128 + (((ks)*64+g16*16)^rsw)))
#define STG4A(buf,tile) do{ \
  gload16(A4 + (size_t)(row0 + 0*64 + wave*8 + srow)*K + (size_t)(tile)*64 + scsw, lds4 + (buf)*49152 + (0*64+wave*8)*128); \
  gload16(A4 + (size_t)(row0 + 1*64 + wave*8 + srow)*K + (size_t)(tile)*64 + scsw, lds4 + (buf)*49152 + (1*64+wave*8)*128); }while(0)
#define STG4B(buf,tile) do{ \
  gload16(B4 + (size_t)(col0 + 0*64 + wave*8 + srow)*K + (size_t)(tile)*64 + scsw, lds4 + (buf)*49152 + 16384 + (0*64+wave*8)*128); \
  gload16(B4 + (size_t)(col0 + 1*64 + wave*8 + srow)*K + (size_t)(tile)*64 + scsw, lds4 + (buf)*49152 + 16384 + (1*64+wave*8)*128); \
  gload16(B4 + (size_t)(col0 + 2*64 + wave*8 + srow)*K + (size_t)(tile)*64 + scsw, lds4 + (buf)*49152 + 16384 + (2*64+wave*8)*128); \
  gload16(B4 + (size_t)(col0 + 3*64 + wave*8 + srow)*K + (size_t)(tile)*64 + scsw, lds4 + (buf)*49152 + 16384 + (3*64+wave*8)*128); }while(0)
#define BLOAD4(bT) do{ \
  bfr4[0][0]=L4B(bT,0,0); bfr4[0][1]=L4B(bT,0,1); bfr4[1][0]=L4B(bT,1,0); bfr4[1][1]=L4B(bT,1,1); \
  bfr4[2][0]=L4B(bT,2,0); bfr4[2][1]=L4B(bT,2,1); bfr4[3][0]=L4B(bT,3,0); bfr4[3][1]=L4B(bT,3,1); }while(0)
#define RD_A4(AR,buf,mb) do{ AR[0]=L4A(buf,mb,0); AR[1]=L4A(buf,mb,1); \
                             AR[2]=L4A(buf,(mb)+1,0); AR[3]=L4A(buf,(mb)+1,1); }while(0)
#define MM44A(mb,AR,n) do{ \
  acc[mb][n]    =__builtin_amdgcn_mfma_f32_16x16x32_bf16(AR[0],bfr4[n][0],acc[mb][n],0,0,0); \
  acc[mb][n]    =__builtin_amdgcn_mfma_f32_16x16x32_bf16(AR[1],bfr4[n][1],acc[mb][n],0,0,0); \
  acc[(mb)+1][n]=__builtin_amdgcn_mfma_f32_16x16x32_bf16(AR[2],bfr4[n][0],acc[(mb)+1][n],0,0,0); \
  acc[(mb)+1][n]=__builtin_amdgcn_mfma_f32_16x16x32_bf16(AR[3],bfr4[n][1],acc[(mb)+1][n],0,0,0); }while(0)
#define MFMA16A4(mb,AR) do{ __builtin_amdgcn_s_setprio(1); \
  MM44A(mb,AR,0); MM44A(mb,AR,1); MM44A(mb,AR,2); MM44A(mb,AR,3); \
  __builtin_amdgcn_s_setprio(0); }while(0)

template<int EP>
__global__ __launch_bounds__(512, 1)
void gemm_4ph(const unsigned short* __restrict__ A, const unsigned short* __restrict__ Bw,
              void* __restrict__ C, const float* __restrict__ bias,
              int K, int ldc, int MB, int kLen){
  __shared__ char lds4[98304];
  const int tid = threadIdx.x;
  const int wave = tid>>6, lane = tid&63;
  const int wm = wave>>2, wn = wave&3;
  const int nwg = gridDim.x;
  const int pp = blockIdx.x;
  const int t = (nwg & 7) ? pp : ((pp & 7)*(nwg>>3) + (pp>>3));
  const int by = t % MB, bx = t / MB;
  const int row0 = by*128, col0 = bx*256;
  const int r = lane&15, g16 = lane>>4;
  const int rsw = (r&7)<<4;
  const int srow = lane>>3;
  const int scsw = ((lane&7) ^ srow)*8;
  const int kz = blockIdx.z;
  const unsigned short* A4 = A + (size_t)kz*kLen;
  const unsigned short* B4 = Bw + (size_t)kz*kLen;

  f32x4 acc[4][4] = {};
  short8 bfr4[4][2];
  short8 aA[4], aB[4];
  const int NT = kLen/64;

  STG4B(0,0); STG4A(0,0); STG4B(1,1);
  VMC(4);
  __builtin_amdgcn_s_barrier();

  for (int T0 = 0; T0 < NT-2; T0 += 2){
    BLOAD4(0); RD_A4(aA,0,0);
    RD_A4(aB,0,2); STG4A(1,T0+1); BARW(4); MFMA16A4(0,aA); ENDP(((void)0));
    STG4B(0,T0+2);                BARW(0); MFMA16A4(2,aB); ENDP(VMC(4));
    BLOAD4(1); RD_A4(aA,1,0);
    RD_A4(aB,1,2); STG4A(0,T0+2); BARW(4); MFMA16A4(0,aA); ENDP(((void)0));
    STG4B(1,T0+3);                BARW(0); MFMA16A4(2,aB); ENDP(VMC(4));
  }
  BLOAD4(0); RD_A4(aA,0,0);
  RD_A4(aB,0,2); STG4A(1,NT-1);   BARW(4); MFMA16A4(0,aA); ENDP(((void)0));
                                  BARW(0); MFMA16A4(2,aB); ENDP(VMC(0));
  BLOAD4(1); RD_A4(aA,1,0);
  RD_A4(aB,1,2);                  BARW(4); MFMA16A4(0,aA); ENDP(((void)0));
                                  BARW(0); MFMA16A4(2,aB);

  float* Cp5 = (float*)C + (size_t)kz*M_*ldc;
  #pragma unroll
  for (int m=0;m<4;m++){
    const int row = row0 + wm*64 + m*16 + g16*4;
    #pragma unroll
    for (int n=0;n<4;n++){
      const int col = col0 + wn*64 + n*16 + r;
      #pragma unroll
      for (int j=0;j<4;j++){
        float val = acc[m][n][j];
        size_t idx = (size_t)(row+j)*ldc + col;
        if constexpr (EP==2) { val += bias[col]; val = 0.5f*val*(1.0f + erff(val*0.70710678118f)); }
        if constexpr (EP==0 || EP==2) ((unsigned short*)C)[idx] = f2bf(val);
        else Cp5[idx] = val;
      }
    }
  }
}

// ---------------- 64x256 4-phase GEMM (QKV / split-K), A-fragment pipelined ----------------
#define L6A(buf,m,ks) (*(const short8*)(lds6 + (buf)*40960 + (wm*32+(m)*16+r)*128 + (((ks)*64+g16*16)^rsw)))
#define L6B(buf,n,ks) (*(const short8*)(lds6 + (buf)*40960 + 8192 + (wn*64+(n)*16+r)*128 + (((ks)*64+g16*16)^rsw)))
#define STG6A(buf,tile) \
  gload16(A6 + (size_t)(row0 + wave*8 + srow)*K + (size_t)(tile)*64 + scsw, lds6 + (buf)*40960 + (wave*8)*128)
#define STG6B(buf,tile) do{ \
  gload16(B6 + (size_t)(col0 + 0*64 + wave*8 + srow)*K + (size_t)(tile)*64 + scsw, lds6 + (buf)*40960 + 8192 + (0*64+wave*8)*128); \
  gload16(B6 + (size_t)(col0 + 1*64 + wave*8 + srow)*K + (size_t)(tile)*64 + scsw, lds6 + (buf)*40960 + 8192 + (1*64+wave*8)*128); \
  gload16(B6 + (size_t)(col0 + 2*64 + wave*8 + srow)*K + (size_t)(tile)*64 + scsw, lds6 + (buf)*40960 + 8192 + (2*64+wave*8)*128); \
  gload16(B6 + (size_t)(col0 + 3*64 + wave*8 + srow)*K + (size_t)(tile)*64 + scsw, lds6 + (buf)*40960 + 8192 + (3*64+wave*8)*128); }while(0)
#define BLOAD6(bT) do{ \
  bfr6[0][0]=L6B(bT,0,0); bfr6[0][1]=L6B(bT,0,1); bfr6[1][0]=L6B(bT,1,0); bfr6[1][1]=L6B(bT,1,1); \
  bfr6[2][0]=L6B(bT,2,0); bfr6[2][1]=L6B(bT,2,1); bfr6[3][0]=L6B(bT,3,0); bfr6[3][1]=L6B(bT,3,1); }while(0)
#define RD_A6(AR,buf,mb) do{ AR[0]=L6A(buf,mb,0); AR[1]=L6A(buf,mb,1); }while(0)
#define MFMA8A6(mb,AR) do{ __builtin_amdgcn_s_setprio(1); \
  _Pragma("unroll") \
  for (int n=0;n<4;n++){ \
    acc[mb][n]=__builtin_amdgcn_mfma_f32_16x16x32_bf16(AR[0],bfr6[n][0],acc[mb][n],0,0,0); \
    acc[mb][n]=__builtin_amdgcn_mfma_f32_16x16x32_bf16(AR[1],bfr6[n][1],acc[mb][n],0,0,0); \
  } \
  __builtin_amdgcn_s_setprio(0); }while(0)

template<int EP>
__global__ __launch_bounds__(512, 2)
void gemm_4ph64(const unsigned short* __restrict__ A, const unsigned short* __restrict__ Bw,
                void* __restrict__ C, const float* __restrict__ bias,
                int K, int ldc, int MB, int kLen){
  __shared__ char lds6[81920];
  const int tid = threadIdx.x;
  const int wave = tid>>6, lane = tid&63;
  const int wm = wave>>2, wn = wave&3;
  const int nwg = gridDim.x;
  const int pp = blockIdx.x;
  const int t = (nwg & 7) ? pp : ((pp & 7)*(nwg>>3) + (pp>>3));
  const int by = t % MB, bx = t / MB;
  const int row0 = by*64, col0 = bx*256;
  const int r = lane&15, g16 = lane>>4;
  const int rsw = (r&7)<<4;
  const int srow = lane>>3;
  const int scsw = ((lane&7) ^ srow)*8;
  const int kz = blockIdx.z;
  const unsigned short* A6 = A + (size_t)kz*kLen;
  const unsigned short* B6 = Bw + (size_t)kz*kLen;

  f32x4 acc[2][4] = {};
  short8 bfr6[4][2];
  short8 aA[2], aB[2];
  const int NT = kLen/64;

  STG6B(0,0); STG6A(0,0); STG6B(1,1);
  VMC(4);
  __builtin_amdgcn_s_barrier();

  for (int T0 = 0; T0 < NT-2; T0 += 2){
    BLOAD6(0); RD_A6(aA,0,0);
    RD_A6(aB,0,1); STG6A(1,T0+1); BARW(2); MFMA8A6(0,aA); ENDP(((void)0));
    STG6B(0,T0+2);                BARW(0); MFMA8A6(1,aB); ENDP(VMC(4));
    BLOAD6(1); RD_A6(aA,1,0);
    RD_A6(aB,1,1); STG6A(0,T0+2); BARW(2); MFMA8A6(0,aA); ENDP(((void)0));
    STG6B(1,T0+3);                BARW(0); MFMA8A6(1,aB); ENDP(VMC(4));
  }
  BLOAD6(0); RD_A6(aA,0,0);
  RD_A6(aB,0,1); STG6A(1,NT-1);   BARW(2); MFMA8A6(0,aA); ENDP(((void)0));
                                  BARW(0); MFMA8A6(1,aB); ENDP(VMC(0));
  BLOAD6(1); RD_A6(aA,1,0);
  RD_A6(aB,1,1);                  BARW(2); MFMA8A6(0,aA); ENDP(((void)0));
                                  BARW(0); MFMA8A6(1,aB);

  float* Cp5 = (float*)C + (size_t)kz*M_*ldc;
  #pragma unroll
  for (int m=0;m<2;m++){
    const int row = row0 + wm*32 + m*16 + g16*4;
    #pragma unroll
    for (int n=0;n<4;n++){
      const int col = col0 + wn*64 + n*16 + r;
      #pragma unroll
      for (int j=0;j<4;j++){
        float val = acc[m][n][j];
        size_t idx = (size_t)(row+j)*ldc + col;
        if constexpr (EP==2) { val += bias[col]; val = 0.5f*val*(1.0f + erff(val*0.70710678118f)); }
        if constexpr (EP==0 || EP==2) ((unsigned short*)C)[idx] = f2bf(val);
        else Cp5[idx] = val;
      }
    }
  }
}

// ---------------- fused causal attention (flash-style, pipelined staging) ----------------
__global__ __launch_bounds__(256)
void attn_k(const unsigned short* __restrict__ qkv, unsigned short* __restrict__ o){
  __shared__ unsigned short Ks[2][64*64];
  __shared__ unsigned short Vt[2][64*64];
  __shared__ unsigned short Ps[4*16*64];
  const int tid = threadIdx.x;
  const int wave = tid>>6, lane = tid&63;
  const int qb = blockIdx.x, h = blockIdx.y, b = blockIdx.z;
  const int r = lane&15, g = lane>>4;
  const size_t rowbase = (size_t)b*S_*3*D_;
  const unsigned short* kbase = qkv + rowbase + D_ + h*64;
  const unsigned short* vbase = qkv + rowbase + 2*D_ + h*64;
  short8 qf[2];
  {
    const unsigned short* qp = qkv + rowbase + (size_t)(qb*64 + wave*16 + r)*(3*D_) + h*64 + g*8;
    short8 q0 = *reinterpret_cast<const short8*>(qp);
    short8 q1 = *reinterpret_cast<const short8*>(qp + 32);
    #pragma unroll
    for (int j=0;j<8;j++){
      qf[0][j] = (short)f2bf(bf2f((unsigned short)q0[j])*0.125f);
      qf[1][j] = (short)f2bf(bf2f((unsigned short)q1[j])*0.125f);
    }
  }
  float mrow[4] = {-INFINITY,-INFINITY,-INFINITY,-INFINITY};
  float lrow[4] = {0.f,0.f,0.f,0.f};
  f32x4 oacc[4] = {};
  const int qglob0 = qb*64 + wave*16 + g*4;
  unsigned short* Pw = Ps + wave*16*64;
  uint4 vdr[2];

  const int key8 = tid>>3;
  const int c8   = (tid&7)*8;
  const int kcsw = ((tid&7) ^ (key8&7))*16;

#define KSTG_A(nxt, kt2) do{ \
  gload16((const char*)(kbase + (size_t)((kt2)*64+key8)*(3*D_)) + kcsw, (char*)Ks[nxt] + wave*1024); \
  gload16((const char*)(kbase + (size_t)((kt2)*64+32+key8)*(3*D_)) + kcsw, (char*)Ks[nxt] + 4096 + wave*1024); \
}while(0)
#define VLOAD_A(kt2) do{ \
  vdr[0] = *reinterpret_cast<const uint4*>(vbase + (size_t)((kt2)*64+key8)*(3*D_) + c8); \
  vdr[1] = *reinterpret_cast<const uint4*>(vbase + (size_t)((kt2)*64+32+key8)*(3*D_) + c8); \
}while(0)
#define VSTORE_A(nxt) do{ \
  _Pragma("unroll") \
  for (int i=0;i<2;i++){ \
    int key = i*32 + key8; \
    const unsigned short* ve = reinterpret_cast<const unsigned short*>(&vdr[i]); \
    _Pragma("unroll") \
    for (int j=0;j<8;j++){ \
      int d = c8 + j; \
      int bo2 = (d*128 + key*2) ^ ((d&7)<<4); \
      *reinterpret_cast<unsigned short*>((char*)Vt[nxt] + bo2) = ve[j]; \
    } \
  } }while(0)

  KSTG_A(0, 0);
  VLOAD_A(0);
  VMC(0);
  VSTORE_A(0);
  __syncthreads();

  int cur = 0;
  for (int kt=0; kt<=qb; kt++){
    const bool pf = (kt < qb);
    if (pf){ KSTG_A(cur^1, kt+1); VLOAD_A(kt+1); }
    f32x4 sacc[4] = {};
    #pragma unroll
    for (int ks=0; ks<2; ks++){
      #pragma unroll
      for (int nb=0; nb<4; nb++){
        int key = nb*16 + r;
        int bo = (key*128 + (ks*32+g*8)*2) ^ ((key&7)<<4);
        short8 kf = *reinterpret_cast<const short8*>((char*)Ks[cur] + bo);
        sacc[nb] = __builtin_amdgcn_mfma_f32_16x16x32_bf16(qf[ks], kf, sacc[nb], 0,0,0);
      }
    }
    float sv[4][4];
    float tm[4] = {-INFINITY,-INFINITY,-INFINITY,-INFINITY};
    if (kt == qb){
      #pragma unroll
      for (int nb=0; nb<4; nb++){
        int key = kt*64 + nb*16 + r;
        #pragma unroll
        for (int j=0;j<4;j++){
          float s = (key <= qglob0 + j) ? sacc[nb][j] : -INFINITY;
          sv[nb][j] = s;
          tm[j] = fmaxf(tm[j], s);
        }
      }
    } else {
      #pragma unroll
      for (int nb=0; nb<4; nb++)
        #pragma unroll
        for (int j=0;j<4;j++){
          float s = sacc[nb][j];
          sv[nb][j] = s;
          tm[j] = fmaxf(tm[j], s);
        }
    }
    #pragma unroll
    for (int off=1; off<16; off<<=1){
      #pragma unroll
      for (int j=0;j<4;j++) tm[j] = fmaxf(tm[j], __shfl_xor(tm[j], off));
    }
    int chg = 0;
    float mn[4];
    #pragma unroll
    for (int j=0;j<4;j++){ mn[j] = fmaxf(mrow[j], tm[j]); chg |= (mn[j] > mrow[j]); }
    if (__any(chg)){
      #pragma unroll
      for (int j=0;j<4;j++){
        float sf = __expf(mrow[j]-mn[j]);
        mrow[j] = mn[j];
        lrow[j] *= sf;
        #pragma unroll
        for (int nb=0;nb<4;nb++) oacc[nb][j] *= sf;
      }
    }
    float psum[4] = {0.f,0.f,0.f,0.f};
    #pragma unroll
    for (int nb=0; nb<4; nb++){
      #pragma unroll
      for (int j=0;j<4;j++){
        float p = __expf(sv[nb][j]-mrow[j]);
        psum[j] += p;
        int prow = g*4+j;
        int bo = (prow*128 + (nb*16+r)*2) ^ ((prow&7)<<4);
        *reinterpret_cast<unsigned short*>((char*)Pw + bo) = f2bf(p);
      }
    }
    #pragma unroll
    for (int off=1; off<16; off<<=1){
      #pragma unroll
      for (int j=0;j<4;j++) psum[j] += __shfl_xor(psum[j], off);
    }
    #pragma unroll
    for (int j=0;j<4;j++) lrow[j] += psum[j];
    asm volatile("s_waitcnt lgkmcnt(0)" ::: "memory");
    #pragma unroll
    for (int ks=0; ks<2; ks++){
      int bo = (r*128 + (ks*32+g*8)*2) ^ ((r&7)<<4);
      short8 pf8 = *reinterpret_cast<const short8*>((char*)Pw + bo);
      #pragma unroll
      for (int nb=0; nb<4; nb++){
        int d = nb*16 + r;
        int bo2 = (d*128 + (ks*32+g*8)*2) ^ ((d&7)<<4);
        short8 vf = *reinterpret_cast<const short8*>((char*)Vt[cur] + bo2);
        oacc[nb] = __builtin_amdgcn_mfma_f32_16x16x32_bf16(pf8, vf, oacc[nb], 0,0,0);
      }
    }
    if (pf){ VMC(0); VSTORE_A(cur^1); }
    __syncthreads();
    cur ^= 1;
  }
  #pragma unroll
  for (int nb=0; nb<4; nb++){
    #pragma unroll
    for (int j=0;j<4;j++){
      float ov = oacc[nb][j] / lrow[j];
      size_t row = (size_t)b*S_ + qb*64 + wave*16 + g*4 + j;
      o[row*D_ + h*64 + nb*16 + r] = f2bf(ov);
    }
  }
}

extern "C" void kernel_launch(void* const* d_in, const int* in_sizes, int n_in,
                              void* d_out, int out_size, void* d_ws, size_t ws_size,
                              hipStream_t stream) {
  const int*   ids   = (const int*)  d_in[0];
  const float* emb   = (const float*)d_in[1];
  const float* Wq    = (const float*)d_in[2];
  const float* Wk    = (const float*)d_in[3];
  const float* Wv    = (const float*)d_in[4];
  const float* Wo    = (const float*)d_in[5];
  const float* W1    = (const float*)d_in[6];
  const float* b1    = (const float*)d_in[7];
  const float* W2    = (const float*)d_in[8];
  const float* b2    = (const float*)d_in[9];
  const float* ln1_g = (const float*)d_in[10];
  const float* ln1_b = (const float*)d_in[11];
  const float* ln2_g = (const float*)d_in[12];
  const float* ln2_b = (const float*)d_in[13];
  const float* lnf_g = (const float*)d_in[14];
  const float* lnf_b = (const float*)d_in[15];
  const float* headw = (const float*)d_in[16];

  unsigned short* ws = (unsigned short*)d_ws;
  unsigned short* wqkvT = ws;                                   // L*3*D*D
  unsigned short* woT   = wqkvT + (size_t)L_*3*D_*D_;           // L*D*D
  unsigned short* w1T   = woT   + (size_t)L_*D_*D_;             // L*DF*D
  unsigned short* w2T   = w1T   + (size_t)L_*D_*DF_;            // L*D*DF
  unsigned short* headT = w2T   + (size_t)L_*D_*DF_;            // V*D
  unsigned short* h     = headT + (size_t)V_*D_;                // M*D
  unsigned short* qkv   = h     + (size_t)M_*D_;                // M*3D
  unsigned short* attno = qkv   + (size_t)M_*3*D_;              // M*D
  unsigned short* h2    = attno + (size_t)M_*D_;                // M*DF
  float*          x     = (float*)(h2 + (size_t)M_*DF_);        // M*D f32
  float*          part  = x + (size_t)M_*D_;                    // 2*M*D f32 (KS=2)
  size_t needed = ((char*)(part + (size_t)2*M_*D_)) - (char*)d_ws;
  const bool splitk = (ws_size >= needed);

  // ---- weight prep ----
  transpose_k<<<dim3(D_/64, D_/64, L_), 256, 0, stream>>>(Wq, wqkvT,            D_, D_, (size_t)D_*D_, (size_t)3*D_*D_);
  transpose_k<<<dim3(D_/64, D_/64, L_), 256, 0, stream>>>(Wk, wqkvT + D_*D_,    D_, D_, (size_t)D_*D_, (size_t)3*D_*D_);
  transpose_k<<<dim3(D_/64, D_/64, L_), 256, 0, stream>>>(Wv, wqkvT + 2*D_*D_,  D_, D_, (size_t)D_*D_, (size_t)3*D_*D_);
  transpose_k<<<dim3(D_/64, D_/64, L_), 256, 0, stream>>>(Wo, woT,              D_, D_, (size_t)D_*D_, (size_t)D_*D_);
  transpose_k<<<dim3(DF_/64, D_/64, L_), 256, 0, stream>>>(W1, w1T,             D_, DF_, (size_t)D_*DF_, (size_t)D_*DF_);
  transpose_k<<<dim3(D_/64, DF_/64, L_), 256, 0, stream>>>(W2, w2T,             DF_, D_, (size_t)D_*DF_, (size_t)D_*DF_);
  transpose_k<<<dim3(V_/64, D_/64, 1), 256, 0, stream>>>(headw, headT,          D_, V_, 0, 0);

  // ---- embed + first LN ----
  embed_k<<<M_, 256, 0, stream>>>(ids, emb, x);
  ln_k<<<M_, 256, 0, stream>>>(x, ln1_g, ln1_b, h);

  // ---- layers (h holds ln1(x) entering each layer) ----
  for (int l = 0; l < L_; l++){
    gemm_4ph64<0><<<dim3((3*D_/256)*(M_/64), 1, 1), 512, 0, stream>>>(h, wqkvT + (size_t)l*3*D_*D_, qkv, nullptr, D_, 3*D_, M_/64, D_);
    attn_k<<<dim3(S_/64, H_, B_), 256, 0, stream>>>(qkv, attno);
    if (splitk){
      gemm_4ph64<5><<<dim3((D_/256)*(M_/64), 1, 2), 512, 0, stream>>>(attno, woT + (size_t)l*D_*D_, part, nullptr, D_, D_, M_/64, D_/2);
      rln_k<<<M_, 256, 0, stream>>>(x, part, nullptr, ln2_g + l*D_, ln2_b + l*D_, h, 2);
    } else {
      gemm_bt<1><<<dim3((D_/128)*(M_/128), 1, 1), 256, 0, stream>>>(attno, woT + (size_t)l*D_*D_, x, nullptr, x, D_, D_, M_/128, D_);
      ln_k<<<M_, 256, 0, stream>>>(x, ln2_g + l*D_, ln2_b + l*D_, h);
    }
    gemm_4ph<2><<<dim3((DF_/256)*(M_/128), 1, 1), 512, 0, stream>>>(h, w1T + (size_t)l*D_*DF_, h2, b1 + l*DF_, D_, DF_, M_/128, D_);
    const float* ng = (l+1 < L_) ? (ln1_g + (l+1)*D_) : lnf_g;
    const float* nb = (l+1 < L_) ? (ln1_b + (l+1)*D_) : lnf_b;
    if (splitk){
      gemm_4ph64<5><<<dim3((D_/256)*(M_/64), 1, 2), 512, 0, stream>>>(h2, w2T + (size_t)l*D_*DF_, part, nullptr, DF_, D_, M_/64, DF_/2);
      rln_k<<<M_, 256, 0, stream>>>(x, part, b2 + l*D_, ng, nb, h, 2);
    } else {
      gemm_bt<3><<<dim3((D_/128)*(M_/128), 1, 1), 256, 0, stream>>>(h2, w2T + (size_t)l*D_*DF_, x, b2 + l*D_, x, DF_, D_, M_/128, DF_);
      ln_k<<<M_, 256, 0, stream>>>(x, ng, nb, h);
    }
  }

  // ---- head GEMM (h = lnf(x) already) ----
  gemm_8ph<<<dim3((V_/256)*(M_/256), 1, 1), 512, 0, stream>>>(h, headT, (float*)d_out, D_, V_, M_/256);
}

// Round 11
// 904.663 us; speedup vs baseline: 1.0173x; 1.0173x over previous
//
#include <hip/hip_runtime.h>
#include <stdint.h>

// Transformer prefill: B=2,S=1024,V=32000,D=1024,H=16,L=4,DK=64,DF=4096
#define B_ 2
#define S_ 1024
#define V_ 32000
#define D_ 1024
#define H_ 16
#define L_ 4
#define DF_ 4096
#define M_ (B_*S_)

typedef short short8 __attribute__((ext_vector_type(8)));
typedef float f32x4 __attribute__((ext_vector_type(4)));

__device__ __forceinline__ unsigned short f2bf(float f){
  union { float f; unsigned int u; } v; v.f = f;
  unsigned int u = v.u;
  u = u + 0x7fffu + ((u >> 16) & 1u);
  return (unsigned short)(u >> 16);
}

__device__ __forceinline__ float bf2f(unsigned short u){
  union { unsigned int u; float f; } v; v.u = ((unsigned int)u) << 16;
  return v.f;
}

__device__ __forceinline__ void gload16(const void* g, void* l){
  __builtin_amdgcn_global_load_lds(
      (__attribute__((address_space(1))) void*)(uintptr_t)g,
      (__attribute__((address_space(3))) void*)(uintptr_t)l, 16, 0, 0);
}

// ---------------- embed gather ----------------
__global__ __launch_bounds__(256) void embed_k(const int* __restrict__ ids,
    const float* __restrict__ emb, float* __restrict__ x){
  int row = blockIdx.x;
  int id = ids[row];
  float4 v = reinterpret_cast<const float4*>(emb + (size_t)id*D_)[threadIdx.x];
  reinterpret_cast<float4*>(x + (size_t)row*D_)[threadIdx.x] = v;
}

// ---------------- layernorm: f32 in -> bf16 out ----------------
__global__ __launch_bounds__(256) void ln_k(const float* __restrict__ x,
    const float* __restrict__ g, const float* __restrict__ b,
    unsigned short* __restrict__ out){
  int row = blockIdx.x;
  int tid = threadIdx.x;
  float4 v = reinterpret_cast<const float4*>(x + (size_t)row*D_)[tid];
  float s = v.x+v.y+v.z+v.w;
  float ss = v.x*v.x + v.y*v.y + v.z*v.z + v.w*v.w;
  #pragma unroll
  for (int off=1; off<64; off<<=1){ s += __shfl_xor(s, off); ss += __shfl_xor(ss, off); }
  __shared__ float rs[4], rss[4];
  int wave = tid>>6, lane = tid&63;
  if (lane==0){ rs[wave]=s; rss[wave]=ss; }
  __syncthreads();
  s  = rs[0]+rs[1]+rs[2]+rs[3];
  ss = rss[0]+rss[1]+rss[2]+rss[3];
  float mean = s * (1.0f/(float)D_);
  float var  = ss * (1.0f/(float)D_) - mean*mean;
  float inv = rsqrtf(var + 1e-5f);
  float4 gg = reinterpret_cast<const float4*>(g)[tid];
  float4 bb = reinterpret_cast<const float4*>(b)[tid];
  ushort4 o;
  o.x = f2bf((v.x-mean)*inv*gg.x + bb.x);
  o.y = f2bf((v.y-mean)*inv*gg.y + bb.y);
  o.z = f2bf((v.z-mean)*inv*gg.z + bb.z);
  o.w = f2bf((v.w-mean)*inv*gg.w + bb.w);
  reinterpret_cast<ushort4*>(out + (size_t)row*D_)[tid] = o;
}

// ---------------- fused split-K reduce + residual + LN ----------------
__global__ __launch_bounds__(256) void rln_k(float* __restrict__ x,
    const float* __restrict__ part, const float* __restrict__ bias,
    const float* __restrict__ g, const float* __restrict__ b,
    unsigned short* __restrict__ out, int KS){
  int row = blockIdx.x;
  int tid = threadIdx.x;
  float4 v = reinterpret_cast<const float4*>(x + (size_t)row*D_)[tid];
  for (int z=0; z<KS; z++){
    float4 p = reinterpret_cast<const float4*>(part + (size_t)z*M_*D_ + (size_t)row*D_)[tid];
    v.x+=p.x; v.y+=p.y; v.z+=p.z; v.w+=p.w;
  }
  if (bias){
    float4 bb4 = reinterpret_cast<const float4*>(bias)[tid];
    v.x+=bb4.x; v.y+=bb4.y; v.z+=bb4.z; v.w+=bb4.w;
  }
  reinterpret_cast<float4*>(x + (size_t)row*D_)[tid] = v;
  float s = v.x+v.y+v.z+v.w;
  float ss = v.x*v.x + v.y*v.y + v.z*v.z + v.w*v.w;
  #pragma unroll
  for (int off=1; off<64; off<<=1){ s += __shfl_xor(s, off); ss += __shfl_xor(ss, off); }
  __shared__ float rs[4], rss[4];
  int wave = tid>>6, lane = tid&63;
  if (lane==0){ rs[wave]=s; rss[wave]=ss; }
  __syncthreads();
  s  = rs[0]+rs[1]+rs[2]+rs[3];
  ss = rss[0]+rss[1]+rss[2]+rss[3];
  float mean = s * (1.0f/(float)D_);
  float var  = ss * (1.0f/(float)D_) - mean*mean;
  float inv = rsqrtf(var + 1e-5f);
  float4 gg = reinterpret_cast<const float4*>(g)[tid];
  float4 bb = reinterpret_cast<const float4*>(b)[tid];
  ushort4 o;
  o.x = f2bf((v.x-mean)*inv*gg.x + bb.x);
  o.y = f2bf((v.y-mean)*inv*gg.y + bb.y);
  o.z = f2bf((v.z-mean)*inv*gg.z + bb.z);
  o.w = f2bf((v.w-mean)*inv*gg.w + bb.w);
  reinterpret_cast<ushort4*>(out + (size_t)row*D_)[tid] = o;
}

// ---------------- transpose + f32->bf16: in [K][N] -> out [N][K] ----------------
__global__ __launch_bounds__(256) void transpose_k(const float* __restrict__ in,
    unsigned short* __restrict__ out, int K, int N, size_t in_ls, size_t out_ls){
  __shared__ float t[64][65];
  const float* inp = in + (size_t)blockIdx.z*in_ls;
  unsigned short* outp = out + (size_t)blockIdx.z*out_ls;
  int k0 = blockIdx.y*64, n0 = blockIdx.x*64;
  int rr = threadIdx.x >> 4, c4 = (threadIdx.x & 15)*4;
  #pragma unroll
  for (int i=0;i<4;i++){
    float4 v = *reinterpret_cast<const float4*>(inp + (size_t)(k0+rr+i*16)*N + n0 + c4);
    t[rr+i*16][c4+0]=v.x; t[rr+i*16][c4+1]=v.y; t[rr+i*16][c4+2]=v.z; t[rr+i*16][c4+3]=v.w;
  }
  __syncthreads();
  #pragma unroll
  for (int i=0;i<4;i++){
    int n = rr + i*16;
    ushort4 o;
    o.x = f2bf(t[c4+0][n]); o.y = f2bf(t[c4+1][n]);
    o.z = f2bf(t[c4+2][n]); o.w = f2bf(t[c4+3][n]);
    *reinterpret_cast<ushort4*>(outp + (size_t)(n0+n)*K + k0 + c4) = o;
  }
}

#define VMC(n)  asm volatile("s_waitcnt vmcnt(" #n ")" ::: "memory")

// ---------------- 128^2 double-buffered 2-phase GEMM (fallback only) ----------------
template<int EP>
__global__ __launch_bounds__(256)
void gemm_bt(const unsigned short* __restrict__ A, const unsigned short* __restrict__ B,
             void* __restrict__ C, const float* __restrict__ bias,
             const float* __restrict__ resid, int K, int ldc, int MB, int kLen){
  __shared__ unsigned short As[2][128*64];
  __shared__ unsigned short Bs[2][128*64];
  const int tid = threadIdx.x;
  const int wave = tid>>6, lane = tid&63;
  const int wm = wave>>1, wn = wave&1;
  const int nwg = gridDim.x;
  const int p = blockIdx.x;
  const int t = (nwg & 7) ? p : ((p & 7)*(nwg>>3) + (p>>3));
  const int by = t % MB, bx = t / MB;
  const int row0 = by*128, col0 = bx*128;
  const int kz = blockIdx.z;
  const int k0 = kz*kLen;
  f32x4 acc[4][4] = {};
  const int sw8 = ((lane&7) ^ ((lane>>3)&7))*8;
  const unsigned short* Ag = A + (size_t)(row0 + wave*8 + (lane>>3))*K + sw8;
  const unsigned short* Bg = B + (size_t)(col0 + wave*8 + (lane>>3))*K + sw8;
  const int r = lane&15, g16 = lane>>4;
  const int rsw = (r&7)<<4;
#define STAGE_BT(buf, kt) do{ \
    _Pragma("unroll") \
    for (int i=0;i<4;i++){ \
      gload16(Ag + (size_t)i*32*K + (kt), As[buf] + (wave*8 + i*32)*64); \
      gload16(Bg + (size_t)i*32*K + (kt), Bs[buf] + (wave*8 + i*32)*64); \
    } }while(0)
  STAGE_BT(0, k0);
  __syncthreads();
  int cur = 0;
  for (int kt=k0; kt<k0+kLen; kt+=64){
    if (kt + 64 < k0 + kLen) STAGE_BT(cur^1, kt+64);
    #pragma unroll
    for (int ks=0; ks<2; ks++){
      short8 a[4], b[4];
      #pragma unroll
      for (int m=0;m<4;m++)
        a[m] = *reinterpret_cast<const short8*>((const char*)As[cur] + (wm*64+m*16+r)*128 + ((ks*64 + g16*16) ^ rsw));
      #pragma unroll
      for (int n=0;n<4;n++)
        b[n] = *reinterpret_cast<const short8*>((const char*)Bs[cur] + (wn*64+n*16+r)*128 + ((ks*64 + g16*16) ^ rsw));
      #pragma unroll
      for (int m=0;m<4;m++)
        #pragma unroll
        for (int n=0;n<4;n++)
          acc[m][n] = __builtin_amdgcn_mfma_f32_16x16x32_bf16(a[m], b[n], acc[m][n], 0,0,0);
    }
    __syncthreads();
    cur ^= 1;
  }
  #pragma unroll
  for (int m=0;m<4;m++){
    const int row = row0 + wm*64 + m*16 + g16*4;
    #pragma unroll
    for (int n=0;n<4;n++){
      const int col = col0 + wn*64 + n*16 + r;
      #pragma unroll
      for (int j=0;j<4;j++){
        float val = acc[m][n][j];
        size_t idx = (size_t)(row+j)*ldc + col;
        if constexpr (EP==2 || EP==3) val += bias[col];
        if constexpr (EP==2) val = 0.5f*val*(1.0f + erff(val*0.70710678118f));
        if constexpr (EP==1 || EP==3) val += resid[idx];
        if constexpr (EP==0 || EP==2) ((unsigned short*)C)[idx] = f2bf(val);
        else ((float*)C)[idx] = val;
      }
    }
  }
}

// ---------------- 256^2 8-phase GEMM (head) ----------------
#define LDA8(buf,m,ks) (*(const short8*)(lds8 + (buf)*65536 + (wm*128+(m)*16+r)*128 + (((ks)*64+g16*16)^rsw)))
#define LDB8(buf,n,ks) (*(const short8*)(lds8 + (buf)*65536 + 32768 + (wn*64+(n)*16+r)*128 + (((ks)*64+g16*16)^rsw)))
#define STG(buf,isB,h,i,tile) gload16( \
    ((isB) ? Bw + (size_t)(col0 + (h)*128 + (i)*64 + wave*8 + srow)*K + (size_t)(tile)*64 + scsw \
           : A  + (size_t)(row0 + (h)*128 + (i)*64 + wave*8 + srow)*K + (size_t)(tile)*64 + scsw), \
    lds8 + (buf)*65536 + (isB)*32768 + ((h)*128 + (i)*64 + wave*8)*128 )
#define STG_HT(buf,isB,h,tile) do{ STG(buf,isB,h,0,tile); STG(buf,isB,h,1,tile); }while(0)
#define BLOAD8(bT) do{ \
  bfr[0][0]=LDB8(bT,0,0); bfr[0][1]=LDB8(bT,0,1); bfr[1][0]=LDB8(bT,1,0); bfr[1][1]=LDB8(bT,1,1); \
  bfr[2][0]=LDB8(bT,2,0); bfr[2][1]=LDB8(bT,2,1); bfr[3][0]=LDB8(bT,3,0); bfr[3][1]=LDB8(bT,3,1); }while(0)
#define MM8(mb,n) do{ \
  acc[mb][n]    =__builtin_amdgcn_mfma_f32_16x16x32_bf16(a0[0],bfr[n][0],acc[mb][n],0,0,0); \
  acc[mb][n]    =__builtin_amdgcn_mfma_f32_16x16x32_bf16(a0[1],bfr[n][1],acc[mb][n],0,0,0); \
  acc[(mb)+1][n]=__builtin_amdgcn_mfma_f32_16x16x32_bf16(a1[0],bfr[n][0],acc[(mb)+1][n],0,0,0); \
  acc[(mb)+1][n]=__builtin_amdgcn_mfma_f32_16x16x32_bf16(a1[1],bfr[n][1],acc[(mb)+1][n],0,0,0); }while(0)
#define PH8(bT, mb, STAGES, TAIL) do{ \
  short8 a0[2], a1[2]; \
  a0[0]=LDA8(bT,mb,0); a0[1]=LDA8(bT,mb,1); a1[0]=LDA8(bT,(mb)+1,0); a1[1]=LDA8(bT,(mb)+1,1); \
  STAGES; \
  __builtin_amdgcn_s_barrier(); \
  asm volatile("s_waitcnt lgkmcnt(0)" ::: "memory"); \
  __builtin_amdgcn_s_setprio(1); \
  MM8(mb,0); MM8(mb,1); MM8(mb,2); MM8(mb,3); \
  __builtin_amdgcn_s_setprio(0); \
  TAIL; \
  __builtin_amdgcn_s_barrier(); \
}while(0)

__global__ __launch_bounds__(512, 2)
void gemm_8ph(const unsigned short* __restrict__ A, const unsigned short* __restrict__ Bw,
              float* __restrict__ C, int K, int ldc, int MB){
  __shared__ char lds8[131072];
  const int tid = threadIdx.x;
  const int wave = tid>>6, lane = tid&63;
  const int wm = wave>>2, wn = wave&3;
  const int nwg = gridDim.x;
  const int pp = blockIdx.x;
  const int t = (nwg & 7) ? pp : ((pp & 7)*(nwg>>3) + (pp>>3));
  const int by = t % MB, bx = t / MB;
  const int row0 = by*256, col0 = bx*256;
  const int r = lane&15, g16 = lane>>4;
  const int rsw = (r&7)<<4;
  const int srow = lane>>3;
  const int scsw = ((lane&7) ^ srow)*8;

  f32x4 acc[8][4] = {};
  short8 bfr[4][2];
  const int NT = K/64;

  STG_HT(0,1,0,0); STG_HT(0,1,1,0);
  STG_HT(0,0,0,0); STG_HT(0,0,1,0);
  STG_HT(1,1,0,1); STG_HT(1,1,1,1);
  VMC(4);
  __builtin_amdgcn_s_barrier();

  for (int T0 = 0; T0 < NT-2; T0 += 2){
    BLOAD8(0);
    PH8(0, 0, STG_HT(1,0,0,T0+1), ((void)0));
    PH8(0, 2, STG_HT(1,0,1,T0+1), ((void)0));
    PH8(0, 4, STG_HT(0,1,0,T0+2), ((void)0));
    PH8(0, 6, STG_HT(0,1,1,T0+2), VMC(4));
    BLOAD8(1);
    PH8(1, 0, STG_HT(0,0,0,T0+2), ((void)0));
    PH8(1, 2, STG_HT(0,0,1,T0+2), ((void)0));
    PH8(1, 4, STG_HT(1,1,0,T0+3), ((void)0));
    PH8(1, 6, STG_HT(1,1,1,T0+3), VMC(4));
  }
  BLOAD8(0);
  PH8(0, 0, STG_HT(1,0,0,NT-1), ((void)0));
  PH8(0, 2, STG_HT(1,0,1,NT-1), ((void)0));
  PH8(0, 4, ((void)0), ((void)0));
  PH8(0, 6, ((void)0), VMC(0));
  BLOAD8(1);
  PH8(1, 0, ((void)0), ((void)0));
  PH8(1, 2, ((void)0), ((void)0));
  PH8(1, 4, ((void)0), ((void)0));
  PH8(1, 6, ((void)0), ((void)0));

  // ---- coalesced epilogue: stage C through LDS (64-row chunks), float4 stores ----
  // acc->LDS: f32 slot-XOR swizzle; write conflicts 2-way only (free); read: one
  // 1KB row per wave, conflict-free; global: each wave stores 1KB contiguous.
  float* lf = (float*)lds8;
  #pragma unroll
  for (int c=0;c<4;c++){
    __builtin_amdgcn_s_barrier();
    if (wm == (c>>1)){
      #pragma unroll
      for (int mm=0;mm<4;mm++){
        #pragma unroll
        for (int n=0;n<4;n++){
          const int col = wn*64 + n*16 + r;
          #pragma unroll
          for (int j=0;j<4;j++){
            const int lr = mm*16 + g16*4 + j;
            const int slot = (col>>2) ^ (lr&7);
            lf[lr*256 + slot*4 + (col&3)] = acc[4*(c&1)+mm][n][j];
          }
        }
      }
    }
    __builtin_amdgcn_s_barrier();
    #pragma unroll
    for (int i=0;i<8;i++){
      const int gidx = tid + 512*i;          // 4096 float4 slots per chunk
      const int lr = gidx >> 6;
      const int slot = gidx & 63;
      const int ss = slot ^ (lr&7);
      float4 v = *reinterpret_cast<const float4*>(lf + lr*256 + ss*4);
      *reinterpret_cast<float4*>(C + (size_t)(row0 + c*64 + lr)*ldc + col0 + slot*4) = v;
    }
  }
}

// ---------------- 128x256 4-phase GEMM (layer GEMMs) ----------------
#define L4A(buf,m,ks) (*(const short8*)(lds4 + (buf)*49152 + (wm*64+(m)*16+r)*128 + (((ks)*64+g16*16)^rsw)))
#define L4B(buf,n,ks) (*(const short8*)(lds4 + (buf)*49152 + 16384 + (wn*64+(n)*16+r)*128 + (((ks)*64+g16*16)^rsw)))
#define STG4A(buf,tile) do{ \
  gload16(A4 + (size_t)(row0 + 0*64 + wave*8 + srow)*K + (size_t)(tile)*64 + scsw, lds4 + (buf)*49152 + (0*64+wave*8)*128); \
  gload16(A4 + (size_t)(row0 + 1*64 + wave*8 + srow)*K + (size_t)(tile)*64 + scsw, lds4 + (buf)*49152 + (1*64+wave*8)*128); }while(0)
#define STG4B(buf,tile) do{ \
  gload16(B4 + (size_t)(col0 + 0*64 + wave*8 + srow)*K + (size_t)(tile)*64 + scsw, lds4 + (buf)*49152 + 16384 + (0*64+wave*8)*128); \
  gload16(B4 + (size_t)(col0 + 1*64 + wave*8 + srow)*K + (size_t)(tile)*64 + scsw, lds4 + (buf)*49152 + 16384 + (1*64+wave*8)*128); \
  gload16(B4 + (size_t)(col0 + 2*64 + wave*8 + srow)*K + (size_t)(tile)*64 + scsw, lds4 + (buf)*49152 + 16384 + (2*64+wave*8)*128); \
  gload16(B4 + (size_t)(col0 + 3*64 + wave*8 + srow)*K + (size_t)(tile)*64 + scsw, lds4 + (buf)*49152 + 16384 + (3*64+wave*8)*128); }while(0)
#define BLOAD4(bT) do{ \
  bfr4[0][0]=L4B(bT,0,0); bfr4[0][1]=L4B(bT,0,1); bfr4[1][0]=L4B(bT,1,0); bfr4[1][1]=L4B(bT,1,1); \
  bfr4[2][0]=L4B(bT,2,0); bfr4[2][1]=L4B(bT,2,1); bfr4[3][0]=L4B(bT,3,0); bfr4[3][1]=L4B(bT,3,1); }while(0)
#define MM44(mb,n) do{ \
  acc[mb][n]    =__builtin_amdgcn_mfma_f32_16x16x32_bf16(a0[0],bfr4[n][0],acc[mb][n],0,0,0); \
  acc[mb][n]    =__builtin_amdgcn_mfma_f32_16x16x32_bf16(a0[1],bfr4[n][1],acc[mb][n],0,0,0); \
  acc[(mb)+1][n]=__builtin_amdgcn_mfma_f32_16x16x32_bf16(a1[0],bfr4[n][0],acc[(mb)+1][n],0,0,0); \
  acc[(mb)+1][n]=__builtin_amdgcn_mfma_f32_16x16x32_bf16(a1[1],bfr4[n][1],acc[(mb)+1][n],0,0,0); }while(0)
#define PH4(bT, mb, STAGES, TAIL) do{ \
  short8 a0[2], a1[2]; \
  a0[0]=L4A(bT,mb,0); a0[1]=L4A(bT,mb,1); a1[0]=L4A(bT,(mb)+1,0); a1[1]=L4A(bT,(mb)+1,1); \
  STAGES; \
  __builtin_amdgcn_s_barrier(); \
  asm volatile("s_waitcnt lgkmcnt(0)" ::: "memory"); \
  __builtin_amdgcn_s_setprio(1); \
  MM44(mb,0); MM44(mb,1); MM44(mb,2); MM44(mb,3); \
  __builtin_amdgcn_s_setprio(0); \
  TAIL; \
  __builtin_amdgcn_s_barrier(); \
}while(0)

template<int EP>
__global__ __launch_bounds__(512, 2)
void gemm_4ph(const unsigned short* __restrict__ A, const unsigned short* __restrict__ Bw,
              void* __restrict__ C, const float* __restrict__ bias,
              int K, int ldc, int MB, int kLen){
  __shared__ char lds4[98304];
  const int tid = threadIdx.x;
  const int wave = tid>>6, lane = tid&63;
  const int wm = wave>>2, wn = wave&3;
  const int nwg = gridDim.x;
  const int pp = blockIdx.x;
  const int t = (nwg & 7) ? pp : ((pp & 7)*(nwg>>3) + (pp>>3));
  const int by = t % MB, bx = t / MB;
  const int row0 = by*128, col0 = bx*256;
  const int r = lane&15, g16 = lane>>4;
  const int rsw = (r&7)<<4;
  const int srow = lane>>3;
  const int scsw = ((lane&7) ^ srow)*8;
  const int kz = blockIdx.z;
  const unsigned short* A4 = A + (size_t)kz*kLen;
  const unsigned short* B4 = Bw + (size_t)kz*kLen;

  f32x4 acc[4][4] = {};
  short8 bfr4[4][2];
  const int NT = kLen/64;

  STG4B(0,0); STG4A(0,0); STG4B(1,1);
  VMC(4);
  __builtin_amdgcn_s_barrier();

  for (int T0 = 0; T0 < NT-2; T0 += 2){
    BLOAD4(0);
    PH4(0, 0, STG4A(1,T0+1), ((void)0));
    PH4(0, 2, STG4B(0,T0+2), VMC(4));
    BLOAD4(1);
    PH4(1, 0, STG4A(0,T0+2), ((void)0));
    PH4(1, 2, STG4B(1,T0+3), VMC(4));
  }
  BLOAD4(0);
  PH4(0, 0, STG4A(1,NT-1), ((void)0));
  PH4(0, 2, ((void)0), VMC(0));
  BLOAD4(1);
  PH4(1, 0, ((void)0), ((void)0));
  PH4(1, 2, ((void)0), ((void)0));

  float* Cp5 = (float*)C + (size_t)kz*M_*ldc;
  #pragma unroll
  for (int m=0;m<4;m++){
    const int row = row0 + wm*64 + m*16 + g16*4;
    #pragma unroll
    for (int n=0;n<4;n++){
      const int col = col0 + wn*64 + n*16 + r;
      #pragma unroll
      for (int j=0;j<4;j++){
        float val = acc[m][n][j];
        size_t idx = (size_t)(row+j)*ldc + col;
        if constexpr (EP==2) { val += bias[col]; val = 0.5f*val*(1.0f + erff(val*0.70710678118f)); }
        if constexpr (EP==0 || EP==2) ((unsigned short*)C)[idx] = f2bf(val);
        else Cp5[idx] = val;
      }
    }
  }
}

// ---------------- fused causal attention (flash-style, pipelined staging) ----------------
__global__ __launch_bounds__(256)
void attn_k(const unsigned short* __restrict__ qkv, unsigned short* __restrict__ o){
  __shared__ unsigned short Ks[2][64*64];
  __shared__ unsigned short Vt[2][64*64];
  __shared__ unsigned short Ps[4*16*64];
  const int tid = threadIdx.x;
  const int wave = tid>>6, lane = tid&63;
  const int qb = blockIdx.x, h = blockIdx.y, b = blockIdx.z;
  const int r = lane&15, g = lane>>4;
  const size_t rowbase = (size_t)b*S_*3*D_;
  const unsigned short* kbase = qkv + rowbase + D_ + h*64;
  const unsigned short* vbase = qkv + rowbase + 2*D_ + h*64;
  short8 qf[2];
  {
    const unsigned short* qp = qkv + rowbase + (size_t)(qb*64 + wave*16 + r)*(3*D_) + h*64 + g*8;
    short8 q0 = *reinterpret_cast<const short8*>(qp);
    short8 q1 = *reinterpret_cast<const short8*>(qp + 32);
    #pragma unroll
    for (int j=0;j<8;j++){
      qf[0][j] = (short)f2bf(bf2f((unsigned short)q0[j])*0.125f);
      qf[1][j] = (short)f2bf(bf2f((unsigned short)q1[j])*0.125f);
    }
  }
  float mrow[4] = {-INFINITY,-INFINITY,-INFINITY,-INFINITY};
  float lrow[4] = {0.f,0.f,0.f,0.f};
  f32x4 oacc[4] = {};
  const int qglob0 = qb*64 + wave*16 + g*4;
  unsigned short* Pw = Ps + wave*16*64;
  uint4 vdr[2];

  const int key8 = tid>>3;
  const int c8   = (tid&7)*8;
  const int kcsw = ((tid&7) ^ (key8&7))*16;

#define KSTG_A(nxt, kt2) do{ \
  gload16((const char*)(kbase + (size_t)((kt2)*64+key8)*(3*D_)) + kcsw, (char*)Ks[nxt] + wave*1024); \
  gload16((const char*)(kbase + (size_t)((kt2)*64+32+key8)*(3*D_)) + kcsw, (char*)Ks[nxt] + 4096 + wave*1024); \
}while(0)
#define VLOAD_A(kt2) do{ \
  vdr[0] = *reinterpret_cast<const uint4*>(vbase + (size_t)((kt2)*64+key8)*(3*D_) + c8); \
  vdr[1] = *reinterpret_cast<const uint4*>(vbase + (size_t)((kt2)*64+32+key8)*(3*D_) + c8); \
}while(0)
#define VSTORE_A(nxt) do{ \
  _Pragma("unroll") \
  for (int i=0;i<2;i++){ \
    int key = i*32 + key8; \
    const unsigned short* ve = reinterpret_cast<const unsigned short*>(&vdr[i]); \
    _Pragma("unroll") \
    for (int j=0;j<8;j++){ \
      int d = c8 + j; \
      int bo2 = (d*128 + key*2) ^ ((d&7)<<4); \
      *reinterpret_cast<unsigned short*>((char*)Vt[nxt] + bo2) = ve[j]; \
    } \
  } }while(0)

  KSTG_A(0, 0);
  VLOAD_A(0);
  VMC(0);
  VSTORE_A(0);
  __syncthreads();

  int cur = 0;
  for (int kt=0; kt<=qb; kt++){
    const bool pf = (kt < qb);
    if (pf){ KSTG_A(cur^1, kt+1); VLOAD_A(kt+1); }
    f32x4 sacc[4] = {};
    #pragma unroll
    for (int ks=0; ks<2; ks++){
      #pragma unroll
      for (int nb=0; nb<4; nb++){
        int key = nb*16 + r;
        int bo = (key*128 + (ks*32+g*8)*2) ^ ((key&7)<<4);
        short8 kf = *reinterpret_cast<const short8*>((char*)Ks[cur] + bo);
        sacc[nb] = __builtin_amdgcn_mfma_f32_16x16x32_bf16(qf[ks], kf, sacc[nb], 0,0,0);
      }
    }
    float sv[4][4];
    float tm[4] = {-INFINITY,-INFINITY,-INFINITY,-INFINITY};
    if (kt == qb){
      #pragma unroll
      for (int nb=0; nb<4; nb++){
        int key = kt*64 + nb*16 + r;
        #pragma unroll
        for (int j=0;j<4;j++){
          float s = (key <= qglob0 + j) ? sacc[nb][j] : -INFINITY;
          sv[nb][j] = s;
          tm[j] = fmaxf(tm[j], s);
        }
      }
    } else {
      #pragma unroll
      for (int nb=0; nb<4; nb++)
        #pragma unroll
        for (int j=0;j<4;j++){
          float s = sacc[nb][j];
          sv[nb][j] = s;
          tm[j] = fmaxf(tm[j], s);
        }
    }
    #pragma unroll
    for (int off=1; off<16; off<<=1){
      #pragma unroll
      for (int j=0;j<4;j++) tm[j] = fmaxf(tm[j], __shfl_xor(tm[j], off));
    }
    int chg = 0;
    float mn[4];
    #pragma unroll
    for (int j=0;j<4;j++){ mn[j] = fmaxf(mrow[j], tm[j]); chg |= (mn[j] > mrow[j]); }
    if (__any(chg)){
      #pragma unroll
      for (int j=0;j<4;j++){
        float sf = __expf(mrow[j]-mn[j]);
        mrow[j] = mn[j];
        lrow[j] *= sf;
        #pragma unroll
        for (int nb=0;nb<4;nb++) oacc[nb][j] *= sf;
      }
    }
    float psum[4] = {0.f,0.f,0.f,0.f};
    #pragma unroll
    for (int nb=0; nb<4; nb++){
      #pragma unroll
      for (int j=0;j<4;j++){
        float p = __expf(sv[nb][j]-mrow[j]);
        psum[j] += p;
        int prow = g*4+j;
        int bo = (prow*128 + (nb*16+r)*2) ^ ((prow&7)<<4);
        *reinterpret_cast<unsigned short*>((char*)Pw + bo) = f2bf(p);
      }
    }
    #pragma unroll
    for (int off=1; off<16; off<<=1){
      #pragma unroll
      for (int j=0;j<4;j++) psum[j] += __shfl_xor(psum[j], off);
    }
    #pragma unroll
    for (int j=0;j<4;j++) lrow[j] += psum[j];
    asm volatile("s_waitcnt lgkmcnt(0)" ::: "memory");
    #pragma unroll
    for (int ks=0; ks<2; ks++){
      int bo = (r*128 + (ks*32+g*8)*2) ^ ((r&7)<<4);
      short8 pf8 = *reinterpret_cast<const short8*>((char*)Pw + bo);
      #pragma unroll
      for (int nb=0; nb<4; nb++){
        int d = nb*16 + r;
        int bo2 = (d*128 + (ks*32+g*8)*2) ^ ((d&7)<<4);
        short8 vf = *reinterpret_cast<const short8*>((char*)Vt[cur] + bo2);
        oacc[nb] = __builtin_amdgcn_mfma_f32_16x16x32_bf16(pf8, vf, oacc[nb], 0,0,0);
      }
    }
    if (pf){ VMC(0); VSTORE_A(cur^1); }
    __syncthreads();
    cur ^= 1;
  }
  #pragma unroll
  for (int nb=0; nb<4; nb++){
    #pragma unroll
    for (int j=0;j<4;j++){
      float ov = oacc[nb][j] / lrow[j];
      size_t row = (size_t)b*S_ + qb*64 + wave*16 + g*4 + j;
      o[row*D_ + h*64 + nb*16 + r] = f2bf(ov);
    }
  }
}

extern "C" void kernel_launch(void* const* d_in, const int* in_sizes, int n_in,
                              void* d_out, int out_size, void* d_ws, size_t ws_size,
                              hipStream_t stream) {
  const int*   ids   = (const int*)  d_in[0];
  const float* emb   = (const float*)d_in[1];
  const float* Wq    = (const float*)d_in[2];
  const float* Wk    = (const float*)d_in[3];
  const float* Wv    = (const float*)d_in[4];
  const float* Wo    = (const float*)d_in[5];
  const float* W1    = (const float*)d_in[6];
  const float* b1    = (const float*)d_in[7];
  const float* W2    = (const float*)d_in[8];
  const float* b2    = (const float*)d_in[9];
  const float* ln1_g = (const float*)d_in[10];
  const float* ln1_b = (const float*)d_in[11];
  const float* ln2_g = (const float*)d_in[12];
  const float* ln2_b = (const float*)d_in[13];
  const float* lnf_g = (const float*)d_in[14];
  const float* lnf_b = (const float*)d_in[15];
  const float* headw = (const float*)d_in[16];

  unsigned short* ws = (unsigned short*)d_ws;
  unsigned short* wqkvT = ws;                                   // L*3*D*D
  unsigned short* woT   = wqkvT + (size_t)L_*3*D_*D_;           // L*D*D
  unsigned short* w1T   = woT   + (size_t)L_*D_*D_;             // L*DF*D
  unsigned short* w2T   = w1T   + (size_t)L_*D_*DF_;            // L*D*DF
  unsigned short* headT = w2T   + (size_t)L_*D_*DF_;            // V*D
  unsigned short* h     = headT + (size_t)V_*D_;                // M*D
  unsigned short* qkv   = h     + (size_t)M_*D_;                // M*3D
  unsigned short* attno = qkv   + (size_t)M_*3*D_;              // M*D
  unsigned short* h2    = attno + (size_t)M_*D_;                // M*DF
  float*          x     = (float*)(h2 + (size_t)M_*DF_);        // M*D f32
  float*          part  = x + (size_t)M_*D_;                    // 4*M*D f32 (KS=4)
  size_t needed = ((char*)(part + (size_t)4*M_*D_)) - (char*)d_ws;
  const bool splitk = (ws_size >= needed);

  // ---- weight prep ----
  transpose_k<<<dim3(D_/64, D_/64, L_), 256, 0, stream>>>(Wq, wqkvT,            D_, D_, (size_t)D_*D_, (size_t)3*D_*D_);
  transpose_k<<<dim3(D_/64, D_/64, L_), 256, 0, stream>>>(Wk, wqkvT + D_*D_,    D_, D_, (size_t)D_*D_, (size_t)3*D_*D_);
  transpose_k<<<dim3(D_/64, D_/64, L_), 256, 0, stream>>>(Wv, wqkvT + 2*D_*D_,  D_, D_, (size_t)D_*D_, (size_t)3*D_*D_);
  transpose_k<<<dim3(D_/64, D_/64, L_), 256, 0, stream>>>(Wo, woT,              D_, D_, (size_t)D_*D_, (size_t)D_*D_);
  transpose_k<<<dim3(DF_/64, D_/64, L_), 256, 0, stream>>>(W1, w1T,             D_, DF_, (size_t)D_*DF_, (size_t)D_*DF_);
  transpose_k<<<dim3(D_/64, DF_/64, L_), 256, 0, stream>>>(W2, w2T,             DF_, D_, (size_t)D_*DF_, (size_t)D_*DF_);
  transpose_k<<<dim3(V_/64, D_/64, 1), 256, 0, stream>>>(headw, headT,          D_, V_, 0, 0);

  // ---- embed + first LN ----
  embed_k<<<M_, 256, 0, stream>>>(ids, emb, x);
  ln_k<<<M_, 256, 0, stream>>>(x, ln1_g, ln1_b, h);

  // ---- layers (h holds ln1(x) entering each layer) ----
  for (int l = 0; l < L_; l++){
    gemm_4ph<0><<<dim3((3*D_/256)*(M_/128), 1, 1), 512, 0, stream>>>(h, wqkvT + (size_t)l*3*D_*D_, qkv, nullptr, D_, 3*D_, M_/128, D_);
    attn_k<<<dim3(S_/64, H_, B_), 256, 0, stream>>>(qkv, attno);
    if (splitk){
      gemm_4ph<5><<<dim3((D_/256)*(M_/128), 1, 4), 512, 0, stream>>>(attno, woT + (size_t)l*D_*D_, part, nullptr, D_, D_, M_/128, D_/4);
      rln_k<<<M_, 256, 0, stream>>>(x, part, nullptr, ln2_g + l*D_, ln2_b + l*D_, h, 4);
    } else {
      gemm_bt<1><<<dim3((D_/128)*(M_/128), 1, 1), 256, 0, stream>>>(attno, woT + (size_t)l*D_*D_, x, nullptr, x, D_, D_, M_/128, D_);
      ln_k<<<M_, 256, 0, stream>>>(x, ln2_g + l*D_, ln2_b + l*D_, h);
    }
    gemm_4ph<2><<<dim3((DF_/256)*(M_/128), 1, 1), 512, 0, stream>>>(h, w1T + (size_t)l*D_*DF_, h2, b1 + l*DF_, D_, DF_, M_/128, D_);
    const float* ng = (l+1 < L_) ? (ln1_g + (l+1)*D_) : lnf_g;
    const float* nb = (l+1 < L_) ? (ln1_b + (l+1)*D_) : lnf_b;
    if (splitk){
      gemm_4ph<5><<<dim3((D_/256)*(M_/128), 1, 4), 512, 0, stream>>>(h2, w2T + (size_t)l*D_*DF_, part, nullptr, DF_, D_, M_/128, DF_/4);
      rln_k<<<M_, 256, 0, stream>>>(x, part, b2 + l*D_, ng, nb, h, 4);
    } else {
      gemm_bt<3><<<dim3((D_/128)*(M_/128), 1, 1), 256, 0, stream>>>(h2, w2T + (size_t)l*D_*DF_, x, b2 + l*D_, x, DF_, D_, M_/128, DF_);
      ln_k<<<M_, 256, 0, stream>>>(x, ng, nb, h);
    }
  }

  // ---- head GEMM (h = lnf(x) already) ----
  gemm_8ph<<<dim3((V_/256)*(M_/256), 1, 1), 512, 0, stream>>>(h, headT, (float*)d_out, D_, V_, M_/256);
}

// Round 12
// 894.088 us; speedup vs baseline: 1.0293x; 1.0118x over previous
//
#include <hip/hip_runtime.h>
#include <stdint.h>

// Transformer prefill: B=2,S=1024,V=32000,D=1024,H=16,L=4,DK=64,DF=4096
#define B_ 2
#define S_ 1024
#define V_ 32000
#define D_ 1024
#define H_ 16
#define L_ 4
#define DF_ 4096
#define M_ (B_*S_)

typedef short short8 __attribute__((ext_vector_type(8)));
typedef float f32x4 __attribute__((ext_vector_type(4)));

__device__ __forceinline__ unsigned short f2bf(float f){
  union { float f; unsigned int u; } v; v.f = f;
  unsigned int u = v.u;
  u = u + 0x7fffu + ((u >> 16) & 1u);
  return (unsigned short)(u >> 16);
}

__device__ __forceinline__ float bf2f(unsigned short u){
  union { unsigned int u; float f; } v; v.u = ((unsigned int)u) << 16;
  return v.f;
}

__device__ __forceinline__ void gload16(const void* g, void* l){
  __builtin_amdgcn_global_load_lds(
      (__attribute__((address_space(1))) void*)(uintptr_t)g,
      (__attribute__((address_space(3))) void*)(uintptr_t)l, 16, 0, 0);
}

// ---------------- embed gather ----------------
__global__ __launch_bounds__(256) void embed_k(const int* __restrict__ ids,
    const float* __restrict__ emb, float* __restrict__ x){
  int row = blockIdx.x;
  int id = ids[row];
  float4 v = reinterpret_cast<const float4*>(emb + (size_t)id*D_)[threadIdx.x];
  reinterpret_cast<float4*>(x + (size_t)row*D_)[threadIdx.x] = v;
}

// ---------------- layernorm: f32 in -> bf16 out ----------------
__global__ __launch_bounds__(256) void ln_k(const float* __restrict__ x,
    const float* __restrict__ g, const float* __restrict__ b,
    unsigned short* __restrict__ out){
  int row = blockIdx.x;
  int tid = threadIdx.x;
  float4 v = reinterpret_cast<const float4*>(x + (size_t)row*D_)[tid];
  float s = v.x+v.y+v.z+v.w;
  float ss = v.x*v.x + v.y*v.y + v.z*v.z + v.w*v.w;
  #pragma unroll
  for (int off=1; off<64; off<<=1){ s += __shfl_xor(s, off); ss += __shfl_xor(ss, off); }
  __shared__ float rs[4], rss[4];
  int wave = tid>>6, lane = tid&63;
  if (lane==0){ rs[wave]=s; rss[wave]=ss; }
  __syncthreads();
  s  = rs[0]+rs[1]+rs[2]+rs[3];
  ss = rss[0]+rss[1]+rss[2]+rss[3];
  float mean = s * (1.0f/(float)D_);
  float var  = ss * (1.0f/(float)D_) - mean*mean;
  float inv = rsqrtf(var + 1e-5f);
  float4 gg = reinterpret_cast<const float4*>(g)[tid];
  float4 bb = reinterpret_cast<const float4*>(b)[tid];
  ushort4 o;
  o.x = f2bf((v.x-mean)*inv*gg.x + bb.x);
  o.y = f2bf((v.y-mean)*inv*gg.y + bb.y);
  o.z = f2bf((v.z-mean)*inv*gg.z + bb.z);
  o.w = f2bf((v.w-mean)*inv*gg.w + bb.w);
  reinterpret_cast<ushort4*>(out + (size_t)row*D_)[tid] = o;
}

// ---------------- fused split-K reduce + residual + LN ----------------
__global__ __launch_bounds__(256) void rln_k(float* __restrict__ x,
    const float* __restrict__ part, const float* __restrict__ bias,
    const float* __restrict__ g, const float* __restrict__ b,
    unsigned short* __restrict__ out, int KS){
  int row = blockIdx.x;
  int tid = threadIdx.x;
  float4 v = reinterpret_cast<const float4*>(x + (size_t)row*D_)[tid];
  for (int z=0; z<KS; z++){
    float4 p = reinterpret_cast<const float4*>(part + (size_t)z*M_*D_ + (size_t)row*D_)[tid];
    v.x+=p.x; v.y+=p.y; v.z+=p.z; v.w+=p.w;
  }
  if (bias){
    float4 bb4 = reinterpret_cast<const float4*>(bias)[tid];
    v.x+=bb4.x; v.y+=bb4.y; v.z+=bb4.z; v.w+=bb4.w;
  }
  reinterpret_cast<float4*>(x + (size_t)row*D_)[tid] = v;
  float s = v.x+v.y+v.z+v.w;
  float ss = v.x*v.x + v.y*v.y + v.z*v.z + v.w*v.w;
  #pragma unroll
  for (int off=1; off<64; off<<=1){ s += __shfl_xor(s, off); ss += __shfl_xor(ss, off); }
  __shared__ float rs[4], rss[4];
  int wave = tid>>6, lane = tid&63;
  if (lane==0){ rs[wave]=s; rss[wave]=ss; }
  __syncthreads();
  s  = rs[0]+rs[1]+rs[2]+rs[3];
  ss = rss[0]+rss[1]+rss[2]+rss[3];
  float mean = s * (1.0f/(float)D_);
  float var  = ss * (1.0f/(float)D_) - mean*mean;
  float inv = rsqrtf(var + 1e-5f);
  float4 gg = reinterpret_cast<const float4*>(g)[tid];
  float4 bb = reinterpret_cast<const float4*>(b)[tid];
  ushort4 o;
  o.x = f2bf((v.x-mean)*inv*gg.x + bb.x);
  o.y = f2bf((v.y-mean)*inv*gg.y + bb.y);
  o.z = f2bf((v.z-mean)*inv*gg.z + bb.z);
  o.w = f2bf((v.w-mean)*inv*gg.w + bb.w);
  reinterpret_cast<ushort4*>(out + (size_t)row*D_)[tid] = o;
}

// ---------------- transpose + f32->bf16: in [K][N] -> out [N][K] ----------------
__global__ __launch_bounds__(256) void transpose_k(const float* __restrict__ in,
    unsigned short* __restrict__ out, int K, int N, size_t in_ls, size_t out_ls){
  __shared__ float t[64][65];
  const float* inp = in + (size_t)blockIdx.z*in_ls;
  unsigned short* outp = out + (size_t)blockIdx.z*out_ls;
  int k0 = blockIdx.y*64, n0 = blockIdx.x*64;
  int rr = threadIdx.x >> 4, c4 = (threadIdx.x & 15)*4;
  #pragma unroll
  for (int i=0;i<4;i++){
    float4 v = *reinterpret_cast<const float4*>(inp + (size_t)(k0+rr+i*16)*N + n0 + c4);
    t[rr+i*16][c4+0]=v.x; t[rr+i*16][c4+1]=v.y; t[rr+i*16][c4+2]=v.z; t[rr+i*16][c4+3]=v.w;
  }
  __syncthreads();
  #pragma unroll
  for (int i=0;i<4;i++){
    int n = rr + i*16;
    ushort4 o;
    o.x = f2bf(t[c4+0][n]); o.y = f2bf(t[c4+1][n]);
    o.z = f2bf(t[c4+2][n]); o.w = f2bf(t[c4+3][n]);
    *reinterpret_cast<ushort4*>(outp + (size_t)(n0+n)*K + k0 + c4) = o;
  }
}

#define VMC(n)  asm volatile("s_waitcnt vmcnt(" #n ")" ::: "memory")

// ---------------- 128^2 double-buffered 2-phase GEMM (fallback only) ----------------
template<int EP>
__global__ __launch_bounds__(256)
void gemm_bt(const unsigned short* __restrict__ A, const unsigned short* __restrict__ B,
             void* __restrict__ C, const float* __restrict__ bias,
             const float* __restrict__ resid, int K, int ldc, int MB, int kLen){
  __shared__ unsigned short As[2][128*64];
  __shared__ unsigned short Bs[2][128*64];
  const int tid = threadIdx.x;
  const int wave = tid>>6, lane = tid&63;
  const int wm = wave>>1, wn = wave&1;
  const int nwg = gridDim.x;
  const int p = blockIdx.x;
  const int t = (nwg & 7) ? p : ((p & 7)*(nwg>>3) + (p>>3));
  const int by = t % MB, bx = t / MB;
  const int row0 = by*128, col0 = bx*128;
  const int kz = blockIdx.z;
  const int k0 = kz*kLen;
  f32x4 acc[4][4] = {};
  const int sw8 = ((lane&7) ^ ((lane>>3)&7))*8;
  const unsigned short* Ag = A + (size_t)(row0 + wave*8 + (lane>>3))*K + sw8;
  const unsigned short* Bg = B + (size_t)(col0 + wave*8 + (lane>>3))*K + sw8;
  const int r = lane&15, g16 = lane>>4;
  const int rsw = (r&7)<<4;
#define STAGE_BT(buf, kt) do{ \
    _Pragma("unroll") \
    for (int i=0;i<4;i++){ \
      gload16(Ag + (size_t)i*32*K + (kt), As[buf] + (wave*8 + i*32)*64); \
      gload16(Bg + (size_t)i*32*K + (kt), Bs[buf] + (wave*8 + i*32)*64); \
    } }while(0)
  STAGE_BT(0, k0);
  __syncthreads();
  int cur = 0;
  for (int kt=k0; kt<k0+kLen; kt+=64){
    if (kt + 64 < k0 + kLen) STAGE_BT(cur^1, kt+64);
    #pragma unroll
    for (int ks=0; ks<2; ks++){
      short8 a[4], b[4];
      #pragma unroll
      for (int m=0;m<4;m++)
        a[m] = *reinterpret_cast<const short8*>((const char*)As[cur] + (wm*64+m*16+r)*128 + ((ks*64 + g16*16) ^ rsw));
      #pragma unroll
      for (int n=0;n<4;n++)
        b[n] = *reinterpret_cast<const short8*>((const char*)Bs[cur] + (wn*64+n*16+r)*128 + ((ks*64 + g16*16) ^ rsw));
      #pragma unroll
      for (int m=0;m<4;m++)
        #pragma unroll
        for (int n=0;n<4;n++)
          acc[m][n] = __builtin_amdgcn_mfma_f32_16x16x32_bf16(a[m], b[n], acc[m][n], 0,0,0);
    }
    __syncthreads();
    cur ^= 1;
  }
  #pragma unroll
  for (int m=0;m<4;m++){
    const int row = row0 + wm*64 + m*16 + g16*4;
    #pragma unroll
    for (int n=0;n<4;n++){
      const int col = col0 + wn*64 + n*16 + r;
      #pragma unroll
      for (int j=0;j<4;j++){
        float val = acc[m][n][j];
        size_t idx = (size_t)(row+j)*ldc + col;
        if constexpr (EP==2 || EP==3) val += bias[col];
        if constexpr (EP==2) val = 0.5f*val*(1.0f + erff(val*0.70710678118f));
        if constexpr (EP==1 || EP==3) val += resid[idx];
        if constexpr (EP==0 || EP==2) ((unsigned short*)C)[idx] = f2bf(val);
        else ((float*)C)[idx] = val;
      }
    }
  }
}

// ---------------- 256^2 8-phase GEMM (head) ----------------
#define LDA8(buf,m,ks) (*(const short8*)(lds8 + (buf)*65536 + (wm*128+(m)*16+r)*128 + (((ks)*64+g16*16)^rsw)))
#define LDB8(buf,n,ks) (*(const short8*)(lds8 + (buf)*65536 + 32768 + (wn*64+(n)*16+r)*128 + (((ks)*64+g16*16)^rsw)))
#define STG(buf,isB,h,i,tile) gload16( \
    ((isB) ? Bw + (size_t)(col0 + (h)*128 + (i)*64 + wave*8 + srow)*K + (size_t)(tile)*64 + scsw \
           : A  + (size_t)(row0 + (h)*128 + (i)*64 + wave*8 + srow)*K + (size_t)(tile)*64 + scsw), \
    lds8 + (buf)*65536 + (isB)*32768 + ((h)*128 + (i)*64 + wave*8)*128 )
#define STG_HT(buf,isB,h,tile) do{ STG(buf,isB,h,0,tile); STG(buf,isB,h,1,tile); }while(0)
#define BLOAD8(bT) do{ \
  bfr[0][0]=LDB8(bT,0,0); bfr[0][1]=LDB8(bT,0,1); bfr[1][0]=LDB8(bT,1,0); bfr[1][1]=LDB8(bT,1,1); \
  bfr[2][0]=LDB8(bT,2,0); bfr[2][1]=LDB8(bT,2,1); bfr[3][0]=LDB8(bT,3,0); bfr[3][1]=LDB8(bT,3,1); }while(0)
#define MM8(mb,n) do{ \
  acc[mb][n]    =__builtin_amdgcn_mfma_f32_16x16x32_bf16(a0[0],bfr[n][0],acc[mb][n],0,0,0); \
  acc[mb][n]    =__builtin_amdgcn_mfma_f32_16x16x32_bf16(a0[1],bfr[n][1],acc[mb][n],0,0,0); \
  acc[(mb)+1][n]=__builtin_amdgcn_mfma_f32_16x16x32_bf16(a1[0],bfr[n][0],acc[(mb)+1][n],0,0,0); \
  acc[(mb)+1][n]=__builtin_amdgcn_mfma_f32_16x16x32_bf16(a1[1],bfr[n][1],acc[(mb)+1][n],0,0,0); }while(0)
#define PH8(bT, mb, STAGES, TAIL) do{ \
  short8 a0[2], a1[2]; \
  a0[0]=LDA8(bT,mb,0); a0[1]=LDA8(bT,mb,1); a1[0]=LDA8(bT,(mb)+1,0); a1[1]=LDA8(bT,(mb)+1,1); \
  STAGES; \
  __builtin_amdgcn_s_barrier(); \
  asm volatile("s_waitcnt lgkmcnt(0)" ::: "memory"); \
  __builtin_amdgcn_s_setprio(1); \
  MM8(mb,0); MM8(mb,1); MM8(mb,2); MM8(mb,3); \
  __builtin_amdgcn_s_setprio(0); \
  TAIL; \
  __builtin_amdgcn_s_barrier(); \
}while(0)

__global__ __launch_bounds__(512, 2)
void gemm_8ph(const unsigned short* __restrict__ A, const unsigned short* __restrict__ Bw,
              float* __restrict__ C, int K, int ldc, int MB){
  __shared__ char lds8[131072];
  const int tid = threadIdx.x;
  const int wave = tid>>6, lane = tid&63;
  const int wm = wave>>2, wn = wave&3;
  const int nwg = gridDim.x;
  const int pp = blockIdx.x;
  const int t = (nwg & 7) ? pp : ((pp & 7)*(nwg>>3) + (pp>>3));
  const int by = t % MB, bx = t / MB;
  const int row0 = by*256, col0 = bx*256;
  const int r = lane&15, g16 = lane>>4;
  const int rsw = (r&7)<<4;
  const int srow = lane>>3;
  const int scsw = ((lane&7) ^ srow)*8;

  f32x4 acc[8][4] = {};
  short8 bfr[4][2];
  const int NT = K/64;

  STG_HT(0,1,0,0); STG_HT(0,1,1,0);
  STG_HT(0,0,0,0); STG_HT(0,0,1,0);
  STG_HT(1,1,0,1); STG_HT(1,1,1,1);
  VMC(4);
  __builtin_amdgcn_s_barrier();

  for (int T0 = 0; T0 < NT-2; T0 += 2){
    BLOAD8(0);
    PH8(0, 0, STG_HT(1,0,0,T0+1), ((void)0));
    PH8(0, 2, STG_HT(1,0,1,T0+1), ((void)0));
    PH8(0, 4, STG_HT(0,1,0,T0+2), ((void)0));
    PH8(0, 6, STG_HT(0,1,1,T0+2), VMC(4));
    BLOAD8(1);
    PH8(1, 0, STG_HT(0,0,0,T0+2), ((void)0));
    PH8(1, 2, STG_HT(0,0,1,T0+2), ((void)0));
    PH8(1, 4, STG_HT(1,1,0,T0+3), ((void)0));
    PH8(1, 6, STG_HT(1,1,1,T0+3), VMC(4));
  }
  BLOAD8(0);
  PH8(0, 0, STG_HT(1,0,0,NT-1), ((void)0));
  PH8(0, 2, STG_HT(1,0,1,NT-1), ((void)0));
  PH8(0, 4, ((void)0), ((void)0));
  PH8(0, 6, ((void)0), VMC(0));
  BLOAD8(1);
  PH8(1, 0, ((void)0), ((void)0));
  PH8(1, 2, ((void)0), ((void)0));
  PH8(1, 4, ((void)0), ((void)0));
  PH8(1, 6, ((void)0), ((void)0));

  #pragma unroll
  for (int m=0;m<8;m++){
    const int row = row0 + wm*128 + m*16 + g16*4;
    #pragma unroll
    for (int n=0;n<4;n++){
      const int col = col0 + wn*64 + n*16 + r;
      #pragma unroll
      for (int j=0;j<4;j++)
        C[(size_t)(row+j)*ldc + col] = acc[m][n][j];
    }
  }
}

// ---------------- 128x256 4-phase GEMM (layer GEMMs) ----------------
#define L4A(buf,m,ks) (*(const short8*)(lds4 + (buf)*49152 + (wm*64+(m)*16+r)*128 + (((ks)*64+g16*16)^rsw)))
#define L4B(buf,n,ks) (*(const short8*)(lds4 + (buf)*49152 + 16384 + (wn*64+(n)*16+r)*128 + (((ks)*64+g16*16)^rsw)))
#define STG4A(buf,tile) do{ \
  gload16(A4 + (size_t)(row0 + 0*64 + wave*8 + srow)*K + (size_t)(tile)*64 + scsw, lds4 + (buf)*49152 + (0*64+wave*8)*128); \
  gload16(A4 + (size_t)(row0 + 1*64 + wave*8 + srow)*K + (size_t)(tile)*64 + scsw, lds4 + (buf)*49152 + (1*64+wave*8)*128); }while(0)
#define STG4B(buf,tile) do{ \
  gload16(B4 + (size_t)(col0 + 0*64 + wave*8 + srow)*K + (size_t)(tile)*64 + scsw, lds4 + (buf)*49152 + 16384 + (0*64+wave*8)*128); \
  gload16(B4 + (size_t)(col0 + 1*64 + wave*8 + srow)*K + (size_t)(tile)*64 + scsw, lds4 + (buf)*49152 + 16384 + (1*64+wave*8)*128); \
  gload16(B4 + (size_t)(col0 + 2*64 + wave*8 + srow)*K + (size_t)(tile)*64 + scsw, lds4 + (buf)*49152 + 16384 + (2*64+wave*8)*128); \
  gload16(B4 + (size_t)(col0 + 3*64 + wave*8 + srow)*K + (size_t)(tile)*64 + scsw, lds4 + (buf)*49152 + 16384 + (3*64+wave*8)*128); }while(0)
#define BLOAD4(bT) do{ \
  bfr4[0][0]=L4B(bT,0,0); bfr4[0][1]=L4B(bT,0,1); bfr4[1][0]=L4B(bT,1,0); bfr4[1][1]=L4B(bT,1,1); \
  bfr4[2][0]=L4B(bT,2,0); bfr4[2][1]=L4B(bT,2,1); bfr4[3][0]=L4B(bT,3,0); bfr4[3][1]=L4B(bT,3,1); }while(0)
#define MM44(mb,n) do{ \
  acc[mb][n]    =__builtin_amdgcn_mfma_f32_16x16x32_bf16(a0[0],bfr4[n][0],acc[mb][n],0,0,0); \
  acc[mb][n]    =__builtin_amdgcn_mfma_f32_16x16x32_bf16(a0[1],bfr4[n][1],acc[mb][n],0,0,0); \
  acc[(mb)+1][n]=__builtin_amdgcn_mfma_f32_16x16x32_bf16(a1[0],bfr4[n][0],acc[(mb)+1][n],0,0,0); \
  acc[(mb)+1][n]=__builtin_amdgcn_mfma_f32_16x16x32_bf16(a1[1],bfr4[n][1],acc[(mb)+1][n],0,0,0); }while(0)
#define PH4(bT, mb, STAGES, TAIL) do{ \
  short8 a0[2], a1[2]; \
  a0[0]=L4A(bT,mb,0); a0[1]=L4A(bT,mb,1); a1[0]=L4A(bT,(mb)+1,0); a1[1]=L4A(bT,(mb)+1,1); \
  STAGES; \
  __builtin_amdgcn_s_barrier(); \
  asm volatile("s_waitcnt lgkmcnt(0)" ::: "memory"); \
  __builtin_amdgcn_s_setprio(1); \
  MM44(mb,0); MM44(mb,1); MM44(mb,2); MM44(mb,3); \
  __builtin_amdgcn_s_setprio(0); \
  TAIL; \
  __builtin_amdgcn_s_barrier(); \
}while(0)

template<int EP>
__global__ __launch_bounds__(512, 2)
void gemm_4ph(const unsigned short* __restrict__ A, const unsigned short* __restrict__ Bw,
              void* __restrict__ C, const float* __restrict__ bias,
              int K, int ldc, int MB, int kLen){
  __shared__ char lds4[98304];
  const int tid = threadIdx.x;
  const int wave = tid>>6, lane = tid&63;
  const int wm = wave>>2, wn = wave&3;
  const int nwg = gridDim.x;
  const int pp = blockIdx.x;
  const int t = (nwg & 7) ? pp : ((pp & 7)*(nwg>>3) + (pp>>3));
  const int by = t % MB, bx = t / MB;
  const int row0 = by*128, col0 = bx*256;
  const int r = lane&15, g16 = lane>>4;
  const int rsw = (r&7)<<4;
  const int srow = lane>>3;
  const int scsw = ((lane&7) ^ srow)*8;
  const int kz = blockIdx.z;
  const unsigned short* A4 = A + (size_t)kz*kLen;
  const unsigned short* B4 = Bw + (size_t)kz*kLen;

  f32x4 acc[4][4] = {};
  short8 bfr4[4][2];
  const int NT = kLen/64;

  STG4B(0,0); STG4A(0,0); STG4B(1,1);
  VMC(4);
  __builtin_amdgcn_s_barrier();

  for (int T0 = 0; T0 < NT-2; T0 += 2){
    BLOAD4(0);
    PH4(0, 0, STG4A(1,T0+1), ((void)0));
    PH4(0, 2, STG4B(0,T0+2), VMC(4));
    BLOAD4(1);
    PH4(1, 0, STG4A(0,T0+2), ((void)0));
    PH4(1, 2, STG4B(1,T0+3), VMC(4));
  }
  BLOAD4(0);
  PH4(0, 0, STG4A(1,NT-1), ((void)0));
  PH4(0, 2, ((void)0), VMC(0));
  BLOAD4(1);
  PH4(1, 0, ((void)0), ((void)0));
  PH4(1, 2, ((void)0), ((void)0));

  float* Cp5 = (float*)C + (size_t)kz*M_*ldc;
  #pragma unroll
  for (int m=0;m<4;m++){
    const int row = row0 + wm*64 + m*16 + g16*4;
    #pragma unroll
    for (int n=0;n<4;n++){
      const int col = col0 + wn*64 + n*16 + r;
      #pragma unroll
      for (int j=0;j<4;j++){
        float val = acc[m][n][j];
        size_t idx = (size_t)(row+j)*ldc + col;
        if constexpr (EP==2) { val += bias[col]; val = 0.5f*val*(1.0f + erff(val*0.70710678118f)); }
        if constexpr (EP==0 || EP==2) ((unsigned short*)C)[idx] = f2bf(val);
        else Cp5[idx] = val;
      }
    }
  }
}

// ---------------- fused causal attention (flash-style, pipelined staging) ----------------
__global__ __launch_bounds__(256)
void attn_k(const unsigned short* __restrict__ qkv, unsigned short* __restrict__ o){
  __shared__ unsigned short Ks[2][64*64];
  __shared__ unsigned short Vt[2][64*64];
  __shared__ unsigned short Ps[4*16*64];
  const int tid = threadIdx.x;
  const int wave = tid>>6, lane = tid&63;
  const int qb = blockIdx.x, h = blockIdx.y, b = blockIdx.z;
  const int r = lane&15, g = lane>>4;
  const size_t rowbase = (size_t)b*S_*3*D_;
  const unsigned short* kbase = qkv + rowbase + D_ + h*64;
  const unsigned short* vbase = qkv + rowbase + 2*D_ + h*64;
  short8 qf[2];
  {
    const unsigned short* qp = qkv + rowbase + (size_t)(qb*64 + wave*16 + r)*(3*D_) + h*64 + g*8;
    short8 q0 = *reinterpret_cast<const short8*>(qp);
    short8 q1 = *reinterpret_cast<const short8*>(qp + 32);
    #pragma unroll
    for (int j=0;j<8;j++){
      qf[0][j] = (short)f2bf(bf2f((unsigned short)q0[j])*0.125f);
      qf[1][j] = (short)f2bf(bf2f((unsigned short)q1[j])*0.125f);
    }
  }
  float mrow[4] = {-INFINITY,-INFINITY,-INFINITY,-INFINITY};
  float lrow[4] = {0.f,0.f,0.f,0.f};
  f32x4 oacc[4] = {};
  const int qglob0 = qb*64 + wave*16 + g*4;
  unsigned short* Pw = Ps + wave*16*64;
  uint4 vdr[2];

  const int key8 = tid>>3;
  const int c8   = (tid&7)*8;
  const int kcsw = ((tid&7) ^ (key8&7))*16;

#define KSTG_A(nxt, kt2) do{ \
  gload16((const char*)(kbase + (size_t)((kt2)*64+key8)*(3*D_)) + kcsw, (char*)Ks[nxt] + wave*1024); \
  gload16((const char*)(kbase + (size_t)((kt2)*64+32+key8)*(3*D_)) + kcsw, (char*)Ks[nxt] + 4096 + wave*1024); \
}while(0)
#define VLOAD_A(kt2) do{ \
  vdr[0] = *reinterpret_cast<const uint4*>(vbase + (size_t)((kt2)*64+key8)*(3*D_) + c8); \
  vdr[1] = *reinterpret_cast<const uint4*>(vbase + (size_t)((kt2)*64+32+key8)*(3*D_) + c8); \
}while(0)
#define VSTORE_A(nxt) do{ \
  _Pragma("unroll") \
  for (int i=0;i<2;i++){ \
    int key = i*32 + key8; \
    const unsigned short* ve = reinterpret_cast<const unsigned short*>(&vdr[i]); \
    _Pragma("unroll") \
    for (int j=0;j<8;j++){ \
      int d = c8 + j; \
      int bo2 = (d*128 + key*2) ^ ((d&7)<<4); \
      *reinterpret_cast<unsigned short*>((char*)Vt[nxt] + bo2) = ve[j]; \
    } \
  } }while(0)

  KSTG_A(0, 0);
  VLOAD_A(0);
  VMC(0);
  VSTORE_A(0);
  __syncthreads();

  int cur = 0;
  for (int kt=0; kt<=qb; kt++){
    const bool pf = (kt < qb);
    if (pf){ KSTG_A(cur^1, kt+1); VLOAD_A(kt+1); }
    f32x4 sacc[4] = {};
    #pragma unroll
    for (int ks=0; ks<2; ks++){
      #pragma unroll
      for (int nb=0; nb<4; nb++){
        int key = nb*16 + r;
        int bo = (key*128 + (ks*32+g*8)*2) ^ ((key&7)<<4);
        short8 kf = *reinterpret_cast<const short8*>((char*)Ks[cur] + bo);
        sacc[nb] = __builtin_amdgcn_mfma_f32_16x16x32_bf16(qf[ks], kf, sacc[nb], 0,0,0);
      }
    }
    float sv[4][4];
    float tm[4] = {-INFINITY,-INFINITY,-INFINITY,-INFINITY};
    if (kt == qb){
      #pragma unroll
      for (int nb=0; nb<4; nb++){
        int key = kt*64 + nb*16 + r;
        #pragma unroll
        for (int j=0;j<4;j++){
          float s = (key <= qglob0 + j) ? sacc[nb][j] : -INFINITY;
          sv[nb][j] = s;
          tm[j] = fmaxf(tm[j], s);
        }
      }
    } else {
      #pragma unroll
      for (int nb=0; nb<4; nb++)
        #pragma unroll
        for (int j=0;j<4;j++){
          float s = sacc[nb][j];
          sv[nb][j] = s;
          tm[j] = fmaxf(tm[j], s);
        }
    }
    #pragma unroll
    for (int off=1; off<16; off<<=1){
      #pragma unroll
      for (int j=0;j<4;j++) tm[j] = fmaxf(tm[j], __shfl_xor(tm[j], off));
    }
    int chg = 0;
    float mn[4];
    #pragma unroll
    for (int j=0;j<4;j++){ mn[j] = fmaxf(mrow[j], tm[j]); chg |= (mn[j] > mrow[j]); }
    if (__any(chg)){
      #pragma unroll
      for (int j=0;j<4;j++){
        float sf = __expf(mrow[j]-mn[j]);
        mrow[j] = mn[j];
        lrow[j] *= sf;
        #pragma unroll
        for (int nb=0;nb<4;nb++) oacc[nb][j] *= sf;
      }
    }
    float psum[4] = {0.f,0.f,0.f,0.f};
    #pragma unroll
    for (int nb=0; nb<4; nb++){
      #pragma unroll
      for (int j=0;j<4;j++){
        float p = __expf(sv[nb][j]-mrow[j]);
        psum[j] += p;
        int prow = g*4+j;
        int bo = (prow*128 + (nb*16+r)*2) ^ ((prow&7)<<4);
        *reinterpret_cast<unsigned short*>((char*)Pw + bo) = f2bf(p);
      }
    }
    #pragma unroll
    for (int off=1; off<16; off<<=1){
      #pragma unroll
      for (int j=0;j<4;j++) psum[j] += __shfl_xor(psum[j], off);
    }
    #pragma unroll
    for (int j=0;j<4;j++) lrow[j] += psum[j];
    asm volatile("s_waitcnt lgkmcnt(0)" ::: "memory");
    #pragma unroll
    for (int ks=0; ks<2; ks++){
      int bo = (r*128 + (ks*32+g*8)*2) ^ ((r&7)<<4);
      short8 pf8 = *reinterpret_cast<const short8*>((char*)Pw + bo);
      #pragma unroll
      for (int nb=0; nb<4; nb++){
        int d = nb*16 + r;
        int bo2 = (d*128 + (ks*32+g*8)*2) ^ ((d&7)<<4);
        short8 vf = *reinterpret_cast<const short8*>((char*)Vt[cur] + bo2);
        oacc[nb] = __builtin_amdgcn_mfma_f32_16x16x32_bf16(pf8, vf, oacc[nb], 0,0,0);
      }
    }
    if (pf){ VMC(0); VSTORE_A(cur^1); }
    __syncthreads();
    cur ^= 1;
  }
  #pragma unroll
  for (int nb=0; nb<4; nb++){
    #pragma unroll
    for (int j=0;j<4;j++){
      float ov = oacc[nb][j] / lrow[j];
      size_t row = (size_t)b*S_ + qb*64 + wave*16 + g*4 + j;
      o[row*D_ + h*64 + nb*16 + r] = f2bf(ov);
    }
  }
}

extern "C" void kernel_launch(void* const* d_in, const int* in_sizes, int n_in,
                              void* d_out, int out_size, void* d_ws, size_t ws_size,
                              hipStream_t stream) {
  const int*   ids   = (const int*)  d_in[0];
  const float* emb   = (const float*)d_in[1];
  const float* Wq    = (const float*)d_in[2];
  const float* Wk    = (const float*)d_in[3];
  const float* Wv    = (const float*)d_in[4];
  const float* Wo    = (const float*)d_in[5];
  const float* W1    = (const float*)d_in[6];
  const float* b1    = (const float*)d_in[7];
  const float* W2    = (const float*)d_in[8];
  const float* b2    = (const float*)d_in[9];
  const float* ln1_g = (const float*)d_in[10];
  const float* ln1_b = (const float*)d_in[11];
  const float* ln2_g = (const float*)d_in[12];
  const float* ln2_b = (const float*)d_in[13];
  const float* lnf_g = (const float*)d_in[14];
  const float* lnf_b = (const float*)d_in[15];
  const float* headw = (const float*)d_in[16];

  unsigned short* ws = (unsigned short*)d_ws;
  unsigned short* wqkvT = ws;                                   // L*3*D*D
  unsigned short* woT   = wqkvT + (size_t)L_*3*D_*D_;           // L*D*D
  unsigned short* w1T   = woT   + (size_t)L_*D_*D_;             // L*DF*D
  unsigned short* w2T   = w1T   + (size_t)L_*D_*DF_;            // L*D*DF
  unsigned short* headT = w2T   + (size_t)L_*D_*DF_;            // V*D
  unsigned short* h     = headT + (size_t)V_*D_;                // M*D
  unsigned short* qkv   = h     + (size_t)M_*D_;                // M*3D
  unsigned short* attno = qkv   + (size_t)M_*3*D_;              // M*D
  unsigned short* h2    = attno + (size_t)M_*D_;                // M*DF
  float*          x     = (float*)(h2 + (size_t)M_*DF_);        // M*D f32
  float*          part  = x + (size_t)M_*D_;                    // 4*M*D f32 (KS=4)
  size_t needed = ((char*)(part + (size_t)4*M_*D_)) - (char*)d_ws;
  const bool splitk = (ws_size >= needed);

  // ---- weight prep ----
  transpose_k<<<dim3(D_/64, D_/64, L_), 256, 0, stream>>>(Wq, wqkvT,            D_, D_, (size_t)D_*D_, (size_t)3*D_*D_);
  transpose_k<<<dim3(D_/64, D_/64, L_), 256, 0, stream>>>(Wk, wqkvT + D_*D_,    D_, D_, (size_t)D_*D_, (size_t)3*D_*D_);
  transpose_k<<<dim3(D_/64, D_/64, L_), 256, 0, stream>>>(Wv, wqkvT + 2*D_*D_,  D_, D_, (size_t)D_*D_, (size_t)3*D_*D_);
  transpose_k<<<dim3(D_/64, D_/64, L_), 256, 0, stream>>>(Wo, woT,              D_, D_, (size_t)D_*D_, (size_t)D_*D_);
  transpose_k<<<dim3(DF_/64, D_/64, L_), 256, 0, stream>>>(W1, w1T,             D_, DF_, (size_t)D_*DF_, (size_t)D_*DF_);
  transpose_k<<<dim3(D_/64, DF_/64, L_), 256, 0, stream>>>(W2, w2T,             DF_, D_, (size_t)D_*DF_, (size_t)D_*DF_);
  transpose_k<<<dim3(V_/64, D_/64, 1), 256, 0, stream>>>(headw, headT,          D_, V_, 0, 0);

  // ---- embed + first LN ----
  embed_k<<<M_, 256, 0, stream>>>(ids, emb, x);
  ln_k<<<M_, 256, 0, stream>>>(x, ln1_g, ln1_b, h);

  // ---- layers (h holds ln1(x) entering each layer) ----
  for (int l = 0; l < L_; l++){
    gemm_4ph<0><<<dim3((3*D_/256)*(M_/128), 1, 1), 512, 0, stream>>>(h, wqkvT + (size_t)l*3*D_*D_, qkv, nullptr, D_, 3*D_, M_/128, D_);
    attn_k<<<dim3(S_/64, H_, B_), 256, 0, stream>>>(qkv, attno);
    if (splitk){
      gemm_4ph<5><<<dim3((D_/256)*(M_/128), 1, 4), 512, 0, stream>>>(attno, woT + (size_t)l*D_*D_, part, nullptr, D_, D_, M_/128, D_/4);
      rln_k<<<M_, 256, 0, stream>>>(x, part, nullptr, ln2_g + l*D_, ln2_b + l*D_, h, 4);
    } else {
      gemm_bt<1><<<dim3((D_/128)*(M_/128), 1, 1), 256, 0, stream>>>(attno, woT + (size_t)l*D_*D_, x, nullptr, x, D_, D_, M_/128, D_);
      ln_k<<<M_, 256, 0, stream>>>(x, ln2_g + l*D_, ln2_b + l*D_, h);
    }
    gemm_4ph<2><<<dim3((DF_/256)*(M_/128), 1, 1), 512, 0, stream>>>(h, w1T + (size_t)l*D_*DF_, h2, b1 + l*DF_, D_, DF_, M_/128, D_);
    const float* ng = (l+1 < L_) ? (ln1_g + (l+1)*D_) : lnf_g;
    const float* nb = (l+1 < L_) ? (ln1_b + (l+1)*D_) : lnf_b;
    if (splitk){
      gemm_4ph<5><<<dim3((D_/256)*(M_/128), 1, 4), 512, 0, stream>>>(h2, w2T + (size_t)l*D_*DF_, part, nullptr, DF_, D_, M_/128, DF_/4);
      rln_k<<<M_, 256, 0, stream>>>(x, part, b2 + l*D_, ng, nb, h, 4);
    } else {
      gemm_bt<3><<<dim3((D_/128)*(M_/128), 1, 1), 256, 0, stream>>>(h2, w2T + (size_t)l*D_*DF_, x, b2 + l*D_, x, DF_, D_, M_/128, DF_);
      ln_k<<<M_, 256, 0, stream>>>(x, ng, nb, h);
    }
  }

  // ---- head GEMM (h = lnf(x) already) ----
  gemm_8ph<<<dim3((V_/256)*(M_/256), 1, 1), 512, 0, stream>>>(h, headT, (float*)d_out, D_, V_, M_/256);
}

// Round 13
// 888.916 us; speedup vs baseline: 1.0353x; 1.0058x over previous
//
#include <hip/hip_runtime.h>
#include <stdint.h>

// Transformer prefill: B=2,S=1024,V=32000,D=1024,H=16,L=4,DK=64,DF=4096
#define B_ 2
#define S_ 1024
#define V_ 32000
#define D_ 1024
#define H_ 16
#define L_ 4
#define DF_ 4096
#define M_ (B_*S_)

typedef short short8 __attribute__((ext_vector_type(8)));
typedef float f32x4 __attribute__((ext_vector_type(4)));

__device__ __forceinline__ unsigned short f2bf(float f){
  union { float f; unsigned int u; } v; v.f = f;
  unsigned int u = v.u;
  u = u + 0x7fffu + ((u >> 16) & 1u);
  return (unsigned short)(u >> 16);
}

__device__ __forceinline__ float bf2f(unsigned short u){
  union { unsigned int u; float f; } v; v.u = ((unsigned int)u) << 16;
  return v.f;
}

__device__ __forceinline__ void gload16(const void* g, void* l){
  __builtin_amdgcn_global_load_lds(
      (__attribute__((address_space(1))) void*)(uintptr_t)g,
      (__attribute__((address_space(3))) void*)(uintptr_t)l, 16, 0, 0);
}

// ---------------- fused embed gather + first LN ----------------
__global__ __launch_bounds__(256) void embedln_k(const int* __restrict__ ids,
    const float* __restrict__ emb, const float* __restrict__ g,
    const float* __restrict__ b, float* __restrict__ x,
    unsigned short* __restrict__ out){
  int row = blockIdx.x;
  int tid = threadIdx.x;
  int id = ids[row];
  float4 v = reinterpret_cast<const float4*>(emb + (size_t)id*D_)[tid];
  reinterpret_cast<float4*>(x + (size_t)row*D_)[tid] = v;
  float s = v.x+v.y+v.z+v.w;
  float ss = v.x*v.x + v.y*v.y + v.z*v.z + v.w*v.w;
  #pragma unroll
  for (int off=1; off<64; off<<=1){ s += __shfl_xor(s, off); ss += __shfl_xor(ss, off); }
  __shared__ float rs[4], rss[4];
  int wave = tid>>6, lane = tid&63;
  if (lane==0){ rs[wave]=s; rss[wave]=ss; }
  __syncthreads();
  s  = rs[0]+rs[1]+rs[2]+rs[3];
  ss = rss[0]+rss[1]+rss[2]+rss[3];
  float mean = s * (1.0f/(float)D_);
  float var  = ss * (1.0f/(float)D_) - mean*mean;
  float inv = rsqrtf(var + 1e-5f);
  float4 gg = reinterpret_cast<const float4*>(g)[tid];
  float4 bb = reinterpret_cast<const float4*>(b)[tid];
  ushort4 o;
  o.x = f2bf((v.x-mean)*inv*gg.x + bb.x);
  o.y = f2bf((v.y-mean)*inv*gg.y + bb.y);
  o.z = f2bf((v.z-mean)*inv*gg.z + bb.z);
  o.w = f2bf((v.w-mean)*inv*gg.w + bb.w);
  reinterpret_cast<ushort4*>(out + (size_t)row*D_)[tid] = o;
}

// ---------------- layernorm: f32 in -> bf16 out ----------------
__global__ __launch_bounds__(256) void ln_k(const float* __restrict__ x,
    const float* __restrict__ g, const float* __restrict__ b,
    unsigned short* __restrict__ out){
  int row = blockIdx.x;
  int tid = threadIdx.x;
  float4 v = reinterpret_cast<const float4*>(x + (size_t)row*D_)[tid];
  float s = v.x+v.y+v.z+v.w;
  float ss = v.x*v.x + v.y*v.y + v.z*v.z + v.w*v.w;
  #pragma unroll
  for (int off=1; off<64; off<<=1){ s += __shfl_xor(s, off); ss += __shfl_xor(ss, off); }
  __shared__ float rs[4], rss[4];
  int wave = tid>>6, lane = tid&63;
  if (lane==0){ rs[wave]=s; rss[wave]=ss; }
  __syncthreads();
  s  = rs[0]+rs[1]+rs[2]+rs[3];
  ss = rss[0]+rss[1]+rss[2]+rss[3];
  float mean = s * (1.0f/(float)D_);
  float var  = ss * (1.0f/(float)D_) - mean*mean;
  float inv = rsqrtf(var + 1e-5f);
  float4 gg = reinterpret_cast<const float4*>(g)[tid];
  float4 bb = reinterpret_cast<const float4*>(b)[tid];
  ushort4 o;
  o.x = f2bf((v.x-mean)*inv*gg.x + bb.x);
  o.y = f2bf((v.y-mean)*inv*gg.y + bb.y);
  o.z = f2bf((v.z-mean)*inv*gg.z + bb.z);
  o.w = f2bf((v.w-mean)*inv*gg.w + bb.w);
  reinterpret_cast<ushort4*>(out + (size_t)row*D_)[tid] = o;
}

// ---------------- fused split-K reduce + residual + LN ----------------
__global__ __launch_bounds__(256) void rln_k(float* __restrict__ x,
    const float* __restrict__ part, const float* __restrict__ bias,
    const float* __restrict__ g, const float* __restrict__ b,
    unsigned short* __restrict__ out, int KS){
  int row = blockIdx.x;
  int tid = threadIdx.x;
  float4 v = reinterpret_cast<const float4*>(x + (size_t)row*D_)[tid];
  for (int z=0; z<KS; z++){
    float4 p = reinterpret_cast<const float4*>(part + (size_t)z*M_*D_ + (size_t)row*D_)[tid];
    v.x+=p.x; v.y+=p.y; v.z+=p.z; v.w+=p.w;
  }
  if (bias){
    float4 bb4 = reinterpret_cast<const float4*>(bias)[tid];
    v.x+=bb4.x; v.y+=bb4.y; v.z+=bb4.z; v.w+=bb4.w;
  }
  reinterpret_cast<float4*>(x + (size_t)row*D_)[tid] = v;
  float s = v.x+v.y+v.z+v.w;
  float ss = v.x*v.x + v.y*v.y + v.z*v.z + v.w*v.w;
  #pragma unroll
  for (int off=1; off<64; off<<=1){ s += __shfl_xor(s, off); ss += __shfl_xor(ss, off); }
  __shared__ float rs[4], rss[4];
  int wave = tid>>6, lane = tid&63;
  if (lane==0){ rs[wave]=s; rss[wave]=ss; }
  __syncthreads();
  s  = rs[0]+rs[1]+rs[2]+rs[3];
  ss = rss[0]+rss[1]+rss[2]+rss[3];
  float mean = s * (1.0f/(float)D_);
  float var  = ss * (1.0f/(float)D_) - mean*mean;
  float inv = rsqrtf(var + 1e-5f);
  float4 gg = reinterpret_cast<const float4*>(g)[tid];
  float4 bb = reinterpret_cast<const float4*>(b)[tid];
  ushort4 o;
  o.x = f2bf((v.x-mean)*inv*gg.x + bb.x);
  o.y = f2bf((v.y-mean)*inv*gg.y + bb.y);
  o.z = f2bf((v.z-mean)*inv*gg.z + bb.z);
  o.w = f2bf((v.w-mean)*inv*gg.w + bb.w);
  reinterpret_cast<ushort4*>(out + (size_t)row*D_)[tid] = o;
}

// ---------------- transpose + f32->bf16: in [K][N] -> out [N][K] ----------------
// 64x64 tiles; float4 loads; ushort8 (16B) stores — 8 lanes cover a contiguous
// 128B k-segment per n-row. LDS col-read bank pattern = 2 lanes/bank (free, m136).
__global__ __launch_bounds__(256) void transpose_k(const float* __restrict__ in,
    unsigned short* __restrict__ out, int K, int N, size_t in_ls, size_t out_ls){
  __shared__ float t[64][65];
  const float* inp = in + (size_t)blockIdx.z*in_ls;
  unsigned short* outp = out + (size_t)blockIdx.z*out_ls;
  int k0 = blockIdx.y*64, n0 = blockIdx.x*64;
  int rr = threadIdx.x >> 4, c4 = (threadIdx.x & 15)*4;
  #pragma unroll
  for (int i=0;i<4;i++){
    float4 v = *reinterpret_cast<const float4*>(inp + (size_t)(k0+rr+i*16)*N + n0 + c4);
    t[rr+i*16][c4+0]=v.x; t[rr+i*16][c4+1]=v.y; t[rr+i*16][c4+2]=v.z; t[rr+i*16][c4+3]=v.w;
  }
  __syncthreads();
  const int c8 = (threadIdx.x & 7)*8;
  const int nn = threadIdx.x >> 3;            // 0..31
  #pragma unroll
  for (int i=0;i<2;i++){
    const int n = nn + i*32;
    unsigned short o[8];
    #pragma unroll
    for (int j=0;j<8;j++) o[j] = f2bf(t[c8+j][n]);
    *reinterpret_cast<short8*>(outp + (size_t)(n0+n)*K + k0 + c8) =
        *reinterpret_cast<const short8*>(o);
  }
}

#define VMC(n)  asm volatile("s_waitcnt vmcnt(" #n ")" ::: "memory")

// ---------------- 256^2 8-phase GEMM (head) ----------------
#define LDA8(buf,m,ks) (*(const short8*)(lds8 + (buf)*65536 + (wm*128+(m)*16+r)*128 + (((ks)*64+g16*16)^rsw)))
#define LDB8(buf,n,ks) (*(const short8*)(lds8 + (buf)*65536 + 32768 + (wn*64+(n)*16+r)*128 + (((ks)*64+g16*16)^rsw)))
#define STG(buf,isB,h,i,tile) gload16( \
    ((isB) ? Bw + (size_t)(col0 + (h)*128 + (i)*64 + wave*8 + srow)*K + (size_t)(tile)*64 + scsw \
           : A  + (size_t)(row0 + (h)*128 + (i)*64 + wave*8 + srow)*K + (size_t)(tile)*64 + scsw), \
    lds8 + (buf)*65536 + (isB)*32768 + ((h)*128 + (i)*64 + wave*8)*128 )
#define STG_HT(buf,isB,h,tile) do{ STG(buf,isB,h,0,tile); STG(buf,isB,h,1,tile); }while(0)
#define BLOAD8(bT) do{ \
  bfr[0][0]=LDB8(bT,0,0); bfr[0][1]=LDB8(bT,0,1); bfr[1][0]=LDB8(bT,1,0); bfr[1][1]=LDB8(bT,1,1); \
  bfr[2][0]=LDB8(bT,2,0); bfr[2][1]=LDB8(bT,2,1); bfr[3][0]=LDB8(bT,3,0); bfr[3][1]=LDB8(bT,3,1); }while(0)
#define MM8(mb,n) do{ \
  acc[mb][n]    =__builtin_amdgcn_mfma_f32_16x16x32_bf16(a0[0],bfr[n][0],acc[mb][n],0,0,0); \
  acc[mb][n]    =__builtin_amdgcn_mfma_f32_16x16x32_bf16(a0[1],bfr[n][1],acc[mb][n],0,0,0); \
  acc[(mb)+1][n]=__builtin_amdgcn_mfma_f32_16x16x32_bf16(a1[0],bfr[n][0],acc[(mb)+1][n],0,0,0); \
  acc[(mb)+1][n]=__builtin_amdgcn_mfma_f32_16x16x32_bf16(a1[1],bfr[n][1],acc[(mb)+1][n],0,0,0); }while(0)
#define PH8(bT, mb, STAGES, TAIL) do{ \
  short8 a0[2], a1[2]; \
  a0[0]=LDA8(bT,mb,0); a0[1]=LDA8(bT,mb,1); a1[0]=LDA8(bT,(mb)+1,0); a1[1]=LDA8(bT,(mb)+1,1); \
  STAGES; \
  __builtin_amdgcn_s_barrier(); \
  asm volatile("s_waitcnt lgkmcnt(0)" ::: "memory"); \
  __builtin_amdgcn_s_setprio(1); \
  MM8(mb,0); MM8(mb,1); MM8(mb,2); MM8(mb,3); \
  __builtin_amdgcn_s_setprio(0); \
  TAIL; \
  __builtin_amdgcn_s_barrier(); \
}while(0)

__global__ __launch_bounds__(512, 2)
void gemm_8ph(const unsigned short* __restrict__ A, const unsigned short* __restrict__ Bw,
              float* __restrict__ C, int K, int ldc, int MB){
  __shared__ char lds8[131072];
  const int tid = threadIdx.x;
  const int wave = tid>>6, lane = tid&63;
  const int wm = wave>>2, wn = wave&3;
  const int nwg = gridDim.x;
  const int pp = blockIdx.x;
  const int t = (nwg & 7) ? pp : ((pp & 7)*(nwg>>3) + (pp>>3));
  const int by = t % MB, bx = t / MB;
  const int row0 = by*256, col0 = bx*256;
  const int r = lane&15, g16 = lane>>4;
  const int rsw = (r&7)<<4;
  const int srow = lane>>3;
  const int scsw = ((lane&7) ^ srow)*8;

  f32x4 acc[8][4] = {};
  short8 bfr[4][2];
  const int NT = K/64;

  STG_HT(0,1,0,0); STG_HT(0,1,1,0);
  STG_HT(0,0,0,0); STG_HT(0,0,1,0);
  STG_HT(1,1,0,1); STG_HT(1,1,1,1);
  VMC(4);
  __builtin_amdgcn_s_barrier();

  for (int T0 = 0; T0 < NT-2; T0 += 2){
    BLOAD8(0);
    PH8(0, 0, STG_HT(1,0,0,T0+1), ((void)0));
    PH8(0, 2, STG_HT(1,0,1,T0+1), ((void)0));
    PH8(0, 4, STG_HT(0,1,0,T0+2), ((void)0));
    PH8(0, 6, STG_HT(0,1,1,T0+2), VMC(4));
    BLOAD8(1);
    PH8(1, 0, STG_HT(0,0,0,T0+2), ((void)0));
    PH8(1, 2, STG_HT(0,0,1,T0+2), ((void)0));
    PH8(1, 4, STG_HT(1,1,0,T0+3), ((void)0));
    PH8(1, 6, STG_HT(1,1,1,T0+3), VMC(4));
  }
  BLOAD8(0);
  PH8(0, 0, STG_HT(1,0,0,NT-1), ((void)0));
  PH8(0, 2, STG_HT(1,0,1,NT-1), ((void)0));
  PH8(0, 4, ((void)0), ((void)0));
  PH8(0, 6, ((void)0), VMC(0));
  BLOAD8(1);
  PH8(1, 0, ((void)0), ((void)0));
  PH8(1, 2, ((void)0), ((void)0));
  PH8(1, 4, ((void)0), ((void)0));
  PH8(1, 6, ((void)0), ((void)0));

  #pragma unroll
  for (int m=0;m<8;m++){
    const int row = row0 + wm*128 + m*16 + g16*4;
    #pragma unroll
    for (int n=0;n<4;n++){
      const int col = col0 + wn*64 + n*16 + r;
      #pragma unroll
      for (int j=0;j<4;j++)
        C[(size_t)(row+j)*ldc + col] = acc[m][n][j];
    }
  }
}

// ---------------- 128x256 4-phase GEMM (layer GEMMs) ----------------
#define L4A(buf,m,ks) (*(const short8*)(lds4 + (buf)*49152 + (wm*64+(m)*16+r)*128 + (((ks)*64+g16*16)^rsw)))
#define L4B(buf,n,ks) (*(const short8*)(lds4 + (buf)*49152 + 16384 + (wn*64+(n)*16+r)*128 + (((ks)*64+g16*16)^rsw)))
#define STG4A(buf,tile) do{ \
  gload16(A4 + (size_t)(row0 + 0*64 + wave*8 + srow)*K + (size_t)(tile)*64 + scsw, lds4 + (buf)*49152 + (0*64+wave*8)*128); \
  gload16(A4 + (size_t)(row0 + 1*64 + wave*8 + srow)*K + (size_t)(tile)*64 + scsw, lds4 + (buf)*49152 + (1*64+wave*8)*128); }while(0)
#define STG4B(buf,tile) do{ \
  gload16(B4 + (size_t)(col0 + 0*64 + wave*8 + srow)*K + (size_t)(tile)*64 + scsw, lds4 + (buf)*49152 + 16384 + (0*64+wave*8)*128); \
  gload16(B4 + (size_t)(col0 + 1*64 + wave*8 + srow)*K + (size_t)(tile)*64 + scsw, lds4 + (buf)*49152 + 16384 + (1*64+wave*8)*128); \
  gload16(B4 + (size_t)(col0 + 2*64 + wave*8 + srow)*K + (size_t)(tile)*64 + scsw, lds4 + (buf)*49152 + 16384 + (2*64+wave*8)*128); \
  gload16(B4 + (size_t)(col0 + 3*64 + wave*8 + srow)*K + (size_t)(tile)*64 + scsw, lds4 + (buf)*49152 + 16384 + (3*64+wave*8)*128); }while(0)
#define BLOAD4(bT) do{ \
  bfr4[0][0]=L4B(bT,0,0); bfr4[0][1]=L4B(bT,0,1); bfr4[1][0]=L4B(bT,1,0); bfr4[1][1]=L4B(bT,1,1); \
  bfr4[2][0]=L4B(bT,2,0); bfr4[2][1]=L4B(bT,2,1); bfr4[3][0]=L4B(bT,3,0); bfr4[3][1]=L4B(bT,3,1); }while(0)
#define MM44(mb,n) do{ \
  acc[mb][n]    =__builtin_amdgcn_mfma_f32_16x16x32_bf16(a0[0],bfr4[n][0],acc[mb][n],0,0,0); \
  acc[mb][n]    =__builtin_amdgcn_mfma_f32_16x16x32_bf16(a0[1],bfr4[n][1],acc[mb][n],0,0,0); \
  acc[(mb)+1][n]=__builtin_amdgcn_mfma_f32_16x16x32_bf16(a1[0],bfr4[n][0],acc[(mb)+1][n],0,0,0); \
  acc[(mb)+1][n]=__builtin_amdgcn_mfma_f32_16x16x32_bf16(a1[1],bfr4[n][1],acc[(mb)+1][n],0,0,0); }while(0)
#define PH4(bT, mb, STAGES, TAIL) do{ \
  short8 a0[2], a1[2]; \
  a0[0]=L4A(bT,mb,0); a0[1]=L4A(bT,mb,1); a1[0]=L4A(bT,(mb)+1,0); a1[1]=L4A(bT,(mb)+1,1); \
  STAGES; \
  __builtin_amdgcn_s_barrier(); \
  asm volatile("s_waitcnt lgkmcnt(0)" ::: "memory"); \
  __builtin_amdgcn_s_setprio(1); \
  MM44(mb,0); MM44(mb,1); MM44(mb,2); MM44(mb,3); \
  __builtin_amdgcn_s_setprio(0); \
  TAIL; \
  __builtin_amdgcn_s_barrier(); \
}while(0)

template<int EP>
__global__ __launch_bounds__(512, 2)
void gemm_4ph(const unsigned short* __restrict__ A, const unsigned short* __restrict__ Bw,
              void* __restrict__ C, const float* __restrict__ bias,
              int K, int ldc, int MB, int kLen){
  __shared__ char lds4[98304];
  const int tid = threadIdx.x;
  const int wave = tid>>6, lane = tid&63;
  const int wm = wave>>2, wn = wave&3;
  const int nwg = gridDim.x;
  const int pp = blockIdx.x;
  const int t = (nwg & 7) ? pp : ((pp & 7)*(nwg>>3) + (pp>>3));
  const int by = t % MB, bx = t / MB;
  const int row0 = by*128, col0 = bx*256;
  const int r = lane&15, g16 = lane>>4;
  const int rsw = (r&7)<<4;
  const int srow = lane>>3;
  const int scsw = ((lane&7) ^ srow)*8;
  const int kz = blockIdx.z;
  const unsigned short* A4 = A + (size_t)kz*kLen;
  const unsigned short* B4 = Bw + (size_t)kz*kLen;

  f32x4 acc[4][4] = {};
  short8 bfr4[4][2];
  const int NT = kLen/64;

  STG4B(0,0); STG4A(0,0); STG4B(1,1);
  VMC(4);
  __builtin_amdgcn_s_barrier();

  for (int T0 = 0; T0 < NT-2; T0 += 2){
    BLOAD4(0);
    PH4(0, 0, STG4A(1,T0+1), ((void)0));
    PH4(0, 2, STG4B(0,T0+2), VMC(4));
    BLOAD4(1);
    PH4(1, 0, STG4A(0,T0+2), ((void)0));
    PH4(1, 2, STG4B(1,T0+3), VMC(4));
  }
  BLOAD4(0);
  PH4(0, 0, STG4A(1,NT-1), ((void)0));
  PH4(0, 2, ((void)0), VMC(0));
  BLOAD4(1);
  PH4(1, 0, ((void)0), ((void)0));
  PH4(1, 2, ((void)0), ((void)0));

  float* Cp5 = (float*)C + (size_t)kz*M_*ldc;
  #pragma unroll
  for (int m=0;m<4;m++){
    const int row = row0 + wm*64 + m*16 + g16*4;
    #pragma unroll
    for (int n=0;n<4;n++){
      const int col = col0 + wn*64 + n*16 + r;
      #pragma unroll
      for (int j=0;j<4;j++){
        float val = acc[m][n][j];
        size_t idx = (size_t)(row+j)*ldc + col;
        if constexpr (EP==2) { val += bias[col]; val = 0.5f*val*(1.0f + erff(val*0.70710678118f)); }
        if constexpr (EP==0 || EP==2) ((unsigned short*)C)[idx] = f2bf(val);
        else Cp5[idx] = val;
      }
    }
  }
}

// ---------------- fused causal attention (flash-style, pipelined staging) ----------------
__global__ __launch_bounds__(256)
void attn_k(const unsigned short* __restrict__ qkv, unsigned short* __restrict__ o){
  __shared__ unsigned short Ks[2][64*64];
  __shared__ unsigned short Vt[2][64*64];
  __shared__ unsigned short Ps[4*16*64];
  const int tid = threadIdx.x;
  const int wave = tid>>6, lane = tid&63;
  const int qb = blockIdx.x, h = blockIdx.y, b = blockIdx.z;
  const int r = lane&15, g = lane>>4;
  const size_t rowbase = (size_t)b*S_*3*D_;
  const unsigned short* kbase = qkv + rowbase + D_ + h*64;
  const unsigned short* vbase = qkv + rowbase + 2*D_ + h*64;
  short8 qf[2];
  {
    const unsigned short* qp = qkv + rowbase + (size_t)(qb*64 + wave*16 + r)*(3*D_) + h*64 + g*8;
    short8 q0 = *reinterpret_cast<const short8*>(qp);
    short8 q1 = *reinterpret_cast<const short8*>(qp + 32);
    #pragma unroll
    for (int j=0;j<8;j++){
      qf[0][j] = (short)f2bf(bf2f((unsigned short)q0[j])*0.125f);
      qf[1][j] = (short)f2bf(bf2f((unsigned short)q1[j])*0.125f);
    }
  }
  float mrow[4] = {-INFINITY,-INFINITY,-INFINITY,-INFINITY};
  float lrow[4] = {0.f,0.f,0.f,0.f};
  f32x4 oacc[4] = {};
  const int qglob0 = qb*64 + wave*16 + g*4;
  unsigned short* Pw = Ps + wave*16*64;
  uint4 vdr[2];

  const int key8 = tid>>3;
  const int c8   = (tid&7)*8;
  const int kcsw = ((tid&7) ^ (key8&7))*16;

#define KSTG_A(nxt, kt2) do{ \
  gload16((const char*)(kbase + (size_t)((kt2)*64+key8)*(3*D_)) + kcsw, (char*)Ks[nxt] + wave*1024); \
  gload16((const char*)(kbase + (size_t)((kt2)*64+32+key8)*(3*D_)) + kcsw, (char*)Ks[nxt] + 4096 + wave*1024); \
}while(0)
#define VLOAD_A(kt2) do{ \
  vdr[0] = *reinterpret_cast<const uint4*>(vbase + (size_t)((kt2)*64+key8)*(3*D_) + c8); \
  vdr[1] = *reinterpret_cast<const uint4*>(vbase + (size_t)((kt2)*64+32+key8)*(3*D_) + c8); \
}while(0)
#define VSTORE_A(nxt) do{ \
  _Pragma("unroll") \
  for (int i=0;i<2;i++){ \
    int key = i*32 + key8; \
    const unsigned short* ve = reinterpret_cast<const unsigned short*>(&vdr[i]); \
    _Pragma("unroll") \
    for (int j=0;j<8;j++){ \
      int d = c8 + j; \
      int bo2 = (d*128 + key*2) ^ ((d&7)<<4); \
      *reinterpret_cast<unsigned short*>((char*)Vt[nxt] + bo2) = ve[j]; \
    } \
  } }while(0)

  KSTG_A(0, 0);
  VLOAD_A(0);
  VMC(0);
  VSTORE_A(0);
  __syncthreads();

  int cur = 0;
  for (int kt=0; kt<=qb; kt++){
    const bool pf = (kt < qb);
    if (pf){ KSTG_A(cur^1, kt+1); VLOAD_A(kt+1); }
    f32x4 sacc[4] = {};
    #pragma unroll
    for (int ks=0; ks<2; ks++){
      #pragma unroll
      for (int nb=0; nb<4; nb++){
        int key = nb*16 + r;
        int bo = (key*128 + (ks*32+g*8)*2) ^ ((key&7)<<4);
        short8 kf = *reinterpret_cast<const short8*>((char*)Ks[cur] + bo);
        sacc[nb] = __builtin_amdgcn_mfma_f32_16x16x32_bf16(qf[ks], kf, sacc[nb], 0,0,0);
      }
    }
    float sv[4][4];
    float tm[4] = {-INFINITY,-INFINITY,-INFINITY,-INFINITY};
    if (kt == qb){
      #pragma unroll
      for (int nb=0; nb<4; nb++){
        int key = kt*64 + nb*16 + r;
        #pragma unroll
        for (int j=0;j<4;j++){
          float s = (key <= qglob0 + j) ? sacc[nb][j] : -INFINITY;
          sv[nb][j] = s;
          tm[j] = fmaxf(tm[j], s);
        }
      }
    } else {
      #pragma unroll
      for (int nb=0; nb<4; nb++)
        #pragma unroll
        for (int j=0;j<4;j++){
          float s = sacc[nb][j];
          sv[nb][j] = s;
          tm[j] = fmaxf(tm[j], s);
        }
    }
    #pragma unroll
    for (int off=1; off<16; off<<=1){
      #pragma unroll
      for (int j=0;j<4;j++) tm[j] = fmaxf(tm[j], __shfl_xor(tm[j], off));
    }
    int chg = 0;
    float mn[4];
    #pragma unroll
    for (int j=0;j<4;j++){ mn[j] = fmaxf(mrow[j], tm[j]); chg |= (mn[j] > mrow[j]); }
    if (__any(chg)){
      #pragma unroll
      for (int j=0;j<4;j++){
        float sf = __expf(mrow[j]-mn[j]);
        mrow[j] = mn[j];
        lrow[j] *= sf;
        #pragma unroll
        for (int nb=0;nb<4;nb++) oacc[nb][j] *= sf;
      }
    }
    float psum[4] = {0.f,0.f,0.f,0.f};
    #pragma unroll
    for (int nb=0; nb<4; nb++){
      #pragma unroll
      for (int j=0;j<4;j++){
        float p = __expf(sv[nb][j]-mrow[j]);
        psum[j] += p;
        int prow = g*4+j;
        int bo = (prow*128 + (nb*16+r)*2) ^ ((prow&7)<<4);
        *reinterpret_cast<unsigned short*>((char*)Pw + bo) = f2bf(p);
      }
    }
    #pragma unroll
    for (int off=1; off<16; off<<=1){
      #pragma unroll
      for (int j=0;j<4;j++) psum[j] += __shfl_xor(psum[j], off);
    }
    #pragma unroll
    for (int j=0;j<4;j++) lrow[j] += psum[j];
    asm volatile("s_waitcnt lgkmcnt(0)" ::: "memory");
    #pragma unroll
    for (int ks=0; ks<2; ks++){
      int bo = (r*128 + (ks*32+g*8)*2) ^ ((r&7)<<4);
      short8 pf8 = *reinterpret_cast<const short8*>((char*)Pw + bo);
      #pragma unroll
      for (int nb=0; nb<4; nb++){
        int d = nb*16 + r;
        int bo2 = (d*128 + (ks*32+g*8)*2) ^ ((d&7)<<4);
        short8 vf = *reinterpret_cast<const short8*>((char*)Vt[cur] + bo2);
        oacc[nb] = __builtin_amdgcn_mfma_f32_16x16x32_bf16(pf8, vf, oacc[nb], 0,0,0);
      }
    }
    if (pf){ VMC(0); VSTORE_A(cur^1); }
    __syncthreads();
    cur ^= 1;
  }
  #pragma unroll
  for (int nb=0; nb<4; nb++){
    #pragma unroll
    for (int j=0;j<4;j++){
      float ov = oacc[nb][j] / lrow[j];
      size_t row = (size_t)b*S_ + qb*64 + wave*16 + g*4 + j;
      o[row*D_ + h*64 + nb*16 + r] = f2bf(ov);
    }
  }
}

extern "C" void kernel_launch(void* const* d_in, const int* in_sizes, int n_in,
                              void* d_out, int out_size, void* d_ws, size_t ws_size,
                              hipStream_t stream) {
  const int*   ids   = (const int*)  d_in[0];
  const float* emb   = (const float*)d_in[1];
  const float* Wq    = (const float*)d_in[2];
  const float* Wk    = (const float*)d_in[3];
  const float* Wv    = (const float*)d_in[4];
  const float* Wo    = (const float*)d_in[5];
  const float* W1    = (const float*)d_in[6];
  const float* b1    = (const float*)d_in[7];
  const float* W2    = (const float*)d_in[8];
  const float* b2    = (const float*)d_in[9];
  const float* ln1_g = (const float*)d_in[10];
  const float* ln1_b = (const float*)d_in[11];
  const float* ln2_g = (const float*)d_in[12];
  const float* ln2_b = (const float*)d_in[13];
  const float* lnf_g = (const float*)d_in[14];
  const float* lnf_b = (const float*)d_in[15];
  const float* headw = (const float*)d_in[16];

  unsigned short* ws = (unsigned short*)d_ws;
  unsigned short* wqkvT = ws;                                   // L*3*D*D
  unsigned short* woT   = wqkvT + (size_t)L_*3*D_*D_;           // L*D*D
  unsigned short* w1T   = woT   + (size_t)L_*D_*D_;             // L*DF*D
  unsigned short* w2T   = w1T   + (size_t)L_*D_*DF_;            // L*D*DF
  unsigned short* headT = w2T   + (size_t)L_*D_*DF_;            // V*D
  unsigned short* h     = headT + (size_t)V_*D_;                // M*D
  unsigned short* qkv   = h     + (size_t)M_*D_;                // M*3D
  unsigned short* attno = qkv   + (size_t)M_*3*D_;              // M*D
  unsigned short* h2    = attno + (size_t)M_*D_;                // M*DF
  float*          x     = (float*)(h2 + (size_t)M_*DF_);        // M*D f32
  float*          part  = x + (size_t)M_*D_;                    // 4*M*D f32 (KS=4)
  size_t needed = ((char*)(part + (size_t)4*M_*D_)) - (char*)d_ws;
  const bool splitk = (ws_size >= needed);

  // ---- weight prep ----
  transpose_k<<<dim3(D_/64, D_/64, L_), 256, 0, stream>>>(Wq, wqkvT,            D_, D_, (size_t)D_*D_, (size_t)3*D_*D_);
  transpose_k<<<dim3(D_/64, D_/64, L_), 256, 0, stream>>>(Wk, wqkvT + D_*D_,    D_, D_, (size_t)D_*D_, (size_t)3*D_*D_);
  transpose_k<<<dim3(D_/64, D_/64, L_), 256, 0, stream>>>(Wv, wqkvT + 2*D_*D_,  D_, D_, (size_t)D_*D_, (size_t)3*D_*D_);
  transpose_k<<<dim3(D_/64, D_/64, L_), 256, 0, stream>>>(Wo, woT,              D_, D_, (size_t)D_*D_, (size_t)D_*D_);
  transpose_k<<<dim3(DF_/64, D_/64, L_), 256, 0, stream>>>(W1, w1T,             D_, DF_, (size_t)D_*DF_, (size_t)D_*DF_);
  transpose_k<<<dim3(D_/64, DF_/64, L_), 256, 0, stream>>>(W2, w2T,             DF_, D_, (size_t)D_*DF_, (size_t)D_*DF_);
  transpose_k<<<dim3(V_/64, D_/64, 1), 256, 0, stream>>>(headw, headT,          D_, V_, 0, 0);

  // ---- fused embed + first LN ----
  embedln_k<<<M_, 256, 0, stream>>>(ids, emb, ln1_g, ln1_b, x, h);

  // ---- layers (h holds ln1(x) entering each layer) ----
  for (int l = 0; l < L_; l++){
    gemm_4ph<0><<<dim3((3*D_/256)*(M_/128), 1, 1), 512, 0, stream>>>(h, wqkvT + (size_t)l*3*D_*D_, qkv, nullptr, D_, 3*D_, M_/128, D_);
    attn_k<<<dim3(S_/64, H_, B_), 256, 0, stream>>>(qkv, attno);
    gemm_4ph<5><<<dim3((D_/256)*(M_/128), 1, 4), 512, 0, stream>>>(attno, woT + (size_t)l*D_*D_, part, nullptr, D_, D_, M_/128, D_/4);
    rln_k<<<M_, 256, 0, stream>>>(x, part, nullptr, ln2_g + l*D_, ln2_b + l*D_, h, 4);
    gemm_4ph<2><<<dim3((DF_/256)*(M_/128), 1, 1), 512, 0, stream>>>(h, w1T + (size_t)l*D_*DF_, h2, b1 + l*DF_, D_, DF_, M_/128, D_);
    const float* ng = (l+1 < L_) ? (ln1_g + (l+1)*D_) : lnf_g;
    const float* nb = (l+1 < L_) ? (ln1_b + (l+1)*D_) : lnf_b;
    gemm_4ph<5><<<dim3((D_/256)*(M_/128), 1, 4), 512, 0, stream>>>(h2, w2T + (size_t)l*D_*DF_, part, nullptr, DF_, D_, M_/128, DF_/4);
    rln_k<<<M_, 256, 0, stream>>>(x, part, b2 + l*D_, ng, nb, h, 4);
  }

  // ---- head GEMM (h = lnf(x) already) ----
  gemm_8ph<<<dim3((V_/256)*(M_/256), 1, 1), 512, 0, stream>>>(h, headT, (float*)d_out, D_, V_, M_/256);
}

// Round 14
// 861.118 us; speedup vs baseline: 1.0687x; 1.0323x over previous
//
#include <hip/hip_runtime.h>
#include <stdint.h>

// Transformer prefill: B=2,S=1024,V=32000,D=1024,H=16,L=4,DK=64,DF=4096
#define B_ 2
#define S_ 1024
#define V_ 32000
#define D_ 1024
#define H_ 16
#define L_ 4
#define DF_ 4096
#define M_ (B_*S_)

typedef short short8 __attribute__((ext_vector_type(8)));
typedef float f32x4 __attribute__((ext_vector_type(4)));

__device__ __forceinline__ unsigned short f2bf(float f){
  union { float f; unsigned int u; } v; v.f = f;
  unsigned int u = v.u;
  u = u + 0x7fffu + ((u >> 16) & 1u);
  return (unsigned short)(u >> 16);
}

__device__ __forceinline__ float bf2f(unsigned short u){
  union { unsigned int u; float f; } v; v.u = ((unsigned int)u) << 16;
  return v.f;
}

__device__ __forceinline__ void gload16(const void* g, void* l){
  __builtin_amdgcn_global_load_lds(
      (__attribute__((address_space(1))) void*)(uintptr_t)g,
      (__attribute__((address_space(3))) void*)(uintptr_t)l, 16, 0, 0);
}

// ---------------- fused embed gather + first LN ----------------
__global__ __launch_bounds__(256) void embedln_k(const int* __restrict__ ids,
    const float* __restrict__ emb, const float* __restrict__ g,
    const float* __restrict__ b, float* __restrict__ x,
    unsigned short* __restrict__ out){
  int row = blockIdx.x;
  int tid = threadIdx.x;
  int id = ids[row];
  float4 v = reinterpret_cast<const float4*>(emb + (size_t)id*D_)[tid];
  reinterpret_cast<float4*>(x + (size_t)row*D_)[tid] = v;
  float s = v.x+v.y+v.z+v.w;
  float ss = v.x*v.x + v.y*v.y + v.z*v.z + v.w*v.w;
  #pragma unroll
  for (int off=1; off<64; off<<=1){ s += __shfl_xor(s, off); ss += __shfl_xor(ss, off); }
  __shared__ float rs[4], rss[4];
  int wave = tid>>6, lane = tid&63;
  if (lane==0){ rs[wave]=s; rss[wave]=ss; }
  __syncthreads();
  s  = rs[0]+rs[1]+rs[2]+rs[3];
  ss = rss[0]+rss[1]+rss[2]+rss[3];
  float mean = s * (1.0f/(float)D_);
  float var  = ss * (1.0f/(float)D_) - mean*mean;
  float inv = rsqrtf(var + 1e-5f);
  float4 gg = reinterpret_cast<const float4*>(g)[tid];
  float4 bb = reinterpret_cast<const float4*>(b)[tid];
  ushort4 o;
  o.x = f2bf((v.x-mean)*inv*gg.x + bb.x);
  o.y = f2bf((v.y-mean)*inv*gg.y + bb.y);
  o.z = f2bf((v.z-mean)*inv*gg.z + bb.z);
  o.w = f2bf((v.w-mean)*inv*gg.w + bb.w);
  reinterpret_cast<ushort4*>(out + (size_t)row*D_)[tid] = o;
}

// ---------------- layernorm: f32 in -> bf16 out ----------------
__global__ __launch_bounds__(256) void ln_k(const float* __restrict__ x,
    const float* __restrict__ g, const float* __restrict__ b,
    unsigned short* __restrict__ out){
  int row = blockIdx.x;
  int tid = threadIdx.x;
  float4 v = reinterpret_cast<const float4*>(x + (size_t)row*D_)[tid];
  float s = v.x+v.y+v.z+v.w;
  float ss = v.x*v.x + v.y*v.y + v.z*v.z + v.w*v.w;
  #pragma unroll
  for (int off=1; off<64; off<<=1){ s += __shfl_xor(s, off); ss += __shfl_xor(ss, off); }
  __shared__ float rs[4], rss[4];
  int wave = tid>>6, lane = tid&63;
  if (lane==0){ rs[wave]=s; rss[wave]=ss; }
  __syncthreads();
  s  = rs[0]+rs[1]+rs[2]+rs[3];
  ss = rss[0]+rss[1]+rss[2]+rss[3];
  float mean = s * (1.0f/(float)D_);
  float var  = ss * (1.0f/(float)D_) - mean*mean;
  float inv = rsqrtf(var + 1e-5f);
  float4 gg = reinterpret_cast<const float4*>(g)[tid];
  float4 bb = reinterpret_cast<const float4*>(b)[tid];
  ushort4 o;
  o.x = f2bf((v.x-mean)*inv*gg.x + bb.x);
  o.y = f2bf((v.y-mean)*inv*gg.y + bb.y);
  o.z = f2bf((v.z-mean)*inv*gg.z + bb.z);
  o.w = f2bf((v.w-mean)*inv*gg.w + bb.w);
  reinterpret_cast<ushort4*>(out + (size_t)row*D_)[tid] = o;
}

// ---------------- fused split-K reduce + residual + LN ----------------
__global__ __launch_bounds__(256) void rln_k(float* __restrict__ x,
    const float* __restrict__ part, const float* __restrict__ bias,
    const float* __restrict__ g, const float* __restrict__ b,
    unsigned short* __restrict__ out, int KS){
  int row = blockIdx.x;
  int tid = threadIdx.x;
  float4 v = reinterpret_cast<const float4*>(x + (size_t)row*D_)[tid];
  for (int z=0; z<KS; z++){
    float4 p = reinterpret_cast<const float4*>(part + (size_t)z*M_*D_ + (size_t)row*D_)[tid];
    v.x+=p.x; v.y+=p.y; v.z+=p.z; v.w+=p.w;
  }
  if (bias){
    float4 bb4 = reinterpret_cast<const float4*>(bias)[tid];
    v.x+=bb4.x; v.y+=bb4.y; v.z+=bb4.z; v.w+=bb4.w;
  }
  reinterpret_cast<float4*>(x + (size_t)row*D_)[tid] = v;
  float s = v.x+v.y+v.z+v.w;
  float ss = v.x*v.x + v.y*v.y + v.z*v.z + v.w*v.w;
  #pragma unroll
  for (int off=1; off<64; off<<=1){ s += __shfl_xor(s, off); ss += __shfl_xor(ss, off); }
  __shared__ float rs[4], rss[4];
  int wave = tid>>6, lane = tid&63;
  if (lane==0){ rs[wave]=s; rss[wave]=ss; }
  __syncthreads();
  s  = rs[0]+rs[1]+rs[2]+rs[3];
  ss = rss[0]+rss[1]+rss[2]+rss[3];
  float mean = s * (1.0f/(float)D_);
  float var  = ss * (1.0f/(float)D_) - mean*mean;
  float inv = rsqrtf(var + 1e-5f);
  float4 gg = reinterpret_cast<const float4*>(g)[tid];
  float4 bb = reinterpret_cast<const float4*>(b)[tid];
  ushort4 o;
  o.x = f2bf((v.x-mean)*inv*gg.x + bb.x);
  o.y = f2bf((v.y-mean)*inv*gg.y + bb.y);
  o.z = f2bf((v.z-mean)*inv*gg.z + bb.z);
  o.w = f2bf((v.w-mean)*inv*gg.w + bb.w);
  reinterpret_cast<ushort4*>(out + (size_t)row*D_)[tid] = o;
}

// ---------------- transpose + f32->bf16: in [K][N] -> out [N][K] ----------------
__global__ __launch_bounds__(256) void transpose_k(const float* __restrict__ in,
    unsigned short* __restrict__ out, int K, int N, size_t in_ls, size_t out_ls){
  __shared__ float t[64][65];
  const float* inp = in + (size_t)blockIdx.z*in_ls;
  unsigned short* outp = out + (size_t)blockIdx.z*out_ls;
  int k0 = blockIdx.y*64, n0 = blockIdx.x*64;
  int rr = threadIdx.x >> 4, c4 = (threadIdx.x & 15)*4;
  #pragma unroll
  for (int i=0;i<4;i++){
    float4 v = *reinterpret_cast<const float4*>(inp + (size_t)(k0+rr+i*16)*N + n0 + c4);
    t[rr+i*16][c4+0]=v.x; t[rr+i*16][c4+1]=v.y; t[rr+i*16][c4+2]=v.z; t[rr+i*16][c4+3]=v.w;
  }
  __syncthreads();
  const int c8 = (threadIdx.x & 7)*8;
  const int nn = threadIdx.x >> 3;
  #pragma unroll
  for (int i=0;i<2;i++){
    const int n = nn + i*32;
    unsigned short o[8];
    #pragma unroll
    for (int j=0;j<8;j++) o[j] = f2bf(t[c8+j][n]);
    *reinterpret_cast<short8*>(outp + (size_t)(n0+n)*K + k0 + c8) =
        *reinterpret_cast<const short8*>(o);
  }
}

#define VMC(n)  asm volatile("s_waitcnt vmcnt(" #n ")" ::: "memory")

// ---------------- 256^2 8-phase GEMM (head) ----------------
#define LDA8(buf,m,ks) (*(const short8*)(lds8 + (buf)*65536 + (wm*128+(m)*16+r)*128 + (((ks)*64+g16*16)^rsw)))
#define LDB8(buf,n,ks) (*(const short8*)(lds8 + (buf)*65536 + 32768 + (wn*64+(n)*16+r)*128 + (((ks)*64+g16*16)^rsw)))
#define STG(buf,isB,h,i,tile) gload16( \
    ((isB) ? Bw + (size_t)(col0 + (h)*128 + (i)*64 + wave*8 + srow)*K + (size_t)(tile)*64 + scsw \
           : A  + (size_t)(row0 + (h)*128 + (i)*64 + wave*8 + srow)*K + (size_t)(tile)*64 + scsw), \
    lds8 + (buf)*65536 + (isB)*32768 + ((h)*128 + (i)*64 + wave*8)*128 )
#define STG_HT(buf,isB,h,tile) do{ STG(buf,isB,h,0,tile); STG(buf,isB,h,1,tile); }while(0)
#define BLOAD8(bT) do{ \
  bfr[0][0]=LDB8(bT,0,0); bfr[0][1]=LDB8(bT,0,1); bfr[1][0]=LDB8(bT,1,0); bfr[1][1]=LDB8(bT,1,1); \
  bfr[2][0]=LDB8(bT,2,0); bfr[2][1]=LDB8(bT,2,1); bfr[3][0]=LDB8(bT,3,0); bfr[3][1]=LDB8(bT,3,1); }while(0)
#define MM8(mb,n) do{ \
  acc[mb][n]    =__builtin_amdgcn_mfma_f32_16x16x32_bf16(a0[0],bfr[n][0],acc[mb][n],0,0,0); \
  acc[mb][n]    =__builtin_amdgcn_mfma_f32_16x16x32_bf16(a0[1],bfr[n][1],acc[mb][n],0,0,0); \
  acc[(mb)+1][n]=__builtin_amdgcn_mfma_f32_16x16x32_bf16(a1[0],bfr[n][0],acc[(mb)+1][n],0,0,0); \
  acc[(mb)+1][n]=__builtin_amdgcn_mfma_f32_16x16x32_bf16(a1[1],bfr[n][1],acc[(mb)+1][n],0,0,0); }while(0)
#define PH8(bT, mb, STAGES, TAIL) do{ \
  short8 a0[2], a1[2]; \
  a0[0]=LDA8(bT,mb,0); a0[1]=LDA8(bT,mb,1); a1[0]=LDA8(bT,(mb)+1,0); a1[1]=LDA8(bT,(mb)+1,1); \
  STAGES; \
  __builtin_amdgcn_s_barrier(); \
  asm volatile("s_waitcnt lgkmcnt(0)" ::: "memory"); \
  __builtin_amdgcn_s_setprio(1); \
  MM8(mb,0); MM8(mb,1); MM8(mb,2); MM8(mb,3); \
  __builtin_amdgcn_s_setprio(0); \
  TAIL; \
  __builtin_amdgcn_s_barrier(); \
}while(0)

__global__ __launch_bounds__(512, 2)
void gemm_8ph(const unsigned short* __restrict__ A, const unsigned short* __restrict__ Bw,
              float* __restrict__ C, int K, int ldc, int MB){
  __shared__ char lds8[131072];
  const int tid = threadIdx.x;
  const int wave = tid>>6, lane = tid&63;
  const int wm = wave>>2, wn = wave&3;
  const int nwg = gridDim.x;
  const int pp = blockIdx.x;
  const int t = (nwg & 7) ? pp : ((pp & 7)*(nwg>>3) + (pp>>3));
  const int by = t % MB, bx = t / MB;
  const int row0 = by*256, col0 = bx*256;
  const int r = lane&15, g16 = lane>>4;
  const int rsw = (r&7)<<4;
  const int srow = lane>>3;
  const int scsw = ((lane&7) ^ srow)*8;

  f32x4 acc[8][4] = {};
  short8 bfr[4][2];
  const int NT = K/64;

  STG_HT(0,1,0,0); STG_HT(0,1,1,0);
  STG_HT(0,0,0,0); STG_HT(0,0,1,0);
  STG_HT(1,1,0,1); STG_HT(1,1,1,1);
  VMC(4);
  __builtin_amdgcn_s_barrier();

  for (int T0 = 0; T0 < NT-2; T0 += 2){
    BLOAD8(0);
    PH8(0, 0, STG_HT(1,0,0,T0+1), ((void)0));
    PH8(0, 2, STG_HT(1,0,1,T0+1), ((void)0));
    PH8(0, 4, STG_HT(0,1,0,T0+2), ((void)0));
    PH8(0, 6, STG_HT(0,1,1,T0+2), VMC(4));
    BLOAD8(1);
    PH8(1, 0, STG_HT(0,0,0,T0+2), ((void)0));
    PH8(1, 2, STG_HT(0,0,1,T0+2), ((void)0));
    PH8(1, 4, STG_HT(1,1,0,T0+3), ((void)0));
    PH8(1, 6, STG_HT(1,1,1,T0+3), VMC(4));
  }
  BLOAD8(0);
  PH8(0, 0, STG_HT(1,0,0,NT-1), ((void)0));
  PH8(0, 2, STG_HT(1,0,1,NT-1), ((void)0));
  PH8(0, 4, ((void)0), ((void)0));
  PH8(0, 6, ((void)0), VMC(0));
  BLOAD8(1);
  PH8(1, 0, ((void)0), ((void)0));
  PH8(1, 2, ((void)0), ((void)0));
  PH8(1, 4, ((void)0), ((void)0));
  PH8(1, 6, ((void)0), ((void)0));

  #pragma unroll
  for (int m=0;m<8;m++){
    const int row = row0 + wm*128 + m*16 + g16*4;
    #pragma unroll
    for (int n=0;n<4;n++){
      const int col = col0 + wn*64 + n*16 + r;
      #pragma unroll
      for (int j=0;j<4;j++)
        C[(size_t)(row+j)*ldc + col] = acc[m][n][j];
    }
  }
}

// ---------------- 128x256 4-phase GEMM (layer GEMMs) ----------------
#define L4A(buf,m,ks) (*(const short8*)(lds4 + (buf)*49152 + (wm*64+(m)*16+r)*128 + (((ks)*64+g16*16)^rsw)))
#define L4B(buf,n,ks) (*(const short8*)(lds4 + (buf)*49152 + 16384 + (wn*64+(n)*16+r)*128 + (((ks)*64+g16*16)^rsw)))
#define STG4A(buf,tile) do{ \
  gload16(A4 + (size_t)(row0 + 0*64 + wave*8 + srow)*K + (size_t)(tile)*64 + scsw, lds4 + (buf)*49152 + (0*64+wave*8)*128); \
  gload16(A4 + (size_t)(row0 + 1*64 + wave*8 + srow)*K + (size_t)(tile)*64 + scsw, lds4 + (buf)*49152 + (1*64+wave*8)*128); }while(0)
#define STG4B(buf,tile) do{ \
  gload16(B4 + (size_t)(col0 + 0*64 + wave*8 + srow)*K + (size_t)(tile)*64 + scsw, lds4 + (buf)*49152 + 16384 + (0*64+wave*8)*128); \
  gload16(B4 + (size_t)(col0 + 1*64 + wave*8 + srow)*K + (size_t)(tile)*64 + scsw, lds4 + (buf)*49152 + 16384 + (1*64+wave*8)*128); \
  gload16(B4 + (size_t)(col0 + 2*64 + wave*8 + srow)*K + (size_t)(tile)*64 + scsw, lds4 + (buf)*49152 + 16384 + (2*64+wave*8)*128); \
  gload16(B4 + (size_t)(col0 + 3*64 + wave*8 + srow)*K + (size_t)(tile)*64 + scsw, lds4 + (buf)*49152 + 16384 + (3*64+wave*8)*128); }while(0)
#define BLOAD4(bT) do{ \
  bfr4[0][0]=L4B(bT,0,0); bfr4[0][1]=L4B(bT,0,1); bfr4[1][0]=L4B(bT,1,0); bfr4[1][1]=L4B(bT,1,1); \
  bfr4[2][0]=L4B(bT,2,0); bfr4[2][1]=L4B(bT,2,1); bfr4[3][0]=L4B(bT,3,0); bfr4[3][1]=L4B(bT,3,1); }while(0)
#define MM44(mb,n) do{ \
  acc[mb][n]    =__builtin_amdgcn_mfma_f32_16x16x32_bf16(a0[0],bfr4[n][0],acc[mb][n],0,0,0); \
  acc[mb][n]    =__builtin_amdgcn_mfma_f32_16x16x32_bf16(a0[1],bfr4[n][1],acc[mb][n],0,0,0); \
  acc[(mb)+1][n]=__builtin_amdgcn_mfma_f32_16x16x32_bf16(a1[0],bfr4[n][0],acc[(mb)+1][n],0,0,0); \
  acc[(mb)+1][n]=__builtin_amdgcn_mfma_f32_16x16x32_bf16(a1[1],bfr4[n][1],acc[(mb)+1][n],0,0,0); }while(0)
#define PH4(bT, mb, STAGES, TAIL) do{ \
  short8 a0[2], a1[2]; \
  a0[0]=L4A(bT,mb,0); a0[1]=L4A(bT,mb,1); a1[0]=L4A(bT,(mb)+1,0); a1[1]=L4A(bT,(mb)+1,1); \
  STAGES; \
  __builtin_amdgcn_s_barrier(); \
  asm volatile("s_waitcnt lgkmcnt(0)" ::: "memory"); \
  __builtin_amdgcn_s_setprio(1); \
  MM44(mb,0); MM44(mb,1); MM44(mb,2); MM44(mb,3); \
  __builtin_amdgcn_s_setprio(0); \
  TAIL; \
  __builtin_amdgcn_s_barrier(); \
}while(0)

template<int EP>
__global__ __launch_bounds__(512, 2)
void gemm_4ph(const unsigned short* __restrict__ A, const unsigned short* __restrict__ Bw,
              void* __restrict__ C, const float* __restrict__ bias,
              int K, int ldc, int MB, int kLen){
  __shared__ char lds4[98304];
  const int tid = threadIdx.x;
  const int wave = tid>>6, lane = tid&63;
  const int wm = wave>>2, wn = wave&3;
  const int nwg = gridDim.x;
  const int pp = blockIdx.x;
  const int t = (nwg & 7) ? pp : ((pp & 7)*(nwg>>3) + (pp>>3));
  const int by = t % MB, bx = t / MB;
  const int row0 = by*128, col0 = bx*256;
  const int r = lane&15, g16 = lane>>4;
  const int rsw = (r&7)<<4;
  const int srow = lane>>3;
  const int scsw = ((lane&7) ^ srow)*8;
  const int kz = blockIdx.z;
  const unsigned short* A4 = A + (size_t)kz*kLen;
  const unsigned short* B4 = Bw + (size_t)kz*kLen;

  f32x4 acc[4][4] = {};
  short8 bfr4[4][2];
  const int NT = kLen/64;

  STG4B(0,0); STG4A(0,0); STG4B(1,1);
  VMC(4);
  __builtin_amdgcn_s_barrier();

  for (int T0 = 0; T0 < NT-2; T0 += 2){
    BLOAD4(0);
    PH4(0, 0, STG4A(1,T0+1), ((void)0));
    PH4(0, 2, STG4B(0,T0+2), VMC(4));
    BLOAD4(1);
    PH4(1, 0, STG4A(0,T0+2), ((void)0));
    PH4(1, 2, STG4B(1,T0+3), VMC(4));
  }
  BLOAD4(0);
  PH4(0, 0, STG4A(1,NT-1), ((void)0));
  PH4(0, 2, ((void)0), VMC(0));
  BLOAD4(1);
  PH4(1, 0, ((void)0), ((void)0));
  PH4(1, 2, ((void)0), ((void)0));

  float* Cp5 = (float*)C + (size_t)kz*M_*ldc;
  #pragma unroll
  for (int m=0;m<4;m++){
    const int row = row0 + wm*64 + m*16 + g16*4;
    #pragma unroll
    for (int n=0;n<4;n++){
      const int col = col0 + wn*64 + n*16 + r;
      #pragma unroll
      for (int j=0;j<4;j++){
        float val = acc[m][n][j];
        size_t idx = (size_t)(row+j)*ldc + col;
        if constexpr (EP==2) { val += bias[col]; val = 0.5f*val*(1.0f + erff(val*0.70710678118f)); }
        if constexpr (EP==0 || EP==2) ((unsigned short*)C)[idx] = f2bf(val);
        else Cp5[idx] = val;
      }
    }
  }
}

// ---------------- fused causal attention: KVBLK=128 (two 64-key halves / iter) ----------------
// Single merged softmax pass per 128 keys: one max-reduce, one rescale, one psum
// reduce, 2 barriers (all previously per-64). Per-half layout identical to the
// verified r8 kernel. Single-buffered LDS (48KB -> 3 blocks/CU; pipeline was null).
__global__ __launch_bounds__(256)
void attn_k(const unsigned short* __restrict__ qkv, unsigned short* __restrict__ o){
  __shared__ unsigned short Ks[2][64*64];
  __shared__ unsigned short Vt[2][64*64];
  __shared__ unsigned short Ps[2][4*16*64];
  const int tid = threadIdx.x;
  const int wave = tid>>6, lane = tid&63;
  const int qb = blockIdx.x, h = blockIdx.y, b = blockIdx.z;
  const int r = lane&15, g = lane>>4;
  const size_t rowbase = (size_t)b*S_*3*D_;
  const unsigned short* kbase = qkv + rowbase + D_ + h*64;
  const unsigned short* vbase = qkv + rowbase + 2*D_ + h*64;
  short8 qf[2];
  {
    const unsigned short* qp = qkv + rowbase + (size_t)(qb*64 + wave*16 + r)*(3*D_) + h*64 + g*8;
    short8 q0 = *reinterpret_cast<const short8*>(qp);
    short8 q1 = *reinterpret_cast<const short8*>(qp + 32);
    #pragma unroll
    for (int j=0;j<8;j++){
      qf[0][j] = (short)f2bf(bf2f((unsigned short)q0[j])*0.125f);
      qf[1][j] = (short)f2bf(bf2f((unsigned short)q1[j])*0.125f);
    }
  }
  float mrow[4] = {-INFINITY,-INFINITY,-INFINITY,-INFINITY};
  float lrow[4] = {0.f,0.f,0.f,0.f};
  f32x4 oacc[4] = {};
  const int qglob0 = qb*64 + wave*16 + g*4;
  unsigned short* Pw0 = Ps[0] + wave*16*64;
  unsigned short* Pw1 = Ps[1] + wave*16*64;
  uint4 vd0[2], vd1[2];

  const int key8 = tid>>3;
  const int c8   = (tid&7)*8;
  const int kcsw = ((tid&7) ^ (key8&7))*16;

#define KSTG2(i, hb) do{ \
  gload16((const char*)(kbase + (size_t)((hb)*64+key8)*(3*D_)) + kcsw, (char*)Ks[i] + wave*1024); \
  gload16((const char*)(kbase + (size_t)((hb)*64+32+key8)*(3*D_)) + kcsw, (char*)Ks[i] + 4096 + wave*1024); \
}while(0)
#define VLOAD2(vd, hb) do{ \
  vd[0] = *reinterpret_cast<const uint4*>(vbase + (size_t)((hb)*64+key8)*(3*D_) + c8); \
  vd[1] = *reinterpret_cast<const uint4*>(vbase + (size_t)((hb)*64+32+key8)*(3*D_) + c8); \
}while(0)
#define VSTORE2(i, vd) do{ \
  _Pragma("unroll") \
  for (int ii=0;ii<2;ii++){ \
    int key = ii*32 + key8; \
    const unsigned short* ve = reinterpret_cast<const unsigned short*>(&vd[ii]); \
    _Pragma("unroll") \
    for (int j=0;j<8;j++){ \
      int d = c8 + j; \
      int bo2 = (d*128 + key*2) ^ ((d&7)<<4); \
      *reinterpret_cast<unsigned short*>((char*)Vt[i] + bo2) = ve[j]; \
    } \
  } }while(0)
#define QKT2(sacc, i) do{ \
  _Pragma("unroll") \
  for (int ks=0; ks<2; ks++){ \
    _Pragma("unroll") \
    for (int nb=0; nb<4; nb++){ \
      int key = nb*16 + r; \
      int bo = (key*128 + (ks*32+g*8)*2) ^ ((key&7)<<4); \
      short8 kf = *reinterpret_cast<const short8*>((char*)Ks[i] + bo); \
      sacc[nb] = __builtin_amdgcn_mfma_f32_16x16x32_bf16(qf[ks], kf, sacc[nb], 0,0,0); \
    } \
  } }while(0)
#define PV2(i, PwX) do{ \
  _Pragma("unroll") \
  for (int ks=0; ks<2; ks++){ \
    int bo = (r*128 + (ks*32+g*8)*2) ^ ((r&7)<<4); \
    short8 pf8 = *reinterpret_cast<const short8*>((char*)(PwX) + bo); \
    _Pragma("unroll") \
    for (int nb=0; nb<4; nb++){ \
      int d = nb*16 + r; \
      int bo2 = (d*128 + (ks*32+g*8)*2) ^ ((d&7)<<4); \
      short8 vf = *reinterpret_cast<const short8*>((char*)Vt[i] + bo2); \
      oacc[nb] = __builtin_amdgcn_mfma_f32_16x16x32_bf16(pf8, vf, oacc[nb], 0,0,0); \
    } \
  } }while(0)

  for (int t = 0; 2*t <= qb; ++t){
    const int hb0 = 2*t;
    const bool v1 = (hb0 + 1 <= qb);
    // ---- stage both halves ----
    KSTG2(0, hb0);
    if (v1) KSTG2(1, hb0+1);
    VLOAD2(vd0, hb0);
    if (v1) VLOAD2(vd1, hb0+1);
    VMC(0);
    VSTORE2(0, vd0);
    if (v1) VSTORE2(1, vd1);
    __syncthreads();
    // ---- QK^T both halves ----
    f32x4 sacc0[4] = {}, sacc1[4] = {};
    QKT2(sacc0, 0);
    if (v1) QKT2(sacc1, 1);
    // ---- scores + local max (mask only on diagonal half) ----
    float sv0[4][4], sv1[4][4];
    float tm[4] = {-INFINITY,-INFINITY,-INFINITY,-INFINITY};
    if (hb0 == qb){
      #pragma unroll
      for (int nb=0; nb<4; nb++){
        int key = hb0*64 + nb*16 + r;
        #pragma unroll
        for (int j=0;j<4;j++){
          float s = (key <= qglob0 + j) ? sacc0[nb][j] : -INFINITY;
          sv0[nb][j] = s; tm[j] = fmaxf(tm[j], s);
        }
      }
    } else {
      #pragma unroll
      for (int nb=0; nb<4; nb++)
        #pragma unroll
        for (int j=0;j<4;j++){
          float s = sacc0[nb][j];
          sv0[nb][j] = s; tm[j] = fmaxf(tm[j], s);
        }
    }
    if (v1){
      if (hb0 + 1 == qb){
        #pragma unroll
        for (int nb=0; nb<4; nb++){
          int key = (hb0+1)*64 + nb*16 + r;
          #pragma unroll
          for (int j=0;j<4;j++){
            float s = (key <= qglob0 + j) ? sacc1[nb][j] : -INFINITY;
            sv1[nb][j] = s; tm[j] = fmaxf(tm[j], s);
          }
        }
      } else {
        #pragma unroll
        for (int nb=0; nb<4; nb++)
          #pragma unroll
          for (int j=0;j<4;j++){
            float s = sacc1[nb][j];
            sv1[nb][j] = s; tm[j] = fmaxf(tm[j], s);
          }
      }
    }
    // ---- single merged reduce + rescale ----
    #pragma unroll
    for (int off=1; off<16; off<<=1){
      #pragma unroll
      for (int j=0;j<4;j++) tm[j] = fmaxf(tm[j], __shfl_xor(tm[j], off));
    }
    int chg = 0;
    float mn[4];
    #pragma unroll
    for (int j=0;j<4;j++){ mn[j] = fmaxf(mrow[j], tm[j]); chg |= (mn[j] > mrow[j]); }
    if (__any(chg)){
      #pragma unroll
      for (int j=0;j<4;j++){
        float sf = __expf(mrow[j]-mn[j]);
        mrow[j] = mn[j];
        lrow[j] *= sf;
        #pragma unroll
        for (int nb=0;nb<4;nb++) oacc[nb][j] *= sf;
      }
    }
    // ---- exp + P writes (both halves) + single psum reduce ----
    float psum[4] = {0.f,0.f,0.f,0.f};
    #pragma unroll
    for (int nb=0; nb<4; nb++){
      #pragma unroll
      for (int j=0;j<4;j++){
        float p = __expf(sv0[nb][j]-mrow[j]);
        psum[j] += p;
        int prow = g*4+j;
        int bo = (prow*128 + (nb*16+r)*2) ^ ((prow&7)<<4);
        *reinterpret_cast<unsigned short*>((char*)Pw0 + bo) = f2bf(p);
      }
    }
    if (v1){
      #pragma unroll
      for (int nb=0; nb<4; nb++){
        #pragma unroll
        for (int j=0;j<4;j++){
          float p = __expf(sv1[nb][j]-mrow[j]);
          psum[j] += p;
          int prow = g*4+j;
          int bo = (prow*128 + (nb*16+r)*2) ^ ((prow&7)<<4);
          *reinterpret_cast<unsigned short*>((char*)Pw1 + bo) = f2bf(p);
        }
      }
    }
    #pragma unroll
    for (int off=1; off<16; off<<=1){
      #pragma unroll
      for (int j=0;j<4;j++) psum[j] += __shfl_xor(psum[j], off);
    }
    #pragma unroll
    for (int j=0;j<4;j++) lrow[j] += psum[j];
    asm volatile("s_waitcnt lgkmcnt(0)" ::: "memory");
    // ---- PV both halves ----
    PV2(0, Pw0);
    if (v1) PV2(1, Pw1);
    __syncthreads();
  }
  #pragma unroll
  for (int nb=0; nb<4; nb++){
    #pragma unroll
    for (int j=0;j<4;j++){
      float ov = oacc[nb][j] / lrow[j];
      size_t row = (size_t)b*S_ + qb*64 + wave*16 + g*4 + j;
      o[row*D_ + h*64 + nb*16 + r] = f2bf(ov);
    }
  }
}

extern "C" void kernel_launch(void* const* d_in, const int* in_sizes, int n_in,
                              void* d_out, int out_size, void* d_ws, size_t ws_size,
                              hipStream_t stream) {
  const int*   ids   = (const int*)  d_in[0];
  const float* emb   = (const float*)d_in[1];
  const float* Wq    = (const float*)d_in[2];
  const float* Wk    = (const float*)d_in[3];
  const float* Wv    = (const float*)d_in[4];
  const float* Wo    = (const float*)d_in[5];
  const float* W1    = (const float*)d_in[6];
  const float* b1    = (const float*)d_in[7];
  const float* W2    = (const float*)d_in[8];
  const float* b2    = (const float*)d_in[9];
  const float* ln1_g = (const float*)d_in[10];
  const float* ln1_b = (const float*)d_in[11];
  const float* ln2_g = (const float*)d_in[12];
  const float* ln2_b = (const float*)d_in[13];
  const float* lnf_g = (const float*)d_in[14];
  const float* lnf_b = (const float*)d_in[15];
  const float* headw = (const float*)d_in[16];

  unsigned short* ws = (unsigned short*)d_ws;
  unsigned short* wqkvT = ws;                                   // L*3*D*D
  unsigned short* woT   = wqkvT + (size_t)L_*3*D_*D_;           // L*D*D
  unsigned short* w1T   = woT   + (size_t)L_*D_*D_;             // L*DF*D
  unsigned short* w2T   = w1T   + (size_t)L_*D_*DF_;            // L*D*DF
  unsigned short* headT = w2T   + (size_t)L_*D_*DF_;            // V*D
  unsigned short* h     = headT + (size_t)V_*D_;                // M*D
  unsigned short* qkv   = h     + (size_t)M_*D_;                // M*3D
  unsigned short* attno = qkv   + (size_t)M_*3*D_;              // M*D
  unsigned short* h2    = attno + (size_t)M_*D_;                // M*DF
  float*          x     = (float*)(h2 + (size_t)M_*DF_);        // M*D f32
  float*          part  = x + (size_t)M_*D_;                    // 4*M*D f32 (KS=4)

  // ---- weight prep ----
  transpose_k<<<dim3(D_/64, D_/64, L_), 256, 0, stream>>>(Wq, wqkvT,            D_, D_, (size_t)D_*D_, (size_t)3*D_*D_);
  transpose_k<<<dim3(D_/64, D_/64, L_), 256, 0, stream>>>(Wk, wqkvT + D_*D_,    D_, D_, (size_t)D_*D_, (size_t)3*D_*D_);
  transpose_k<<<dim3(D_/64, D_/64, L_), 256, 0, stream>>>(Wv, wqkvT + 2*D_*D_,  D_, D_, (size_t)D_*D_, (size_t)3*D_*D_);
  transpose_k<<<dim3(D_/64, D_/64, L_), 256, 0, stream>>>(Wo, woT,              D_, D_, (size_t)D_*D_, (size_t)D_*D_);
  transpose_k<<<dim3(DF_/64, D_/64, L_), 256, 0, stream>>>(W1, w1T,             D_, DF_, (size_t)D_*DF_, (size_t)D_*DF_);
  transpose_k<<<dim3(D_/64, DF_/64, L_), 256, 0, stream>>>(W2, w2T,             DF_, D_, (size_t)D_*DF_, (size_t)D_*DF_);
  transpose_k<<<dim3(V_/64, D_/64, 1), 256, 0, stream>>>(headw, headT,          D_, V_, 0, 0);

  // ---- fused embed + first LN ----
  embedln_k<<<M_, 256, 0, stream>>>(ids, emb, ln1_g, ln1_b, x, h);

  // ---- layers (h holds ln1(x) entering each layer) ----
  for (int l = 0; l < L_; l++){
    gemm_4ph<0><<<dim3((3*D_/256)*(M_/128), 1, 1), 512, 0, stream>>>(h, wqkvT + (size_t)l*3*D_*D_, qkv, nullptr, D_, 3*D_, M_/128, D_);
    attn_k<<<dim3(S_/64, H_, B_), 256, 0, stream>>>(qkv, attno);
    gemm_4ph<5><<<dim3((D_/256)*(M_/128), 1, 4), 512, 0, stream>>>(attno, woT + (size_t)l*D_*D_, part, nullptr, D_, D_, M_/128, D_/4);
    rln_k<<<M_, 256, 0, stream>>>(x, part, nullptr, ln2_g + l*D_, ln2_b + l*D_, h, 4);
    gemm_4ph<2><<<dim3((DF_/256)*(M_/128), 1, 1), 512, 0, stream>>>(h, w1T + (size_t)l*D_*DF_, h2, b1 + l*DF_, D_, DF_, M_/128, D_);
    const float* ng = (l+1 < L_) ? (ln1_g + (l+1)*D_) : lnf_g;
    const float* nb = (l+1 < L_) ? (ln1_b + (l+1)*D_) : lnf_b;
    gemm_4ph<5><<<dim3((D_/256)*(M_/128), 1, 4), 512, 0, stream>>>(h2, w2T + (size_t)l*D_*DF_, part, nullptr, DF_, D_, M_/128, DF_/4);
    rln_k<<<M_, 256, 0, stream>>>(x, part, b2 + l*D_, ng, nb, h, 4);
  }

  // ---- head GEMM (h = lnf(x) already) ----
  gemm_8ph<<<dim3((V_/256)*(M_/256), 1, 1), 512, 0, stream>>>(h, headT, (float*)d_out, D_, V_, M_/256);
}

// Round 15
// 842.133 us; speedup vs baseline: 1.0928x; 1.0225x over previous
//
#include <hip/hip_runtime.h>
#include <stdint.h>

// Transformer prefill: B=2,S=1024,V=32000,D=1024,H=16,L=4,DK=64,DF=4096
#define B_ 2
#define S_ 1024
#define V_ 32000
#define D_ 1024
#define H_ 16
#define L_ 4
#define DF_ 4096
#define M_ (B_*S_)

typedef short short8 __attribute__((ext_vector_type(8)));
typedef float f32x4 __attribute__((ext_vector_type(4)));

__device__ __forceinline__ unsigned short f2bf(float f){
  union { float f; unsigned int u; } v; v.f = f;
  unsigned int u = v.u;
  u = u + 0x7fffu + ((u >> 16) & 1u);
  return (unsigned short)(u >> 16);
}

__device__ __forceinline__ float bf2f(unsigned short u){
  union { unsigned int u; float f; } v; v.u = ((unsigned int)u) << 16;
  return v.f;
}

__device__ __forceinline__ void gload16(const void* g, void* l){
  __builtin_amdgcn_global_load_lds(
      (__attribute__((address_space(1))) void*)(uintptr_t)g,
      (__attribute__((address_space(3))) void*)(uintptr_t)l, 16, 0, 0);
}

// ---------------- fused embed gather + first LN ----------------
__global__ __launch_bounds__(256) void embedln_k(const int* __restrict__ ids,
    const float* __restrict__ emb, const float* __restrict__ g,
    const float* __restrict__ b, float* __restrict__ x,
    unsigned short* __restrict__ out){
  int row = blockIdx.x;
  int tid = threadIdx.x;
  int id = ids[row];
  float4 v = reinterpret_cast<const float4*>(emb + (size_t)id*D_)[tid];
  reinterpret_cast<float4*>(x + (size_t)row*D_)[tid] = v;
  float s = v.x+v.y+v.z+v.w;
  float ss = v.x*v.x + v.y*v.y + v.z*v.z + v.w*v.w;
  #pragma unroll
  for (int off=1; off<64; off<<=1){ s += __shfl_xor(s, off); ss += __shfl_xor(ss, off); }
  __shared__ float rs[4], rss[4];
  int wave = tid>>6, lane = tid&63;
  if (lane==0){ rs[wave]=s; rss[wave]=ss; }
  __syncthreads();
  s  = rs[0]+rs[1]+rs[2]+rs[3];
  ss = rss[0]+rss[1]+rss[2]+rss[3];
  float mean = s * (1.0f/(float)D_);
  float var  = ss * (1.0f/(float)D_) - mean*mean;
  float inv = rsqrtf(var + 1e-5f);
  float4 gg = reinterpret_cast<const float4*>(g)[tid];
  float4 bb = reinterpret_cast<const float4*>(b)[tid];
  ushort4 o;
  o.x = f2bf((v.x-mean)*inv*gg.x + bb.x);
  o.y = f2bf((v.y-mean)*inv*gg.y + bb.y);
  o.z = f2bf((v.z-mean)*inv*gg.z + bb.z);
  o.w = f2bf((v.w-mean)*inv*gg.w + bb.w);
  reinterpret_cast<ushort4*>(out + (size_t)row*D_)[tid] = o;
}

// ---------------- layernorm: f32 in -> bf16 out ----------------
__global__ __launch_bounds__(256) void ln_k(const float* __restrict__ x,
    const float* __restrict__ g, const float* __restrict__ b,
    unsigned short* __restrict__ out){
  int row = blockIdx.x;
  int tid = threadIdx.x;
  float4 v = reinterpret_cast<const float4*>(x + (size_t)row*D_)[tid];
  float s = v.x+v.y+v.z+v.w;
  float ss = v.x*v.x + v.y*v.y + v.z*v.z + v.w*v.w;
  #pragma unroll
  for (int off=1; off<64; off<<=1){ s += __shfl_xor(s, off); ss += __shfl_xor(ss, off); }
  __shared__ float rs[4], rss[4];
  int wave = tid>>6, lane = tid&63;
  if (lane==0){ rs[wave]=s; rss[wave]=ss; }
  __syncthreads();
  s  = rs[0]+rs[1]+rs[2]+rs[3];
  ss = rss[0]+rss[1]+rss[2]+rss[3];
  float mean = s * (1.0f/(float)D_);
  float var  = ss * (1.0f/(float)D_) - mean*mean;
  float inv = rsqrtf(var + 1e-5f);
  float4 gg = reinterpret_cast<const float4*>(g)[tid];
  float4 bb = reinterpret_cast<const float4*>(b)[tid];
  ushort4 o;
  o.x = f2bf((v.x-mean)*inv*gg.x + bb.x);
  o.y = f2bf((v.y-mean)*inv*gg.y + bb.y);
  o.z = f2bf((v.z-mean)*inv*gg.z + bb.z);
  o.w = f2bf((v.w-mean)*inv*gg.w + bb.w);
  reinterpret_cast<ushort4*>(out + (size_t)row*D_)[tid] = o;
}

// ---------------- fused split-K reduce + residual + LN ----------------
__global__ __launch_bounds__(256) void rln_k(float* __restrict__ x,
    const float* __restrict__ part, const float* __restrict__ bias,
    const float* __restrict__ g, const float* __restrict__ b,
    unsigned short* __restrict__ out, int KS){
  int row = blockIdx.x;
  int tid = threadIdx.x;
  float4 v = reinterpret_cast<const float4*>(x + (size_t)row*D_)[tid];
  for (int z=0; z<KS; z++){
    float4 p = reinterpret_cast<const float4*>(part + (size_t)z*M_*D_ + (size_t)row*D_)[tid];
    v.x+=p.x; v.y+=p.y; v.z+=p.z; v.w+=p.w;
  }
  if (bias){
    float4 bb4 = reinterpret_cast<const float4*>(bias)[tid];
    v.x+=bb4.x; v.y+=bb4.y; v.z+=bb4.z; v.w+=bb4.w;
  }
  reinterpret_cast<float4*>(x + (size_t)row*D_)[tid] = v;
  float s = v.x+v.y+v.z+v.w;
  float ss = v.x*v.x + v.y*v.y + v.z*v.z + v.w*v.w;
  #pragma unroll
  for (int off=1; off<64; off<<=1){ s += __shfl_xor(s, off); ss += __shfl_xor(ss, off); }
  __shared__ float rs[4], rss[4];
  int wave = tid>>6, lane = tid&63;
  if (lane==0){ rs[wave]=s; rss[wave]=ss; }
  __syncthreads();
  s  = rs[0]+rs[1]+rs[2]+rs[3];
  ss = rss[0]+rss[1]+rss[2]+rss[3];
  float mean = s * (1.0f/(float)D_);
  float var  = ss * (1.0f/(float)D_) - mean*mean;
  float inv = rsqrtf(var + 1e-5f);
  float4 gg = reinterpret_cast<const float4*>(g)[tid];
  float4 bb = reinterpret_cast<const float4*>(b)[tid];
  ushort4 o;
  o.x = f2bf((v.x-mean)*inv*gg.x + bb.x);
  o.y = f2bf((v.y-mean)*inv*gg.y + bb.y);
  o.z = f2bf((v.z-mean)*inv*gg.z + bb.z);
  o.w = f2bf((v.w-mean)*inv*gg.w + bb.w);
  reinterpret_cast<ushort4*>(out + (size_t)row*D_)[tid] = o;
}

// ---------------- transpose + f32->bf16: in [K][N] -> out [N][K] ----------------
__global__ __launch_bounds__(256) void transpose_k(const float* __restrict__ in,
    unsigned short* __restrict__ out, int K, int N, size_t in_ls, size_t out_ls){
  __shared__ float t[64][65];
  const float* inp = in + (size_t)blockIdx.z*in_ls;
  unsigned short* outp = out + (size_t)blockIdx.z*out_ls;
  int k0 = blockIdx.y*64, n0 = blockIdx.x*64;
  int rr = threadIdx.x >> 4, c4 = (threadIdx.x & 15)*4;
  #pragma unroll
  for (int i=0;i<4;i++){
    float4 v = *reinterpret_cast<const float4*>(inp + (size_t)(k0+rr+i*16)*N + n0 + c4);
    t[rr+i*16][c4+0]=v.x; t[rr+i*16][c4+1]=v.y; t[rr+i*16][c4+2]=v.z; t[rr+i*16][c4+3]=v.w;
  }
  __syncthreads();
  const int c8 = (threadIdx.x & 7)*8;
  const int nn = threadIdx.x >> 3;
  #pragma unroll
  for (int i=0;i<2;i++){
    const int n = nn + i*32;
    unsigned short o[8];
    #pragma unroll
    for (int j=0;j<8;j++) o[j] = f2bf(t[c8+j][n]);
    *reinterpret_cast<short8*>(outp + (size_t)(n0+n)*K + k0 + c8) =
        *reinterpret_cast<const short8*>(o);
  }
}

#define VMC(n)  asm volatile("s_waitcnt vmcnt(" #n ")" ::: "memory")

// ---------------- 256^2 8-phase GEMM (head) ----------------
#define LDA8(buf,m,ks) (*(const short8*)(lds8 + (buf)*65536 + (wm*128+(m)*16+r)*128 + (((ks)*64+g16*16)^rsw)))
#define LDB8(buf,n,ks) (*(const short8*)(lds8 + (buf)*65536 + 32768 + (wn*64+(n)*16+r)*128 + (((ks)*64+g16*16)^rsw)))
#define STG(buf,isB,h,i,tile) gload16( \
    ((isB) ? Bw + (size_t)(col0 + (h)*128 + (i)*64 + wave*8 + srow)*K + (size_t)(tile)*64 + scsw \
           : A  + (size_t)(row0 + (h)*128 + (i)*64 + wave*8 + srow)*K + (size_t)(tile)*64 + scsw), \
    lds8 + (buf)*65536 + (isB)*32768 + ((h)*128 + (i)*64 + wave*8)*128 )
#define STG_HT(buf,isB,h,tile) do{ STG(buf,isB,h,0,tile); STG(buf,isB,h,1,tile); }while(0)
#define BLOAD8(bT) do{ \
  bfr[0][0]=LDB8(bT,0,0); bfr[0][1]=LDB8(bT,0,1); bfr[1][0]=LDB8(bT,1,0); bfr[1][1]=LDB8(bT,1,1); \
  bfr[2][0]=LDB8(bT,2,0); bfr[2][1]=LDB8(bT,2,1); bfr[3][0]=LDB8(bT,3,0); bfr[3][1]=LDB8(bT,3,1); }while(0)
#define MM8(mb,n) do{ \
  acc[mb][n]    =__builtin_amdgcn_mfma_f32_16x16x32_bf16(a0[0],bfr[n][0],acc[mb][n],0,0,0); \
  acc[mb][n]    =__builtin_amdgcn_mfma_f32_16x16x32_bf16(a0[1],bfr[n][1],acc[mb][n],0,0,0); \
  acc[(mb)+1][n]=__builtin_amdgcn_mfma_f32_16x16x32_bf16(a1[0],bfr[n][0],acc[(mb)+1][n],0,0,0); \
  acc[(mb)+1][n]=__builtin_amdgcn_mfma_f32_16x16x32_bf16(a1[1],bfr[n][1],acc[(mb)+1][n],0,0,0); }while(0)
#define PH8(bT, mb, STAGES, TAIL) do{ \
  short8 a0[2], a1[2]; \
  a0[0]=LDA8(bT,mb,0); a0[1]=LDA8(bT,mb,1); a1[0]=LDA8(bT,(mb)+1,0); a1[1]=LDA8(bT,(mb)+1,1); \
  STAGES; \
  __builtin_amdgcn_s_barrier(); \
  asm volatile("s_waitcnt lgkmcnt(0)" ::: "memory"); \
  __builtin_amdgcn_s_setprio(1); \
  MM8(mb,0); MM8(mb,1); MM8(mb,2); MM8(mb,3); \
  __builtin_amdgcn_s_setprio(0); \
  TAIL; \
  __builtin_amdgcn_s_barrier(); \
}while(0)

__global__ __launch_bounds__(512, 2)
void gemm_8ph(const unsigned short* __restrict__ A, const unsigned short* __restrict__ Bw,
              float* __restrict__ C, int K, int ldc, int MB){
  __shared__ char lds8[131072];
  const int tid = threadIdx.x;
  const int wave = tid>>6, lane = tid&63;
  const int wm = wave>>2, wn = wave&3;
  const int nwg = gridDim.x;
  const int pp = blockIdx.x;
  const int t = (nwg & 7) ? pp : ((pp & 7)*(nwg>>3) + (pp>>3));
  const int by = t % MB, bx = t / MB;
  const int row0 = by*256, col0 = bx*256;
  const int r = lane&15, g16 = lane>>4;
  const int rsw = (r&7)<<4;
  const int srow = lane>>3;
  const int scsw = ((lane&7) ^ srow)*8;

  f32x4 acc[8][4] = {};
  short8 bfr[4][2];
  const int NT = K/64;

  STG_HT(0,1,0,0); STG_HT(0,1,1,0);
  STG_HT(0,0,0,0); STG_HT(0,0,1,0);
  STG_HT(1,1,0,1); STG_HT(1,1,1,1);
  VMC(4);
  __builtin_amdgcn_s_barrier();

  for (int T0 = 0; T0 < NT-2; T0 += 2){
    BLOAD8(0);
    PH8(0, 0, STG_HT(1,0,0,T0+1), ((void)0));
    PH8(0, 2, STG_HT(1,0,1,T0+1), ((void)0));
    PH8(0, 4, STG_HT(0,1,0,T0+2), ((void)0));
    PH8(0, 6, STG_HT(0,1,1,T0+2), VMC(4));
    BLOAD8(1);
    PH8(1, 0, STG_HT(0,0,0,T0+2), ((void)0));
    PH8(1, 2, STG_HT(0,0,1,T0+2), ((void)0));
    PH8(1, 4, STG_HT(1,1,0,T0+3), ((void)0));
    PH8(1, 6, STG_HT(1,1,1,T0+3), VMC(4));
  }
  BLOAD8(0);
  PH8(0, 0, STG_HT(1,0,0,NT-1), ((void)0));
  PH8(0, 2, STG_HT(1,0,1,NT-1), ((void)0));
  PH8(0, 4, ((void)0), ((void)0));
  PH8(0, 6, ((void)0), VMC(0));
  BLOAD8(1);
  PH8(1, 0, ((void)0), ((void)0));
  PH8(1, 2, ((void)0), ((void)0));
  PH8(1, 4, ((void)0), ((void)0));
  PH8(1, 6, ((void)0), ((void)0));

  #pragma unroll
  for (int m=0;m<8;m++){
    const int row = row0 + wm*128 + m*16 + g16*4;
    #pragma unroll
    for (int n=0;n<4;n++){
      const int col = col0 + wn*64 + n*16 + r;
      #pragma unroll
      for (int j=0;j<4;j++)
        C[(size_t)(row+j)*ldc + col] = acc[m][n][j];
    }
  }
}

// ---------------- 128x256 4-phase GEMM (layer GEMMs) ----------------
#define L4A(buf,m,ks) (*(const short8*)(lds4 + (buf)*49152 + (wm*64+(m)*16+r)*128 + (((ks)*64+g16*16)^rsw)))
#define L4B(buf,n,ks) (*(const short8*)(lds4 + (buf)*49152 + 16384 + (wn*64+(n)*16+r)*128 + (((ks)*64+g16*16)^rsw)))
#define STG4A(buf,tile) do{ \
  gload16(A4 + (size_t)(row0 + 0*64 + wave*8 + srow)*K + (size_t)(tile)*64 + scsw, lds4 + (buf)*49152 + (0*64+wave*8)*128); \
  gload16(A4 + (size_t)(row0 + 1*64 + wave*8 + srow)*K + (size_t)(tile)*64 + scsw, lds4 + (buf)*49152 + (1*64+wave*8)*128); }while(0)
#define STG4B(buf,tile) do{ \
  gload16(B4 + (size_t)(col0 + 0*64 + wave*8 + srow)*K + (size_t)(tile)*64 + scsw, lds4 + (buf)*49152 + 16384 + (0*64+wave*8)*128); \
  gload16(B4 + (size_t)(col0 + 1*64 + wave*8 + srow)*K + (size_t)(tile)*64 + scsw, lds4 + (buf)*49152 + 16384 + (1*64+wave*8)*128); \
  gload16(B4 + (size_t)(col0 + 2*64 + wave*8 + srow)*K + (size_t)(tile)*64 + scsw, lds4 + (buf)*49152 + 16384 + (2*64+wave*8)*128); \
  gload16(B4 + (size_t)(col0 + 3*64 + wave*8 + srow)*K + (size_t)(tile)*64 + scsw, lds4 + (buf)*49152 + 16384 + (3*64+wave*8)*128); }while(0)
#define BLOAD4(bT) do{ \
  bfr4[0][0]=L4B(bT,0,0); bfr4[0][1]=L4B(bT,0,1); bfr4[1][0]=L4B(bT,1,0); bfr4[1][1]=L4B(bT,1,1); \
  bfr4[2][0]=L4B(bT,2,0); bfr4[2][1]=L4B(bT,2,1); bfr4[3][0]=L4B(bT,3,0); bfr4[3][1]=L4B(bT,3,1); }while(0)
#define MM44(mb,n) do{ \
  acc[mb][n]    =__builtin_amdgcn_mfma_f32_16x16x32_bf16(a0[0],bfr4[n][0],acc[mb][n],0,0,0); \
  acc[mb][n]    =__builtin_amdgcn_mfma_f32_16x16x32_bf16(a0[1],bfr4[n][1],acc[mb][n],0,0,0); \
  acc[(mb)+1][n]=__builtin_amdgcn_mfma_f32_16x16x32_bf16(a1[0],bfr4[n][0],acc[(mb)+1][n],0,0,0); \
  acc[(mb)+1][n]=__builtin_amdgcn_mfma_f32_16x16x32_bf16(a1[1],bfr4[n][1],acc[(mb)+1][n],0,0,0); }while(0)
#define PH4(bT, mb, STAGES, TAIL) do{ \
  short8 a0[2], a1[2]; \
  a0[0]=L4A(bT,mb,0); a0[1]=L4A(bT,mb,1); a1[0]=L4A(bT,(mb)+1,0); a1[1]=L4A(bT,(mb)+1,1); \
  STAGES; \
  __builtin_amdgcn_s_barrier(); \
  asm volatile("s_waitcnt lgkmcnt(0)" ::: "memory"); \
  __builtin_amdgcn_s_setprio(1); \
  MM44(mb,0); MM44(mb,1); MM44(mb,2); MM44(mb,3); \
  __builtin_amdgcn_s_setprio(0); \
  TAIL; \
  __builtin_amdgcn_s_barrier(); \
}while(0)

template<int EP>
__global__ __launch_bounds__(512, 2)
void gemm_4ph(const unsigned short* __restrict__ A, const unsigned short* __restrict__ Bw,
              void* __restrict__ C, const float* __restrict__ bias,
              int K, int ldc, int MB, int kLen){
  __shared__ char lds4[98304];
  const int tid = threadIdx.x;
  const int wave = tid>>6, lane = tid&63;
  const int wm = wave>>2, wn = wave&3;
  const int nwg = gridDim.x;
  const int pp = blockIdx.x;
  const int t = (nwg & 7) ? pp : ((pp & 7)*(nwg>>3) + (pp>>3));
  const int by = t % MB, bx = t / MB;
  const int row0 = by*128, col0 = bx*256;
  const int r = lane&15, g16 = lane>>4;
  const int rsw = (r&7)<<4;
  const int srow = lane>>3;
  const int scsw = ((lane&7) ^ srow)*8;
  const int kz = blockIdx.z;
  const unsigned short* A4 = A + (size_t)kz*kLen;
  const unsigned short* B4 = Bw + (size_t)kz*kLen;

  f32x4 acc[4][4] = {};
  short8 bfr4[4][2];
  const int NT = kLen/64;

  STG4B(0,0); STG4A(0,0); STG4B(1,1);
  VMC(4);
  __builtin_amdgcn_s_barrier();

  for (int T0 = 0; T0 < NT-2; T0 += 2){
    BLOAD4(0);
    PH4(0, 0, STG4A(1,T0+1), ((void)0));
    PH4(0, 2, STG4B(0,T0+2), VMC(4));
    BLOAD4(1);
    PH4(1, 0, STG4A(0,T0+2), ((void)0));
    PH4(1, 2, STG4B(1,T0+3), VMC(4));
  }
  BLOAD4(0);
  PH4(0, 0, STG4A(1,NT-1), ((void)0));
  PH4(0, 2, ((void)0), VMC(0));
  BLOAD4(1);
  PH4(1, 0, ((void)0), ((void)0));
  PH4(1, 2, ((void)0), ((void)0));

  float* Cp5 = (float*)C + (size_t)kz*M_*ldc;
  #pragma unroll
  for (int m=0;m<4;m++){
    const int row = row0 + wm*64 + m*16 + g16*4;
    #pragma unroll
    for (int n=0;n<4;n++){
      const int col = col0 + wn*64 + n*16 + r;
      #pragma unroll
      for (int j=0;j<4;j++){
        float val = acc[m][n][j];
        size_t idx = (size_t)(row+j)*ldc + col;
        if constexpr (EP==2) { val += bias[col]; val = 0.5f*val*(1.0f + erff(val*0.70710678118f)); }
        if constexpr (EP==0 || EP==2) ((unsigned short*)C)[idx] = f2bf(val);
        else Cp5[idx] = val;
      }
    }
  }
}

// ---------------- fused causal attention: KVBLK=128, balanced q-tile pairing ----------------
// Block bx processes q-tiles {bx, NQB-1-bx}: (bx+1) + (NQB-bx) = NQB+1 iterations
// per block — perfectly balanced causal work (was 1..16, wall = max CU load).
__global__ __launch_bounds__(256)
void attn_k(const unsigned short* __restrict__ qkv, unsigned short* __restrict__ o){
  __shared__ unsigned short Ks[2][64*64];
  __shared__ unsigned short Vt[2][64*64];
  __shared__ unsigned short Ps[2][4*16*64];
  const int tid = threadIdx.x;
  const int wave = tid>>6, lane = tid&63;
  const int bx = blockIdx.x, h = blockIdx.y, b = blockIdx.z;
  const int NQB = S_/64;
  const int r = lane&15, g = lane>>4;
  const size_t rowbase = (size_t)b*S_*3*D_;
  const unsigned short* kbase = qkv + rowbase + D_ + h*64;
  const unsigned short* vbase = qkv + rowbase + 2*D_ + h*64;
  unsigned short* Pw0 = Ps[0] + wave*16*64;
  unsigned short* Pw1 = Ps[1] + wave*16*64;
  uint4 vd0[2], vd1[2];

  const int key8 = tid>>3;
  const int c8   = (tid&7)*8;
  const int kcsw = ((tid&7) ^ (key8&7))*16;

#define KSTG2(i, hb) do{ \
  gload16((const char*)(kbase + (size_t)((hb)*64+key8)*(3*D_)) + kcsw, (char*)Ks[i] + wave*1024); \
  gload16((const char*)(kbase + (size_t)((hb)*64+32+key8)*(3*D_)) + kcsw, (char*)Ks[i] + 4096 + wave*1024); \
}while(0)
#define VLOAD2(vd, hb) do{ \
  vd[0] = *reinterpret_cast<const uint4*>(vbase + (size_t)((hb)*64+key8)*(3*D_) + c8); \
  vd[1] = *reinterpret_cast<const uint4*>(vbase + (size_t)((hb)*64+32+key8)*(3*D_) + c8); \
}while(0)
#define VSTORE2(i, vd) do{ \
  _Pragma("unroll") \
  for (int ii=0;ii<2;ii++){ \
    int key = ii*32 + key8; \
    const unsigned short* ve = reinterpret_cast<const unsigned short*>(&vd[ii]); \
    _Pragma("unroll") \
    for (int j=0;j<8;j++){ \
      int d = c8 + j; \
      int bo2 = (d*128 + key*2) ^ ((d&7)<<4); \
      *reinterpret_cast<unsigned short*>((char*)Vt[i] + bo2) = ve[j]; \
    } \
  } }while(0)
#define QKT2(sacc, i) do{ \
  _Pragma("unroll") \
  for (int ks=0; ks<2; ks++){ \
    _Pragma("unroll") \
    for (int nb=0; nb<4; nb++){ \
      int key = nb*16 + r; \
      int bo = (key*128 + (ks*32+g*8)*2) ^ ((key&7)<<4); \
      short8 kf = *reinterpret_cast<const short8*>((char*)Ks[i] + bo); \
      sacc[nb] = __builtin_amdgcn_mfma_f32_16x16x32_bf16(qf[ks], kf, sacc[nb], 0,0,0); \
    } \
  } }while(0)
#define PV2(i, PwX) do{ \
  _Pragma("unroll") \
  for (int ks=0; ks<2; ks++){ \
    int bo = (r*128 + (ks*32+g*8)*2) ^ ((r&7)<<4); \
    short8 pf8 = *reinterpret_cast<const short8*>((char*)(PwX) + bo); \
    _Pragma("unroll") \
    for (int nb=0; nb<4; nb++){ \
      int d = nb*16 + r; \
      int bo2 = (d*128 + (ks*32+g*8)*2) ^ ((d&7)<<4); \
      short8 vf = *reinterpret_cast<const short8*>((char*)Vt[i] + bo2); \
      oacc[nb] = __builtin_amdgcn_mfma_f32_16x16x32_bf16(pf8, vf, oacc[nb], 0,0,0); \
    } \
  } }while(0)

  for (int sel = 0; sel < 2; ++sel){
    const int qb = sel ? (NQB - 1 - bx) : bx;
    // Q load, pre-scaled by 1/8 (exact)
    short8 qf[2];
    {
      const unsigned short* qp = qkv + rowbase + (size_t)(qb*64 + wave*16 + r)*(3*D_) + h*64 + g*8;
      short8 q0 = *reinterpret_cast<const short8*>(qp);
      short8 q1 = *reinterpret_cast<const short8*>(qp + 32);
      #pragma unroll
      for (int j=0;j<8;j++){
        qf[0][j] = (short)f2bf(bf2f((unsigned short)q0[j])*0.125f);
        qf[1][j] = (short)f2bf(bf2f((unsigned short)q1[j])*0.125f);
      }
    }
    float mrow[4] = {-INFINITY,-INFINITY,-INFINITY,-INFINITY};
    float lrow[4] = {0.f,0.f,0.f,0.f};
    f32x4 oacc[4] = {};
    const int qglob0 = qb*64 + wave*16 + g*4;

    for (int t = 0; 2*t <= qb; ++t){
      const int hb0 = 2*t;
      const bool v1 = (hb0 + 1 <= qb);
      KSTG2(0, hb0);
      if (v1) KSTG2(1, hb0+1);
      VLOAD2(vd0, hb0);
      if (v1) VLOAD2(vd1, hb0+1);
      VMC(0);
      VSTORE2(0, vd0);
      if (v1) VSTORE2(1, vd1);
      __syncthreads();
      f32x4 sacc0[4] = {}, sacc1[4] = {};
      QKT2(sacc0, 0);
      if (v1) QKT2(sacc1, 1);
      float sv0[4][4], sv1[4][4];
      float tm[4] = {-INFINITY,-INFINITY,-INFINITY,-INFINITY};
      if (hb0 == qb){
        #pragma unroll
        for (int nb=0; nb<4; nb++){
          int key = hb0*64 + nb*16 + r;
          #pragma unroll
          for (int j=0;j<4;j++){
            float s = (key <= qglob0 + j) ? sacc0[nb][j] : -INFINITY;
            sv0[nb][j] = s; tm[j] = fmaxf(tm[j], s);
          }
        }
      } else {
        #pragma unroll
        for (int nb=0; nb<4; nb++)
          #pragma unroll
          for (int j=0;j<4;j++){
            float s = sacc0[nb][j];
            sv0[nb][j] = s; tm[j] = fmaxf(tm[j], s);
          }
      }
      if (v1){
        if (hb0 + 1 == qb){
          #pragma unroll
          for (int nb=0; nb<4; nb++){
            int key = (hb0+1)*64 + nb*16 + r;
            #pragma unroll
            for (int j=0;j<4;j++){
              float s = (key <= qglob0 + j) ? sacc1[nb][j] : -INFINITY;
              sv1[nb][j] = s; tm[j] = fmaxf(tm[j], s);
            }
          }
        } else {
          #pragma unroll
          for (int nb=0; nb<4; nb++)
            #pragma unroll
            for (int j=0;j<4;j++){
              float s = sacc1[nb][j];
              sv1[nb][j] = s; tm[j] = fmaxf(tm[j], s);
            }
        }
      }
      #pragma unroll
      for (int off=1; off<16; off<<=1){
        #pragma unroll
        for (int j=0;j<4;j++) tm[j] = fmaxf(tm[j], __shfl_xor(tm[j], off));
      }
      int chg = 0;
      float mn[4];
      #pragma unroll
      for (int j=0;j<4;j++){ mn[j] = fmaxf(mrow[j], tm[j]); chg |= (mn[j] > mrow[j]); }
      if (__any(chg)){
        #pragma unroll
        for (int j=0;j<4;j++){
          float sf = __expf(mrow[j]-mn[j]);
          mrow[j] = mn[j];
          lrow[j] *= sf;
          #pragma unroll
          for (int nb=0;nb<4;nb++) oacc[nb][j] *= sf;
        }
      }
      float psum[4] = {0.f,0.f,0.f,0.f};
      #pragma unroll
      for (int nb=0; nb<4; nb++){
        #pragma unroll
        for (int j=0;j<4;j++){
          float p = __expf(sv0[nb][j]-mrow[j]);
          psum[j] += p;
          int prow = g*4+j;
          int bo = (prow*128 + (nb*16+r)*2) ^ ((prow&7)<<4);
          *reinterpret_cast<unsigned short*>((char*)Pw0 + bo) = f2bf(p);
        }
      }
      if (v1){
        #pragma unroll
        for (int nb=0; nb<4; nb++){
          #pragma unroll
          for (int j=0;j<4;j++){
            float p = __expf(sv1[nb][j]-mrow[j]);
            psum[j] += p;
            int prow = g*4+j;
            int bo = (prow*128 + (nb*16+r)*2) ^ ((prow&7)<<4);
            *reinterpret_cast<unsigned short*>((char*)Pw1 + bo) = f2bf(p);
          }
        }
      }
      #pragma unroll
      for (int off=1; off<16; off<<=1){
        #pragma unroll
        for (int j=0;j<4;j++) psum[j] += __shfl_xor(psum[j], off);
      }
      #pragma unroll
      for (int j=0;j<4;j++) lrow[j] += psum[j];
      asm volatile("s_waitcnt lgkmcnt(0)" ::: "memory");
      PV2(0, Pw0);
      if (v1) PV2(1, Pw1);
      __syncthreads();
    }
    #pragma unroll
    for (int nb=0; nb<4; nb++){
      #pragma unroll
      for (int j=0;j<4;j++){
        float ov = oacc[nb][j] / lrow[j];
        size_t row = (size_t)b*S_ + qb*64 + wave*16 + g*4 + j;
        o[row*D_ + h*64 + nb*16 + r] = f2bf(ov);
      }
    }
  }
}

extern "C" void kernel_launch(void* const* d_in, const int* in_sizes, int n_in,
                              void* d_out, int out_size, void* d_ws, size_t ws_size,
                              hipStream_t stream) {
  const int*   ids   = (const int*)  d_in[0];
  const float* emb   = (const float*)d_in[1];
  const float* Wq    = (const float*)d_in[2];
  const float* Wk    = (const float*)d_in[3];
  const float* Wv    = (const float*)d_in[4];
  const float* Wo    = (const float*)d_in[5];
  const float* W1    = (const float*)d_in[6];
  const float* b1    = (const float*)d_in[7];
  const float* W2    = (const float*)d_in[8];
  const float* b2    = (const float*)d_in[9];
  const float* ln1_g = (const float*)d_in[10];
  const float* ln1_b = (const float*)d_in[11];
  const float* ln2_g = (const float*)d_in[12];
  const float* ln2_b = (const float*)d_in[13];
  const float* lnf_g = (const float*)d_in[14];
  const float* lnf_b = (const float*)d_in[15];
  const float* headw = (const float*)d_in[16];

  unsigned short* ws = (unsigned short*)d_ws;
  unsigned short* wqkvT = ws;                                   // L*3*D*D
  unsigned short* woT   = wqkvT + (size_t)L_*3*D_*D_;           // L*D*D
  unsigned short* w1T   = woT   + (size_t)L_*D_*D_;             // L*DF*D
  unsigned short* w2T   = w1T   + (size_t)L_*D_*DF_;            // L*D*DF
  unsigned short* headT = w2T   + (size_t)L_*D_*DF_;            // V*D
  unsigned short* h     = headT + (size_t)V_*D_;                // M*D
  unsigned short* qkv   = h     + (size_t)M_*D_;                // M*3D
  unsigned short* attno = qkv   + (size_t)M_*3*D_;              // M*D
  unsigned short* h2    = attno + (size_t)M_*D_;                // M*DF
  float*          x     = (float*)(h2 + (size_t)M_*DF_);        // M*D f32
  float*          part  = x + (size_t)M_*D_;                    // 4*M*D f32 (KS=4)

  // ---- weight prep ----
  transpose_k<<<dim3(D_/64, D_/64, L_), 256, 0, stream>>>(Wq, wqkvT,            D_, D_, (size_t)D_*D_, (size_t)3*D_*D_);
  transpose_k<<<dim3(D_/64, D_/64, L_), 256, 0, stream>>>(Wk, wqkvT + D_*D_,    D_, D_, (size_t)D_*D_, (size_t)3*D_*D_);
  transpose_k<<<dim3(D_/64, D_/64, L_), 256, 0, stream>>>(Wv, wqkvT + 2*D_*D_,  D_, D_, (size_t)D_*D_, (size_t)3*D_*D_);
  transpose_k<<<dim3(D_/64, D_/64, L_), 256, 0, stream>>>(Wo, woT,              D_, D_, (size_t)D_*D_, (size_t)D_*D_);
  transpose_k<<<dim3(DF_/64, D_/64, L_), 256, 0, stream>>>(W1, w1T,             D_, DF_, (size_t)D_*DF_, (size_t)D_*DF_);
  transpose_k<<<dim3(D_/64, DF_/64, L_), 256, 0, stream>>>(W2, w2T,             DF_, D_, (size_t)D_*DF_, (size_t)D_*DF_);
  transpose_k<<<dim3(V_/64, D_/64, 1), 256, 0, stream>>>(headw, headT,          D_, V_, 0, 0);

  // ---- fused embed + first LN ----
  embedln_k<<<M_, 256, 0, stream>>>(ids, emb, ln1_g, ln1_b, x, h);

  // ---- layers (h holds ln1(x) entering each layer) ----
  for (int l = 0; l < L_; l++){
    gemm_4ph<0><<<dim3((3*D_/256)*(M_/128), 1, 1), 512, 0, stream>>>(h, wqkvT + (size_t)l*3*D_*D_, qkv, nullptr, D_, 3*D_, M_/128, D_);
    attn_k<<<dim3(S_/128, H_, B_), 256, 0, stream>>>(qkv, attno);
    gemm_4ph<5><<<dim3((D_/256)*(M_/128), 1, 4), 512, 0, stream>>>(attno, woT + (size_t)l*D_*D_, part, nullptr, D_, D_, M_/128, D_/4);
    rln_k<<<M_, 256, 0, stream>>>(x, part, nullptr, ln2_g + l*D_, ln2_b + l*D_, h, 4);
    gemm_4ph<2><<<dim3((DF_/256)*(M_/128), 1, 1), 512, 0, stream>>>(h, w1T + (size_t)l*D_*DF_, h2, b1 + l*DF_, D_, DF_, M_/128, D_);
    const float* ng = (l+1 < L_) ? (ln1_g + (l+1)*D_) : lnf_g;
    const float* nb = (l+1 < L_) ? (ln1_b + (l+1)*D_) : lnf_b;
    gemm_4ph<5><<<dim3((D_/256)*(M_/128), 1, 4), 512, 0, stream>>>(h2, w2T + (size_t)l*D_*DF_, part, nullptr, DF_, D_, M_/128, DF_/4);
    rln_k<<<M_, 256, 0, stream>>>(x, part, b2 + l*D_, ng, nb, h, 4);
  }

  // ---- head GEMM (h = lnf(x) already) ----
  gemm_8ph<<<dim3((V_/256)*(M_/256), 1, 1), 512, 0, stream>>>(h, headT, (float*)d_out, D_, V_, M_/256);
}

// Round 16
// 810.252 us; speedup vs baseline: 1.1358x; 1.0393x over previous
//
#include <hip/hip_runtime.h>
#include <stdint.h>

// Transformer prefill: B=2,S=1024,V=32000,D=1024,H=16,L=4,DK=64,DF=4096
#define B_ 2
#define S_ 1024
#define V_ 32000
#define D_ 1024
#define H_ 16
#define L_ 4
#define DF_ 4096
#define M_ (B_*S_)

typedef short short8 __attribute__((ext_vector_type(8)));
typedef float f32x4 __attribute__((ext_vector_type(4)));

__device__ __forceinline__ unsigned short f2bf(float f){
  union { float f; unsigned int u; } v; v.f = f;
  unsigned int u = v.u;
  u = u + 0x7fffu + ((u >> 16) & 1u);
  return (unsigned short)(u >> 16);
}

__device__ __forceinline__ float bf2f(unsigned short u){
  union { unsigned int u; float f; } v; v.u = ((unsigned int)u) << 16;
  return v.f;
}

__device__ __forceinline__ void gload16(const void* g, void* l){
  __builtin_amdgcn_global_load_lds(
      (__attribute__((address_space(1))) void*)(uintptr_t)g,
      (__attribute__((address_space(3))) void*)(uintptr_t)l, 16, 0, 0);
}

// ---------------- fused embed gather + first LN ----------------
__global__ __launch_bounds__(256) void embedln_k(const int* __restrict__ ids,
    const float* __restrict__ emb, const float* __restrict__ g,
    const float* __restrict__ b, float* __restrict__ x,
    unsigned short* __restrict__ out){
  int row = blockIdx.x;
  int tid = threadIdx.x;
  int id = ids[row];
  float4 v = reinterpret_cast<const float4*>(emb + (size_t)id*D_)[tid];
  reinterpret_cast<float4*>(x + (size_t)row*D_)[tid] = v;
  float s = v.x+v.y+v.z+v.w;
  float ss = v.x*v.x + v.y*v.y + v.z*v.z + v.w*v.w;
  #pragma unroll
  for (int off=1; off<64; off<<=1){ s += __shfl_xor(s, off); ss += __shfl_xor(ss, off); }
  __shared__ float rs[4], rss[4];
  int wave = tid>>6, lane = tid&63;
  if (lane==0){ rs[wave]=s; rss[wave]=ss; }
  __syncthreads();
  s  = rs[0]+rs[1]+rs[2]+rs[3];
  ss = rss[0]+rss[1]+rss[2]+rss[3];
  float mean = s * (1.0f/(float)D_);
  float var  = ss * (1.0f/(float)D_) - mean*mean;
  float inv = rsqrtf(var + 1e-5f);
  float4 gg = reinterpret_cast<const float4*>(g)[tid];
  float4 bb = reinterpret_cast<const float4*>(b)[tid];
  ushort4 o;
  o.x = f2bf((v.x-mean)*inv*gg.x + bb.x);
  o.y = f2bf((v.y-mean)*inv*gg.y + bb.y);
  o.z = f2bf((v.z-mean)*inv*gg.z + bb.z);
  o.w = f2bf((v.w-mean)*inv*gg.w + bb.w);
  reinterpret_cast<ushort4*>(out + (size_t)row*D_)[tid] = o;
}

// ---------------- fused split-K(bf16 partials) reduce + residual + LN ----------------
__global__ __launch_bounds__(256) void rln_k(float* __restrict__ x,
    const unsigned short* __restrict__ part, const float* __restrict__ bias,
    const float* __restrict__ g, const float* __restrict__ b,
    unsigned short* __restrict__ out, int KS){
  int row = blockIdx.x;
  int tid = threadIdx.x;
  float4 v = reinterpret_cast<const float4*>(x + (size_t)row*D_)[tid];
  for (int z=0; z<KS; z++){
    ushort4 p = reinterpret_cast<const ushort4*>(part + (size_t)z*M_*D_ + (size_t)row*D_)[tid];
    v.x += bf2f(p.x); v.y += bf2f(p.y); v.z += bf2f(p.z); v.w += bf2f(p.w);
  }
  if (bias){
    float4 bb4 = reinterpret_cast<const float4*>(bias)[tid];
    v.x+=bb4.x; v.y+=bb4.y; v.z+=bb4.z; v.w+=bb4.w;
  }
  reinterpret_cast<float4*>(x + (size_t)row*D_)[tid] = v;
  float s = v.x+v.y+v.z+v.w;
  float ss = v.x*v.x + v.y*v.y + v.z*v.z + v.w*v.w;
  #pragma unroll
  for (int off=1; off<64; off<<=1){ s += __shfl_xor(s, off); ss += __shfl_xor(ss, off); }
  __shared__ float rs[4], rss[4];
  int wave = tid>>6, lane = tid&63;
  if (lane==0){ rs[wave]=s; rss[wave]=ss; }
  __syncthreads();
  s  = rs[0]+rs[1]+rs[2]+rs[3];
  ss = rss[0]+rss[1]+rss[2]+rss[3];
  float mean = s * (1.0f/(float)D_);
  float var  = ss * (1.0f/(float)D_) - mean*mean;
  float inv = rsqrtf(var + 1e-5f);
  float4 gg = reinterpret_cast<const float4*>(g)[tid];
  float4 bb = reinterpret_cast<const float4*>(b)[tid];
  ushort4 o;
  o.x = f2bf((v.x-mean)*inv*gg.x + bb.x);
  o.y = f2bf((v.y-mean)*inv*gg.y + bb.y);
  o.z = f2bf((v.z-mean)*inv*gg.z + bb.z);
  o.w = f2bf((v.w-mean)*inv*gg.w + bb.w);
  reinterpret_cast<ushort4*>(out + (size_t)row*D_)[tid] = o;
}

// ---------------- transpose + f32->bf16: in [K][N] -> out [N][K] ----------------
__global__ __launch_bounds__(256) void transpose_k(const float* __restrict__ in,
    unsigned short* __restrict__ out, int K, int N, size_t in_ls, size_t out_ls){
  __shared__ float t[64][65];
  const float* inp = in + (size_t)blockIdx.z*in_ls;
  unsigned short* outp = out + (size_t)blockIdx.z*out_ls;
  int k0 = blockIdx.y*64, n0 = blockIdx.x*64;
  int rr = threadIdx.x >> 4, c4 = (threadIdx.x & 15)*4;
  #pragma unroll
  for (int i=0;i<4;i++){
    float4 v = *reinterpret_cast<const float4*>(inp + (size_t)(k0+rr+i*16)*N + n0 + c4);
    t[rr+i*16][c4+0]=v.x; t[rr+i*16][c4+1]=v.y; t[rr+i*16][c4+2]=v.z; t[rr+i*16][c4+3]=v.w;
  }
  __syncthreads();
  const int c8 = (threadIdx.x & 7)*8;
  const int nn = threadIdx.x >> 3;
  #pragma unroll
  for (int i=0;i<2;i++){
    const int n = nn + i*32;
    unsigned short o[8];
    #pragma unroll
    for (int j=0;j<8;j++) o[j] = f2bf(t[c8+j][n]);
    *reinterpret_cast<short8*>(outp + (size_t)(n0+n)*K + k0 + c8) =
        *reinterpret_cast<const short8*>(o);
  }
}

#define VMC(n)  asm volatile("s_waitcnt vmcnt(" #n ")" ::: "memory")

// ---------------- 256^2 8-phase GEMM (head) ----------------
#define LDA8(buf,m,ks) (*(const short8*)(lds8 + (buf)*65536 + (wm*128+(m)*16+r)*128 + (((ks)*64+g16*16)^rsw)))
#define LDB8(buf,n,ks) (*(const short8*)(lds8 + (buf)*65536 + 32768 + (wn*64+(n)*16+r)*128 + (((ks)*64+g16*16)^rsw)))
#define STG(buf,isB,h,i,tile) gload16( \
    ((isB) ? Bw + (size_t)(col0 + (h)*128 + (i)*64 + wave*8 + srow)*K + (size_t)(tile)*64 + scsw \
           : A  + (size_t)(row0 + (h)*128 + (i)*64 + wave*8 + srow)*K + (size_t)(tile)*64 + scsw), \
    lds8 + (buf)*65536 + (isB)*32768 + ((h)*128 + (i)*64 + wave*8)*128 )
#define STG_HT(buf,isB,h,tile) do{ STG(buf,isB,h,0,tile); STG(buf,isB,h,1,tile); }while(0)
#define BLOAD8(bT) do{ \
  bfr[0][0]=LDB8(bT,0,0); bfr[0][1]=LDB8(bT,0,1); bfr[1][0]=LDB8(bT,1,0); bfr[1][1]=LDB8(bT,1,1); \
  bfr[2][0]=LDB8(bT,2,0); bfr[2][1]=LDB8(bT,2,1); bfr[3][0]=LDB8(bT,3,0); bfr[3][1]=LDB8(bT,3,1); }while(0)
#define MM8(mb,n) do{ \
  acc[mb][n]    =__builtin_amdgcn_mfma_f32_16x16x32_bf16(a0[0],bfr[n][0],acc[mb][n],0,0,0); \
  acc[mb][n]    =__builtin_amdgcn_mfma_f32_16x16x32_bf16(a0[1],bfr[n][1],acc[mb][n],0,0,0); \
  acc[(mb)+1][n]=__builtin_amdgcn_mfma_f32_16x16x32_bf16(a1[0],bfr[n][0],acc[(mb)+1][n],0,0,0); \
  acc[(mb)+1][n]=__builtin_amdgcn_mfma_f32_16x16x32_bf16(a1[1],bfr[n][1],acc[(mb)+1][n],0,0,0); }while(0)
#define PH8(bT, mb, STAGES, TAIL) do{ \
  short8 a0[2], a1[2]; \
  a0[0]=LDA8(bT,mb,0); a0[1]=LDA8(bT,mb,1); a1[0]=LDA8(bT,(mb)+1,0); a1[1]=LDA8(bT,(mb)+1,1); \
  STAGES; \
  __builtin_amdgcn_s_barrier(); \
  asm volatile("s_waitcnt lgkmcnt(0)" ::: "memory"); \
  __builtin_amdgcn_s_setprio(1); \
  MM8(mb,0); MM8(mb,1); MM8(mb,2); MM8(mb,3); \
  __builtin_amdgcn_s_setprio(0); \
  TAIL; \
  __builtin_amdgcn_s_barrier(); \
}while(0)

__global__ __launch_bounds__(512, 2)
void gemm_8ph(const unsigned short* __restrict__ A, const unsigned short* __restrict__ Bw,
              float* __restrict__ C, int K, int ldc, int MB){
  __shared__ char lds8[131072];
  const int tid = threadIdx.x;
  const int wave = tid>>6, lane = tid&63;
  const int wm = wave>>2, wn = wave&3;
  const int nwg = gridDim.x;
  const int pp = blockIdx.x;
  const int t = (nwg & 7) ? pp : ((pp & 7)*(nwg>>3) + (pp>>3));
  const int by = t % MB, bx = t / MB;
  const int row0 = by*256, col0 = bx*256;
  const int r = lane&15, g16 = lane>>4;
  const int rsw = (r&7)<<4;
  const int srow = lane>>3;
  const int scsw = ((lane&7) ^ srow)*8;

  f32x4 acc[8][4] = {};
  short8 bfr[4][2];
  const int NT = K/64;

  STG_HT(0,1,0,0); STG_HT(0,1,1,0);
  STG_HT(0,0,0,0); STG_HT(0,0,1,0);
  STG_HT(1,1,0,1); STG_HT(1,1,1,1);
  VMC(4);
  __builtin_amdgcn_s_barrier();

  for (int T0 = 0; T0 < NT-2; T0 += 2){
    BLOAD8(0);
    PH8(0, 0, STG_HT(1,0,0,T0+1), ((void)0));
    PH8(0, 2, STG_HT(1,0,1,T0+1), ((void)0));
    PH8(0, 4, STG_HT(0,1,0,T0+2), ((void)0));
    PH8(0, 6, STG_HT(0,1,1,T0+2), VMC(4));
    BLOAD8(1);
    PH8(1, 0, STG_HT(0,0,0,T0+2), ((void)0));
    PH8(1, 2, STG_HT(0,0,1,T0+2), ((void)0));
    PH8(1, 4, STG_HT(1,1,0,T0+3), ((void)0));
    PH8(1, 6, STG_HT(1,1,1,T0+3), VMC(4));
  }
  BLOAD8(0);
  PH8(0, 0, STG_HT(1,0,0,NT-1), ((void)0));
  PH8(0, 2, STG_HT(1,0,1,NT-1), ((void)0));
  PH8(0, 4, ((void)0), ((void)0));
  PH8(0, 6, ((void)0), VMC(0));
  BLOAD8(1);
  PH8(1, 0, ((void)0), ((void)0));
  PH8(1, 2, ((void)0), ((void)0));
  PH8(1, 4, ((void)0), ((void)0));
  PH8(1, 6, ((void)0), ((void)0));

  #pragma unroll
  for (int m=0;m<8;m++){
    const int row = row0 + wm*128 + m*16 + g16*4;
    #pragma unroll
    for (int n=0;n<4;n++){
      const int col = col0 + wn*64 + n*16 + r;
      #pragma unroll
      for (int j=0;j<4;j++)
        C[(size_t)(row+j)*ldc + col] = acc[m][n][j];
    }
  }
}

// ---------------- 128x256 4-phase GEMM (layer GEMMs) ----------------
// EP: 0 = bf16 out; 2 = +bias,GELU bf16; 6 = bf16 partial at C + kz*M*ldc
#define L4A(buf,m,ks) (*(const short8*)(lds4 + (buf)*49152 + (wm*64+(m)*16+r)*128 + (((ks)*64+g16*16)^rsw)))
#define L4B(buf,n,ks) (*(const short8*)(lds4 + (buf)*49152 + 16384 + (wn*64+(n)*16+r)*128 + (((ks)*64+g16*16)^rsw)))
#define STG4A(buf,tile) do{ \
  gload16(A4 + (size_t)(row0 + 0*64 + wave*8 + srow)*K + (size_t)(tile)*64 + scsw, lds4 + (buf)*49152 + (0*64+wave*8)*128); \
  gload16(A4 + (size_t)(row0 + 1*64 + wave*8 + srow)*K + (size_t)(tile)*64 + scsw, lds4 + (buf)*49152 + (1*64+wave*8)*128); }while(0)
#define STG4B(buf,tile) do{ \
  gload16(B4 + (size_t)(col0 + 0*64 + wave*8 + srow)*K + (size_t)(tile)*64 + scsw, lds4 + (buf)*49152 + 16384 + (0*64+wave*8)*128); \
  gload16(B4 + (size_t)(col0 + 1*64 + wave*8 + srow)*K + (size_t)(tile)*64 + scsw, lds4 + (buf)*49152 + 16384 + (1*64+wave*8)*128); \
  gload16(B4 + (size_t)(col0 + 2*64 + wave*8 + srow)*K + (size_t)(tile)*64 + scsw, lds4 + (buf)*49152 + 16384 + (2*64+wave*8)*128); \
  gload16(B4 + (size_t)(col0 + 3*64 + wave*8 + srow)*K + (size_t)(tile)*64 + scsw, lds4 + (buf)*49152 + 16384 + (3*64+wave*8)*128); }while(0)
#define BLOAD4(bT) do{ \
  bfr4[0][0]=L4B(bT,0,0); bfr4[0][1]=L4B(bT,0,1); bfr4[1][0]=L4B(bT,1,0); bfr4[1][1]=L4B(bT,1,1); \
  bfr4[2][0]=L4B(bT,2,0); bfr4[2][1]=L4B(bT,2,1); bfr4[3][0]=L4B(bT,3,0); bfr4[3][1]=L4B(bT,3,1); }while(0)
#define MM44(mb,n) do{ \
  acc[mb][n]    =__builtin_amdgcn_mfma_f32_16x16x32_bf16(a0[0],bfr4[n][0],acc[mb][n],0,0,0); \
  acc[mb][n]    =__builtin_amdgcn_mfma_f32_16x16x32_bf16(a0[1],bfr4[n][1],acc[mb][n],0,0,0); \
  acc[(mb)+1][n]=__builtin_amdgcn_mfma_f32_16x16x32_bf16(a1[0],bfr4[n][0],acc[(mb)+1][n],0,0,0); \
  acc[(mb)+1][n]=__builtin_amdgcn_mfma_f32_16x16x32_bf16(a1[1],bfr4[n][1],acc[(mb)+1][n],0,0,0); }while(0)
#define PH4(bT, mb, STAGES, TAIL) do{ \
  short8 a0[2], a1[2]; \
  a0[0]=L4A(bT,mb,0); a0[1]=L4A(bT,mb,1); a1[0]=L4A(bT,(mb)+1,0); a1[1]=L4A(bT,(mb)+1,1); \
  STAGES; \
  __builtin_amdgcn_s_barrier(); \
  asm volatile("s_waitcnt lgkmcnt(0)" ::: "memory"); \
  __builtin_amdgcn_s_setprio(1); \
  MM44(mb,0); MM44(mb,1); MM44(mb,2); MM44(mb,3); \
  __builtin_amdgcn_s_setprio(0); \
  TAIL; \
  __builtin_amdgcn_s_barrier(); \
}while(0)

template<int EP>
__global__ __launch_bounds__(512, 2)
void gemm_4ph(const unsigned short* __restrict__ A, const unsigned short* __restrict__ Bw,
              void* __restrict__ C, const float* __restrict__ bias,
              int K, int ldc, int MB, int kLen){
  __shared__ char lds4[98304];
  const int tid = threadIdx.x;
  const int wave = tid>>6, lane = tid&63;
  const int wm = wave>>2, wn = wave&3;
  const int nwg = gridDim.x;
  const int pp = blockIdx.x;
  const int t = (nwg & 7) ? pp : ((pp & 7)*(nwg>>3) + (pp>>3));
  const int by = t % MB, bx = t / MB;
  const int row0 = by*128, col0 = bx*256;
  const int r = lane&15, g16 = lane>>4;
  const int rsw = (r&7)<<4;
  const int srow = lane>>3;
  const int scsw = ((lane&7) ^ srow)*8;
  const int kz = blockIdx.z;
  const unsigned short* A4 = A + (size_t)kz*kLen;
  const unsigned short* B4 = Bw + (size_t)kz*kLen;

  f32x4 acc[4][4] = {};
  short8 bfr4[4][2];
  const int NT = kLen/64;

  STG4B(0,0); STG4A(0,0); STG4B(1,1);
  VMC(4);
  __builtin_amdgcn_s_barrier();

  for (int T0 = 0; T0 < NT-2; T0 += 2){
    BLOAD4(0);
    PH4(0, 0, STG4A(1,T0+1), ((void)0));
    PH4(0, 2, STG4B(0,T0+2), VMC(4));
    BLOAD4(1);
    PH4(1, 0, STG4A(0,T0+2), ((void)0));
    PH4(1, 2, STG4B(1,T0+3), VMC(4));
  }
  BLOAD4(0);
  PH4(0, 0, STG4A(1,NT-1), ((void)0));
  PH4(0, 2, ((void)0), VMC(0));
  BLOAD4(1);
  PH4(1, 0, ((void)0), ((void)0));
  PH4(1, 2, ((void)0), ((void)0));

  unsigned short* Cp6 = (unsigned short*)C + (size_t)kz*M_*ldc;
  #pragma unroll
  for (int m=0;m<4;m++){
    const int row = row0 + wm*64 + m*16 + g16*4;
    #pragma unroll
    for (int n=0;n<4;n++){
      const int col = col0 + wn*64 + n*16 + r;
      #pragma unroll
      for (int j=0;j<4;j++){
        float val = acc[m][n][j];
        size_t idx = (size_t)(row+j)*ldc + col;
        if constexpr (EP==2) { val += bias[col]; val = 0.5f*val*(1.0f + erff(val*0.70710678118f)); }
        if constexpr (EP==0 || EP==2) ((unsigned short*)C)[idx] = f2bf(val);
        else Cp6[idx] = f2bf(val);
      }
    }
  }
}

// ---------------- fused causal attention: KVBLK=128, balanced q-tile pairing ----------------
__global__ __launch_bounds__(256)
void attn_k(const unsigned short* __restrict__ qkv, unsigned short* __restrict__ o){
  __shared__ unsigned short Ks[2][64*64];
  __shared__ unsigned short Vt[2][64*64];
  __shared__ unsigned short Ps[2][4*16*64];
  const int tid = threadIdx.x;
  const int wave = tid>>6, lane = tid&63;
  const int bx = blockIdx.x, h = blockIdx.y, b = blockIdx.z;
  const int NQB = S_/64;
  const int r = lane&15, g = lane>>4;
  const size_t rowbase = (size_t)b*S_*3*D_;
  const unsigned short* kbase = qkv + rowbase + D_ + h*64;
  const unsigned short* vbase = qkv + rowbase + 2*D_ + h*64;
  unsigned short* Pw0 = Ps[0] + wave*16*64;
  unsigned short* Pw1 = Ps[1] + wave*16*64;
  uint4 vd0[2], vd1[2];

  const int key8 = tid>>3;
  const int c8   = (tid&7)*8;
  const int kcsw = ((tid&7) ^ (key8&7))*16;

#define KSTG2(i, hb) do{ \
  gload16((const char*)(kbase + (size_t)((hb)*64+key8)*(3*D_)) + kcsw, (char*)Ks[i] + wave*1024); \
  gload16((const char*)(kbase + (size_t)((hb)*64+32+key8)*(3*D_)) + kcsw, (char*)Ks[i] + 4096 + wave*1024); \
}while(0)
#define VLOAD2(vd, hb) do{ \
  vd[0] = *reinterpret_cast<const uint4*>(vbase + (size_t)((hb)*64+key8)*(3*D_) + c8); \
  vd[1] = *reinterpret_cast<const uint4*>(vbase + (size_t)((hb)*64+32+key8)*(3*D_) + c8); \
}while(0)
#define VSTORE2(i, vd) do{ \
  _Pragma("unroll") \
  for (int ii=0;ii<2;ii++){ \
    int key = ii*32 + key8; \
    const unsigned short* ve = reinterpret_cast<const unsigned short*>(&vd[ii]); \
    _Pragma("unroll") \
    for (int j=0;j<8;j++){ \
      int d = c8 + j; \
      int bo2 = (d*128 + key*2) ^ ((d&7)<<4); \
      *reinterpret_cast<unsigned short*>((char*)Vt[i] + bo2) = ve[j]; \
    } \
  } }while(0)
#define QKT2(sacc, i) do{ \
  _Pragma("unroll") \
  for (int ks=0; ks<2; ks++){ \
    _Pragma("unroll") \
    for (int nb=0; nb<4; nb++){ \
      int key = nb*16 + r; \
      int bo = (key*128 + (ks*32+g*8)*2) ^ ((key&7)<<4); \
      short8 kf = *reinterpret_cast<const short8*>((char*)Ks[i] + bo); \
      sacc[nb] = __builtin_amdgcn_mfma_f32_16x16x32_bf16(qf[ks], kf, sacc[nb], 0,0,0); \
    } \
  } }while(0)
#define PV2(i, PwX) do{ \
  _Pragma("unroll") \
  for (int ks=0; ks<2; ks++){ \
    int bo = (r*128 + (ks*32+g*8)*2) ^ ((r&7)<<4); \
    short8 pf8 = *reinterpret_cast<const short8*>((char*)(PwX) + bo); \
    _Pragma("unroll") \
    for (int nb=0; nb<4; nb++){ \
      int d = nb*16 + r; \
      int bo2 = (d*128 + (ks*32+g*8)*2) ^ ((d&7)<<4); \
      short8 vf = *reinterpret_cast<const short8*>((char*)Vt[i] + bo2); \
      oacc[nb] = __builtin_amdgcn_mfma_f32_16x16x32_bf16(pf8, vf, oacc[nb], 0,0,0); \
    } \
  } }while(0)

  for (int sel = 0; sel < 2; ++sel){
    const int qb = sel ? (NQB - 1 - bx) : bx;
    short8 qf[2];
    {
      const unsigned short* qp = qkv + rowbase + (size_t)(qb*64 + wave*16 + r)*(3*D_) + h*64 + g*8;
      short8 q0 = *reinterpret_cast<const short8*>(qp);
      short8 q1 = *reinterpret_cast<const short8*>(qp + 32);
      #pragma unroll
      for (int j=0;j<8;j++){
        qf[0][j] = (short)f2bf(bf2f((unsigned short)q0[j])*0.125f);
        qf[1][j] = (short)f2bf(bf2f((unsigned short)q1[j])*0.125f);
      }
    }
    float mrow[4] = {-INFINITY,-INFINITY,-INFINITY,-INFINITY};
    float lrow[4] = {0.f,0.f,0.f,0.f};
    f32x4 oacc[4] = {};
    const int qglob0 = qb*64 + wave*16 + g*4;

    for (int t = 0; 2*t <= qb; ++t){
      const int hb0 = 2*t;
      const bool v1 = (hb0 + 1 <= qb);
      KSTG2(0, hb0);
      if (v1) KSTG2(1, hb0+1);
      VLOAD2(vd0, hb0);
      if (v1) VLOAD2(vd1, hb0+1);
      VMC(0);
      VSTORE2(0, vd0);
      if (v1) VSTORE2(1, vd1);
      __syncthreads();
      f32x4 sacc0[4] = {}, sacc1[4] = {};
      QKT2(sacc0, 0);
      if (v1) QKT2(sacc1, 1);
      float sv0[4][4], sv1[4][4];
      float tm[4] = {-INFINITY,-INFINITY,-INFINITY,-INFINITY};
      if (hb0 == qb){
        #pragma unroll
        for (int nb=0; nb<4; nb++){
          int key = hb0*64 + nb*16 + r;
          #pragma unroll
          for (int j=0;j<4;j++){
            float s = (key <= qglob0 + j) ? sacc0[nb][j] : -INFINITY;
            sv0[nb][j] = s; tm[j] = fmaxf(tm[j], s);
          }
        }
      } else {
        #pragma unroll
        for (int nb=0; nb<4; nb++)
          #pragma unroll
          for (int j=0;j<4;j++){
            float s = sacc0[nb][j];
            sv0[nb][j] = s; tm[j] = fmaxf(tm[j], s);
          }
      }
      if (v1){
        if (hb0 + 1 == qb){
          #pragma unroll
          for (int nb=0; nb<4; nb++){
            int key = (hb0+1)*64 + nb*16 + r;
            #pragma unroll
            for (int j=0;j<4;j++){
              float s = (key <= qglob0 + j) ? sacc1[nb][j] : -INFINITY;
              sv1[nb][j] = s; tm[j] = fmaxf(tm[j], s);
            }
          }
        } else {
          #pragma unroll
          for (int nb=0; nb<4; nb++)
            #pragma unroll
            for (int j=0;j<4;j++){
              float s = sacc1[nb][j];
              sv1[nb][j] = s; tm[j] = fmaxf(tm[j], s);
            }
        }
      }
      #pragma unroll
      for (int off=1; off<16; off<<=1){
        #pragma unroll
        for (int j=0;j<4;j++) tm[j] = fmaxf(tm[j], __shfl_xor(tm[j], off));
      }
      int chg = 0;
      float mn[4];
      #pragma unroll
      for (int j=0;j<4;j++){ mn[j] = fmaxf(mrow[j], tm[j]); chg |= (mn[j] > mrow[j]); }
      if (__any(chg)){
        #pragma unroll
        for (int j=0;j<4;j++){
          float sf = __expf(mrow[j]-mn[j]);
          mrow[j] = mn[j];
          lrow[j] *= sf;
          #pragma unroll
          for (int nb=0;nb<4;nb++) oacc[nb][j] *= sf;
        }
      }
      float psum[4] = {0.f,0.f,0.f,0.f};
      #pragma unroll
      for (int nb=0; nb<4; nb++){
        #pragma unroll
        for (int j=0;j<4;j++){
          float p = __expf(sv0[nb][j]-mrow[j]);
          psum[j] += p;
          int prow = g*4+j;
          int bo = (prow*128 + (nb*16+r)*2) ^ ((prow&7)<<4);
          *reinterpret_cast<unsigned short*>((char*)Pw0 + bo) = f2bf(p);
        }
      }
      if (v1){
        #pragma unroll
        for (int nb=0; nb<4; nb++){
          #pragma unroll
          for (int j=0;j<4;j++){
            float p = __expf(sv1[nb][j]-mrow[j]);
            psum[j] += p;
            int prow = g*4+j;
            int bo = (prow*128 + (nb*16+r)*2) ^ ((prow&7)<<4);
            *reinterpret_cast<unsigned short*>((char*)Pw1 + bo) = f2bf(p);
          }
        }
      }
      #pragma unroll
      for (int off=1; off<16; off<<=1){
        #pragma unroll
        for (int j=0;j<4;j++) psum[j] += __shfl_xor(psum[j], off);
      }
      #pragma unroll
      for (int j=0;j<4;j++) lrow[j] += psum[j];
      asm volatile("s_waitcnt lgkmcnt(0)" ::: "memory");
      PV2(0, Pw0);
      if (v1) PV2(1, Pw1);
      __syncthreads();
    }
    #pragma unroll
    for (int nb=0; nb<4; nb++){
      #pragma unroll
      for (int j=0;j<4;j++){
        float ov = oacc[nb][j] / lrow[j];
        size_t row = (size_t)b*S_ + qb*64 + wave*16 + g*4 + j;
        o[row*D_ + h*64 + nb*16 + r] = f2bf(ov);
      }
    }
  }
}

extern "C" void kernel_launch(void* const* d_in, const int* in_sizes, int n_in,
                              void* d_out, int out_size, void* d_ws, size_t ws_size,
                              hipStream_t stream) {
  const int*   ids   = (const int*)  d_in[0];
  const float* emb   = (const float*)d_in[1];
  const float* Wq    = (const float*)d_in[2];
  const float* Wk    = (const float*)d_in[3];
  const float* Wv    = (const float*)d_in[4];
  const float* Wo    = (const float*)d_in[5];
  const float* W1    = (const float*)d_in[6];
  const float* b1    = (const float*)d_in[7];
  const float* W2    = (const float*)d_in[8];
  const float* b2    = (const float*)d_in[9];
  const float* ln1_g = (const float*)d_in[10];
  const float* ln1_b = (const float*)d_in[11];
  const float* ln2_g = (const float*)d_in[12];
  const float* ln2_b = (const float*)d_in[13];
  const float* lnf_g = (const float*)d_in[14];
  const float* lnf_b = (const float*)d_in[15];
  const float* headw = (const float*)d_in[16];

  unsigned short* ws = (unsigned short*)d_ws;
  unsigned short* wqkvT = ws;                                   // L*3*D*D
  unsigned short* woT   = wqkvT + (size_t)L_*3*D_*D_;           // L*D*D
  unsigned short* w1T   = woT   + (size_t)L_*D_*D_;             // L*DF*D
  unsigned short* w2T   = w1T   + (size_t)L_*D_*DF_;            // L*D*DF
  unsigned short* headT = w2T   + (size_t)L_*D_*DF_;            // V*D
  unsigned short* h     = headT + (size_t)V_*D_;                // M*D
  unsigned short* qkv   = h     + (size_t)M_*D_;                // M*3D
  unsigned short* attno = qkv   + (size_t)M_*3*D_;              // M*D
  unsigned short* h2    = attno + (size_t)M_*D_;                // M*DF
  float*          x     = (float*)(h2 + (size_t)M_*DF_);        // M*D f32
  unsigned short* part  = (unsigned short*)(x + (size_t)M_*D_); // 4*M*D bf16 partials

  // ---- weight prep ----
  transpose_k<<<dim3(D_/64, D_/64, L_), 256, 0, stream>>>(Wq, wqkvT,            D_, D_, (size_t)D_*D_, (size_t)3*D_*D_);
  transpose_k<<<dim3(D_/64, D_/64, L_), 256, 0, stream>>>(Wk, wqkvT + D_*D_,    D_, D_, (size_t)D_*D_, (size_t)3*D_*D_);
  transpose_k<<<dim3(D_/64, D_/64, L_), 256, 0, stream>>>(Wv, wqkvT + 2*D_*D_,  D_, D_, (size_t)D_*D_, (size_t)3*D_*D_);
  transpose_k<<<dim3(D_/64, D_/64, L_), 256, 0, stream>>>(Wo, woT,              D_, D_, (size_t)D_*D_, (size_t)D_*D_);
  transpose_k<<<dim3(DF_/64, D_/64, L_), 256, 0, stream>>>(W1, w1T,             D_, DF_, (size_t)D_*DF_, (size_t)D_*DF_);
  transpose_k<<<dim3(D_/64, DF_/64, L_), 256, 0, stream>>>(W2, w2T,             DF_, D_, (size_t)D_*DF_, (size_t)D_*DF_);
  transpose_k<<<dim3(V_/64, D_/64, 1), 256, 0, stream>>>(headw, headT,          D_, V_, 0, 0);

  // ---- fused embed + first LN ----
  embedln_k<<<M_, 256, 0, stream>>>(ids, emb, ln1_g, ln1_b, x, h);

  // ---- layers (h holds ln1(x) entering each layer) ----
  for (int l = 0; l < L_; l++){
    gemm_4ph<0><<<dim3((3*D_/256)*(M_/128), 1, 1), 512, 0, stream>>>(h, wqkvT + (size_t)l*3*D_*D_, qkv, nullptr, D_, 3*D_, M_/128, D_);
    attn_k<<<dim3(S_/128, H_, B_), 256, 0, stream>>>(qkv, attno);
    gemm_4ph<6><<<dim3((D_/256)*(M_/128), 1, 4), 512, 0, stream>>>(attno, woT + (size_t)l*D_*D_, part, nullptr, D_, D_, M_/128, D_/4);
    rln_k<<<M_, 256, 0, stream>>>(x, part, nullptr, ln2_g + l*D_, ln2_b + l*D_, h, 4);
    gemm_4ph<2><<<dim3((DF_/256)*(M_/128), 1, 1), 512, 0, stream>>>(h, w1T + (size_t)l*D_*DF_, h2, b1 + l*DF_, D_, DF_, M_/128, D_);
    const float* ng = (l+1 < L_) ? (ln1_g + (l+1)*D_) : lnf_g;
    const float* nb = (l+1 < L_) ? (ln1_b + (l+1)*D_) : lnf_b;
    gemm_4ph<6><<<dim3((D_/256)*(M_/128), 1, 4), 512, 0, stream>>>(h2, w2T + (size_t)l*D_*DF_, part, nullptr, DF_, D_, M_/128, DF_/4);
    rln_k<<<M_, 256, 0, stream>>>(x, part, b2 + l*D_, ng, nb, h, 4);
  }

  // ---- head GEMM (h = lnf(x) already) ----
  gemm_8ph<<<dim3((V_/256)*(M_/256), 1, 1), 512, 0, stream>>>(h, headT, (float*)d_out, D_, V_, M_/256);
}